// Round 7
// baseline (1961.545 us; speedup 1.0000x reference)
//
#include <hip/hip_runtime.h>

#define B_  16
#define T_  12
#define N_  1024
#define K_  3
#define H_  64
#define DIN 65
#define KH  192   // K_*H_
#define OG  128   // 2*H_

typedef _Float16 f16x4 __attribute__((ext_vector_type(4)));
typedef float    f32x4 __attribute__((ext_vector_type(4)));

// ---- workspace offsets (float units), total 6,670,912 f = 26.7 MB ----
static const size_t OFF_H   = 0;          // f32 h   [16][1024][64]
static const size_t OFF_ZB  = 1048576;    // f32 z   [16][1024][64]
static const size_t OFF_S2  = 2097152;    // f32 S2  [16][3][12][1024] (x1024)
static const size_t OFF_ZF  = 2686976;    // f16 Z   [16][1024][192]   (x1024)
static const size_t OFF_HT  = 4259840;    // f16 Ht  [16][64][1024]
static const size_t OFF_YT  = 4784128;    // f16 Yt  [16][192][1024]
static const size_t OFF_S1  = 6356992;    // f16 S1  [3][192][1024]
static const size_t OFF_WGT = 6651904;    // f16 wghT [128][192] (/1024)
static const size_t OFF_WUT = 6664192;    // f16 wuhT [64][192]  (/1024)
static const size_t OFF_WX  = 6670336;    // f32 wx: [0..383]=gate [3][128], [384..575]=upd [3][64] (/1024)

// Repack weights: transposed f16 h-part + f32 x-part rows, all pre-divided by 1024.
__global__ __launch_bounds__(256) void k_repack(const float* __restrict__ Wg,
                                                const float* __restrict__ Wu,
                                                _Float16* __restrict__ wghT,
                                                _Float16* __restrict__ wuhT,
                                                float* __restrict__ wx) {
    const float inv = 1.0f / 1024.0f;
    int idx = blockIdx.x * 256 + threadIdx.x;
    if (idx < 128 * 192) {                       // wghT[o][d], d = k*64+c
        int o = idx / 192, d = idx % 192;
        int k = d / 64, c = d % 64;
        wghT[idx] = (_Float16)(Wg[(size_t)(k * DIN + 1 + c) * OG + o] * inv);
    } else if (idx < 128 * 192 + 64 * 192) {     // wuhT[o][d]
        int j = idx - 128 * 192;
        int o = j / 192, d = j % 192;
        int k = d / 64, c = d % 64;
        wuhT[j] = (_Float16)(Wu[(size_t)(k * DIN + 1 + c) * H_ + o] * inv);
    } else if (idx < 128 * 192 + 64 * 192 + 576) {
        int j = idx - 128 * 192 - 64 * 192;
        if (j < 384) { int k = j >> 7, o = j & 127; wx[j] = Wg[(size_t)(k * DIN) * OG + o] * inv; }
        else { int j2 = j - 384; int k = j2 >> 6, o = j2 & 63; wx[j] = Wu[(size_t)(k * DIN) * H_ + o] * inv; }
    }
}

// S1[k][m][i] = sum_j G[k][i][j] x[m][j]  (f16 out). grid 96: kk*32 + it*2 + nh
__global__ __launch_bounds__(256) void k_s1b(const float* __restrict__ G,
                                             const float* __restrict__ x,
                                             _Float16* __restrict__ S1) {
    int bx = blockIdx.x;
    int nh = bx & 1, it = (bx >> 1) & 15, kk = bx >> 5;
    int i0 = it * 64, m0 = nh * 96;
    __shared__ _Float16 sA[64][72], sB[96][72];
    int tid = threadIdx.x, wid = tid >> 6, ln = tid & 15, kl = (tid & 63) >> 4;
    const float* Gk = G + (size_t)kk * N_ * N_;
    f32x4 acc[6];
    #pragma unroll
    for (int n = 0; n < 6; ++n) acc[n] = (f32x4){0.f, 0.f, 0.f, 0.f};
    for (int kc = 0; kc < N_; kc += 64) {
        #pragma unroll
        for (int it2 = 0; it2 < 4; ++it2) {
            int idx = it2 * 256 + tid; int row = idx >> 4, c4 = (idx & 15) * 4;
            float4 g = *(const float4*)&Gk[(size_t)(i0 + row) * N_ + kc + c4];
            f16x4 hv = {(_Float16)g.x, (_Float16)g.y, (_Float16)g.z, (_Float16)g.w};
            *(f16x4*)&sA[row][c4] = hv;
        }
        #pragma unroll
        for (int it2 = 0; it2 < 6; ++it2) {
            int idx = it2 * 256 + tid; int row = idx >> 4, c4 = (idx & 15) * 4;
            float4 g = *(const float4*)&x[(size_t)(m0 + row) * N_ + kc + c4];
            f16x4 hv = {(_Float16)g.x, (_Float16)g.y, (_Float16)g.z, (_Float16)g.w};
            *(f16x4*)&sB[row][c4] = hv;
        }
        __syncthreads();
        #pragma unroll
        for (int ks = 0; ks < 4; ++ks) {
            int ko = ks * 16 + kl * 4;
            f16x4 a = *(const f16x4*)&sA[wid * 16 + ln][ko];
            #pragma unroll
            for (int n = 0; n < 6; ++n) {
                f16x4 b = *(const f16x4*)&sB[n * 16 + ln][ko];
                acc[n] = __builtin_amdgcn_mfma_f32_16x16x16f16(a, b, acc[n], 0, 0, 0);
            }
        }
        __syncthreads();
    }
    #pragma unroll
    for (int n = 0; n < 6; ++n) {
        int m = m0 + n * 16 + ln;
        #pragma unroll
        for (int r = 0; r < 4; ++r) {
            int i = i0 + wid * 16 + kl * 4 + r;
            S1[(((size_t)kk * 192 + m) << 10) + i] = (_Float16)acc[n][r];
        }
    }
}

// S2[b][k][t][i] = sum_j (1024 A[b][i][j]) S1[k][b*12+t][j]  (f32 out). grid 256
__global__ __launch_bounds__(256) void k_s2b(const float* __restrict__ A,
                                             const _Float16* __restrict__ S1,
                                             float* __restrict__ S2) {
    int bx = blockIdx.x; int it = bx & 15, b = bx >> 4; int i0 = it * 64;
    __shared__ _Float16 sA[64][72], sB[48][72];
    int tid = threadIdx.x, wid = tid >> 6, ln = tid & 15, kl = (tid & 63) >> 4;
    const float* Ab = A + (size_t)b * N_ * N_;
    f32x4 acc[3];
    #pragma unroll
    for (int n = 0; n < 3; ++n) acc[n] = (f32x4){0.f, 0.f, 0.f, 0.f};
    for (int kc = 0; kc < N_; kc += 64) {
        #pragma unroll
        for (int it2 = 0; it2 < 4; ++it2) {
            int idx = it2 * 256 + tid; int row = idx >> 4, c4 = (idx & 15) * 4;
            float4 a4 = *(const float4*)&Ab[(size_t)(i0 + row) * N_ + kc + c4];
            f16x4 hv = {(_Float16)(a4.x * 1024.f), (_Float16)(a4.y * 1024.f),
                        (_Float16)(a4.z * 1024.f), (_Float16)(a4.w * 1024.f)};
            *(f16x4*)&sA[row][c4] = hv;
        }
        for (int idx = tid; idx < 288; idx += 256) {
            int row = idx >> 3, c8 = (idx & 7) * 8;
            int kq = row / 12, tq = row - kq * 12;
            *(uint4*)&sB[row][c8] = *(const uint4*)&S1[(((size_t)kq * 192 + b * T_ + tq) << 10) + kc + c8];
        }
        __syncthreads();
        #pragma unroll
        for (int ks = 0; ks < 4; ++ks) {
            int ko = ks * 16 + kl * 4;
            f16x4 a = *(const f16x4*)&sA[wid * 16 + ln][ko];
            #pragma unroll
            for (int n = 0; n < 3; ++n) {
                f16x4 b = *(const f16x4*)&sB[n * 16 + ln][ko];
                acc[n] = __builtin_amdgcn_mfma_f32_16x16x16f16(a, b, acc[n], 0, 0, 0);
            }
        }
        __syncthreads();
    }
    #pragma unroll
    for (int n = 0; n < 3; ++n) {
        int col = n * 16 + ln;
        if (col < 36) {
            int kq = col / 12, tq = col - kq * 12;
            #pragma unroll
            for (int r = 0; r < 4; ++r) {
                int i = i0 + wid * 16 + kl * 4 + r;
                S2[(((size_t)(b * 3 + kq) * T_ + tq) << 10) + i] = acc[n][r];
            }
        }
    }
}

// Stage 1: Yt[b][kk*64+c][i] = sum_j Ht[b][c][j] G[kk][i][j]. grid 768: (kk*16+it)*16+b
__global__ __launch_bounds__(256) void k_gh2(const float* __restrict__ G,
                                             const _Float16* __restrict__ Ht,
                                             _Float16* __restrict__ Yt) {
    int bx = blockIdx.x;
    int b = bx & 15, rest = bx >> 4;
    int it = rest & 15, kk = rest >> 4;
    int i0 = it * 64;
    __shared__ _Float16 sA[64][72], sB[64][72];
    int tid = threadIdx.x, wid = tid >> 6, ln = tid & 15, kl = (tid & 63) >> 4;
    const float* Gk = G + (size_t)kk * N_ * N_;
    const _Float16* Hb = Ht + ((size_t)b << 16);
    f32x4 acc[4];
    #pragma unroll
    for (int m = 0; m < 4; ++m) acc[m] = (f32x4){0.f, 0.f, 0.f, 0.f};
    for (int kc = 0; kc < N_; kc += 64) {
        #pragma unroll
        for (int it2 = 0; it2 < 2; ++it2) {          // Ht: 64x64 halves direct copy
            int idx = it2 * 256 + tid; int row = idx >> 3, c8 = (idx & 7) * 8;
            *(uint4*)&sA[row][c8] = *(const uint4*)&Hb[((size_t)row << 10) + kc + c8];
        }
        #pragma unroll
        for (int it2 = 0; it2 < 4; ++it2) {          // G: 64x64 f32 -> f16
            int idx = it2 * 256 + tid; int row = idx >> 4, c4 = (idx & 15) * 4;
            float4 g = *(const float4*)&Gk[(size_t)(i0 + row) * N_ + kc + c4];
            f16x4 hv = {(_Float16)g.x, (_Float16)g.y, (_Float16)g.z, (_Float16)g.w};
            *(f16x4*)&sB[row][c4] = hv;
        }
        __syncthreads();
        #pragma unroll
        for (int ks = 0; ks < 4; ++ks) {
            int ko = ks * 16 + kl * 4;
            f16x4 bfr = *(const f16x4*)&sB[wid * 16 + ln][ko];
            #pragma unroll
            for (int m = 0; m < 4; ++m) {
                f16x4 a = *(const f16x4*)&sA[m * 16 + ln][ko];
                acc[m] = __builtin_amdgcn_mfma_f32_16x16x16f16(a, bfr, acc[m], 0, 0, 0);
            }
        }
        __syncthreads();
    }
    int i = i0 + wid * 16 + ln;
    #pragma unroll
    for (int m = 0; m < 4; ++m)
        #pragma unroll
        for (int r = 0; r < 4; ++r) {
            int c = m * 16 + kl * 4 + r;
            Yt[(((size_t)b * 192 + kk * 64 + c) << 10) + i] = (_Float16)acc[m][r];
        }
}

// Stage 2: Zf[b][i][c] = sum_j (1024 A[b][i][j]) Yt[b][c][j]  (f16 out). grid 512
__global__ __launch_bounds__(256) void k_az2(const float* __restrict__ A,
                                             const _Float16* __restrict__ Yt,
                                             _Float16* __restrict__ Zf) {
    int bx = blockIdx.x;
    int nh = bx & 1, it = (bx >> 1) & 15, b = bx >> 5;
    int i0 = it * 64, c0 = nh * 96;
    __shared__ _Float16 sA[64][72], sB[96][72];
    int tid = threadIdx.x, wid = tid >> 6, ln = tid & 15, kl = (tid & 63) >> 4;
    const float* Ab = A + (size_t)b * N_ * N_;
    const _Float16* Yb = Yt + (((size_t)b * 192 + c0) << 10);
    f32x4 acc[6];
    #pragma unroll
    for (int n = 0; n < 6; ++n) acc[n] = (f32x4){0.f, 0.f, 0.f, 0.f};
    for (int kc = 0; kc < N_; kc += 64) {
        #pragma unroll
        for (int it2 = 0; it2 < 4; ++it2) {
            int idx = it2 * 256 + tid; int row = idx >> 4, c4 = (idx & 15) * 4;
            float4 a4 = *(const float4*)&Ab[(size_t)(i0 + row) * N_ + kc + c4];
            f16x4 hv = {(_Float16)(a4.x * 1024.f), (_Float16)(a4.y * 1024.f),
                        (_Float16)(a4.z * 1024.f), (_Float16)(a4.w * 1024.f)};
            *(f16x4*)&sA[row][c4] = hv;
        }
        #pragma unroll
        for (int it2 = 0; it2 < 3; ++it2) {
            int idx = it2 * 256 + tid; int row = idx >> 3, c8 = (idx & 7) * 8;
            *(uint4*)&sB[row][c8] = *(const uint4*)&Yb[((size_t)row << 10) + kc + c8];
        }
        __syncthreads();
        #pragma unroll
        for (int ks = 0; ks < 4; ++ks) {
            int ko = ks * 16 + kl * 4;
            f16x4 a = *(const f16x4*)&sA[wid * 16 + ln][ko];
            #pragma unroll
            for (int n = 0; n < 6; ++n) {
                f16x4 b = *(const f16x4*)&sB[n * 16 + ln][ko];
                acc[n] = __builtin_amdgcn_mfma_f32_16x16x16f16(a, b, acc[n], 0, 0, 0);
            }
        }
        __syncthreads();
    }
    #pragma unroll
    for (int n = 0; n < 6; ++n) {
        int c = c0 + n * 16 + ln;
        #pragma unroll
        for (int r = 0; r < 4; ++r) {
            int i = i0 + wid * 16 + kl * 4 + r;
            Zf[((size_t)((b << 10) + i)) * 192 + c] = (_Float16)acc[n][r];
        }
    }
}

// gate epilogue via MFMA: pre = Z@wghT^T + xt + bias; z->zb; r*h -> Ht. grid 256
__global__ __launch_bounds__(256) void k_zrm(const _Float16* __restrict__ Zf,
                                             const _Float16* __restrict__ wghT,
                                             const float* __restrict__ wx,
                                             const float* __restrict__ bg,
                                             const float* __restrict__ S2,
                                             const float* __restrict__ h,
                                             float* __restrict__ zb,
                                             _Float16* __restrict__ Ht, int t) {
    int bx = blockIdx.x; int it = bx & 15, b = bx >> 4; int i0 = it * 64;
    __shared__ _Float16 sZ[64][200];
    __shared__ _Float16 sW[128][72];
    __shared__ float sS2[3][64];
    __shared__ float sWX[3][128];
    __shared__ float sBias[128];
    int tid = threadIdx.x, wid = tid >> 6, ln = tid & 15, kl = (tid & 63) >> 4;
    #pragma unroll
    for (int it2 = 0; it2 < 6; ++it2) {
        int idx = it2 * 256 + tid; int row = idx / 24, c8 = (idx % 24) * 8;
        *(uint4*)&sZ[row][c8] = *(const uint4*)&Zf[((size_t)((b << 10) + i0 + row)) * 192 + c8];
    }
    if (tid < 192) { int k = tid >> 6, ii = tid & 63; sS2[k][ii] = S2[(((size_t)(b * 3 + k) * T_ + t) << 10) + i0 + ii]; }
    for (int q = tid; q < 384; q += 256) sWX[q >> 7][q & 127] = wx[q];
    if (tid < 128) sBias[tid] = bg[tid];
    f32x4 acc[4][2];
    #pragma unroll
    for (int m = 0; m < 4; ++m)
        #pragma unroll
        for (int n = 0; n < 2; ++n) acc[m][n] = (f32x4){0.f, 0.f, 0.f, 0.f};
    for (int kc = 0; kc < 192; kc += 64) {
        #pragma unroll
        for (int it2 = 0; it2 < 4; ++it2) {
            int idx = it2 * 256 + tid; int row = idx >> 3, c8 = (idx & 7) * 8;
            *(uint4*)&sW[row][c8] = *(const uint4*)&wghT[(size_t)row * 192 + kc + c8];
        }
        __syncthreads();
        #pragma unroll
        for (int ks = 0; ks < 4; ++ks) {
            int ko = ks * 16 + kl * 4;
            f16x4 a[4], bb[2];
            #pragma unroll
            for (int m = 0; m < 4; ++m) a[m] = *(const f16x4*)&sZ[m * 16 + ln][kc + ko];
            #pragma unroll
            for (int n = 0; n < 2; ++n) bb[n] = *(const f16x4*)&sW[wid * 32 + n * 16 + ln][ko];
            #pragma unroll
            for (int m = 0; m < 4; ++m)
                #pragma unroll
                for (int n = 0; n < 2; ++n)
                    acc[m][n] = __builtin_amdgcn_mfma_f32_16x16x16f16(a[m], bb[n], acc[m][n], 0, 0, 0);
        }
        __syncthreads();
    }
    #pragma unroll
    for (int n = 0; n < 2; ++n) {
        int o = wid * 32 + n * 16 + ln;
        float wx0 = sWX[0][o], wx1 = sWX[1][o], wx2 = sWX[2][o], bias = sBias[o];
        if (o < H_) {
            #pragma unroll
            for (int m = 0; m < 4; ++m)
                #pragma unroll
                for (int r = 0; r < 4; ++r) {
                    int il = m * 16 + kl * 4 + r;
                    float pre = acc[m][n][r] + wx0 * sS2[0][il] + wx1 * sS2[1][il] + wx2 * sS2[2][il] + bias;
                    float v = 1.0f / (1.0f + expf(-pre));
                    zb[((size_t)((b << 10) + i0 + il)) * H_ + o] = v;
                }
        } else {
            int c = o - H_;
            #pragma unroll
            for (int m = 0; m < 4; ++m) {
                alignas(8) _Float16 hb[4];
                #pragma unroll
                for (int r = 0; r < 4; ++r) {
                    int il = m * 16 + kl * 4 + r;
                    float pre = acc[m][n][r] + wx0 * sS2[0][il] + wx1 * sS2[1][il] + wx2 * sS2[2][il] + bias;
                    float v = 1.0f / (1.0f + expf(-pre));
                    hb[r] = (_Float16)(v * h[((size_t)((b << 10) + i0 + il)) * H_ + c]);
                }
                *(f16x4*)&Ht[(((size_t)(b * 64 + c)) << 10) + i0 + m * 16 + kl * 4] = *(f16x4*)&hb[0];
            }
        }
    }
}

// update epilogue via MFMA: hc = tanh(...); h = z*hc + (1-z)h; write h f32 + Ht f16. grid 256
__global__ __launch_bounds__(256) void k_updm(const _Float16* __restrict__ Zf,
                                              const _Float16* __restrict__ wuhT,
                                              const float* __restrict__ wx,
                                              const float* __restrict__ bu,
                                              const float* __restrict__ S2,
                                              const float* __restrict__ zb,
                                              float* __restrict__ h,
                                              _Float16* __restrict__ Ht, int t) {
    int bx = blockIdx.x; int it = bx & 15, b = bx >> 4; int i0 = it * 64;
    __shared__ _Float16 sZ[64][200];
    __shared__ _Float16 sW[64][72];
    __shared__ float sS2[3][64];
    __shared__ float sWX[3][64];
    __shared__ float sBias[64];
    int tid = threadIdx.x, wid = tid >> 6, ln = tid & 15, kl = (tid & 63) >> 4;
    #pragma unroll
    for (int it2 = 0; it2 < 6; ++it2) {
        int idx = it2 * 256 + tid; int row = idx / 24, c8 = (idx % 24) * 8;
        *(uint4*)&sZ[row][c8] = *(const uint4*)&Zf[((size_t)((b << 10) + i0 + row)) * 192 + c8];
    }
    if (tid < 192) { int k = tid >> 6, ii = tid & 63; sS2[k][ii] = S2[(((size_t)(b * 3 + k) * T_ + t) << 10) + i0 + ii]; }
    if (tid < 192) sWX[tid / 64][tid % 64] = wx[384 + tid];
    if (tid < 64) sBias[tid] = bu[tid];
    f32x4 acc[4];
    #pragma unroll
    for (int m = 0; m < 4; ++m) acc[m] = (f32x4){0.f, 0.f, 0.f, 0.f};
    for (int kc = 0; kc < 192; kc += 64) {
        #pragma unroll
        for (int it2 = 0; it2 < 2; ++it2) {
            int idx = it2 * 256 + tid; int row = idx >> 3, c8 = (idx & 7) * 8;
            *(uint4*)&sW[row][c8] = *(const uint4*)&wuhT[(size_t)row * 192 + kc + c8];
        }
        __syncthreads();
        #pragma unroll
        for (int ks = 0; ks < 4; ++ks) {
            int ko = ks * 16 + kl * 4;
            f16x4 bb = *(const f16x4*)&sW[wid * 16 + ln][ko];
            #pragma unroll
            for (int m = 0; m < 4; ++m) {
                f16x4 a = *(const f16x4*)&sZ[m * 16 + ln][kc + ko];
                acc[m] = __builtin_amdgcn_mfma_f32_16x16x16f16(a, bb, acc[m], 0, 0, 0);
            }
        }
        __syncthreads();
    }
    int o = wid * 16 + ln;
    float wx0 = sWX[0][o], wx1 = sWX[1][o], wx2 = sWX[2][o], bias = sBias[o];
    #pragma unroll
    for (int m = 0; m < 4; ++m) {
        alignas(8) _Float16 hb[4];
        #pragma unroll
        for (int r = 0; r < 4; ++r) {
            int il = m * 16 + kl * 4 + r;
            float pre = acc[m][r] + wx0 * sS2[0][il] + wx1 * sS2[1][il] + wx2 * sS2[2][il] + bias;
            float hc = tanhf(pre);
            size_t gi = ((size_t)((b << 10) + i0 + il)) * H_ + o;
            float z = zb[gi], hold = h[gi];
            float hn = z * hc + (1.0f - z) * hold;
            h[gi] = hn;
            hb[r] = (_Float16)hn;
        }
        *(f16x4*)&Ht[(((size_t)(b * 64 + o)) << 10) + i0 + m * 16 + kl * 4] = *(f16x4*)&hb[0];
    }
}

// out[(b*12+tt)*1024 + i] = h[b][i][:] @ W_dec[:,tt] + b_dec[tt]
__global__ __launch_bounds__(256) void k_dec(const float* __restrict__ h,
                                             const float* __restrict__ Wd,
                                             const float* __restrict__ bd,
                                             float* __restrict__ out) {
    int bx = blockIdx.x;
    int b = bx >> 4, it = bx & 15; int i0 = it * 64;
    __shared__ float hs[64][65];
    __shared__ float Wds[64][12];
    __shared__ float bds[12];
    int tid = threadIdx.x;
    for (int idx = tid; idx < 4096; idx += 256) {
        int r = idx >> 6, c = idx & 63;
        hs[r][c] = h[(size_t)(b * N_ + i0 + r) * H_ + c];
    }
    for (int idx = tid; idx < 768; idx += 256)
        Wds[idx / 12][idx % 12] = Wd[idx];
    if (tid < 12) bds[tid] = bd[tid];
    __syncthreads();
    for (int oidx = tid; oidx < 768; oidx += 256) {
        int i = oidx & 63, tt = oidx >> 6;
        float acc = bds[tt];
        #pragma unroll
        for (int c = 0; c < 64; ++c) acc += hs[i][c] * Wds[c][tt];
        out[(size_t)(b * T_ + tt) * N_ + i0 + i] = acc;
    }
}

extern "C" void kernel_launch(void* const* d_in, const int* in_sizes, int n_in,
                              void* d_out, int out_size, void* d_ws, size_t ws_size,
                              hipStream_t stream) {
    const float* x  = (const float*)d_in[0];
    const float* G  = (const float*)d_in[1];
    const float* A  = (const float*)d_in[2];
    const float* Wg = (const float*)d_in[3];
    const float* bg = (const float*)d_in[4];
    const float* Wu = (const float*)d_in[5];
    const float* bu = (const float*)d_in[6];
    const float* Wd = (const float*)d_in[7];
    const float* bd = (const float*)d_in[8];
    float* out = (float*)d_out;
    float* ws  = (float*)d_ws;

    float* h   = ws + OFF_H;
    float* zb  = ws + OFF_ZB;
    float* S2  = ws + OFF_S2;
    float* wxb = ws + OFF_WX;
    _Float16* Zf   = (_Float16*)(ws + OFF_ZF);
    _Float16* Ht   = (_Float16*)(ws + OFF_HT);
    _Float16* Yt   = (_Float16*)(ws + OFF_YT);
    _Float16* S1   = (_Float16*)(ws + OFF_S1);
    _Float16* wghT = (_Float16*)(ws + OFF_WGT);
    _Float16* wuhT = (_Float16*)(ws + OFF_WUT);

    hipMemsetAsync(h, 0, (size_t)B_ * N_ * H_ * sizeof(float), stream);
    hipMemsetAsync((void*)Ht, 0, (size_t)B_ * N_ * H_ * sizeof(_Float16), stream);
    k_repack<<<147, 256, 0, stream>>>(Wg, Wu, wghT, wuhT, wxb);
    k_s1b<<<96, 256, 0, stream>>>(G, x, S1);
    k_s2b<<<256, 256, 0, stream>>>(A, S1, S2);

    for (int t = 0; t < T_; ++t) {
        k_gh2<<<768, 256, 0, stream>>>(G, Ht, Yt);
        k_az2<<<512, 256, 0, stream>>>(A, Yt, Zf);
        k_zrm<<<256, 256, 0, stream>>>(Zf, wghT, wxb, bg, S2, h, zb, Ht, t);
        k_gh2<<<768, 256, 0, stream>>>(G, Ht, Yt);
        k_az2<<<512, 256, 0, stream>>>(A, Yt, Zf);
        k_updm<<<256, 256, 0, stream>>>(Zf, wuhT, wxb, bu, S2, zb, h, Ht, t);
    }
    k_dec<<<256, 256, 0, stream>>>(h, Wd, bd, out);
}

// Round 8
// 1956.566 us; speedup vs baseline: 1.0025x; 1.0025x over previous
//
#include <hip/hip_runtime.h>

#define B_  16
#define T_  12
#define N_  1024
#define K_  3
#define H_  64
#define DIN 65
#define KH  192   // K_*H_
#define OG  128   // 2*H_

typedef _Float16 f16x4 __attribute__((ext_vector_type(4)));
typedef float    f32x4 __attribute__((ext_vector_type(4)));

// ---- workspace offsets (float units), total 6,670,912 f = 26.7 MB ----
static const size_t OFF_H   = 0;          // f32 h   [16][1024][64]
static const size_t OFF_ZB  = 1048576;    // f32 z   [16][1024][64]
static const size_t OFF_S2  = 2097152;    // f32 S2  [16][3][12][1024] (x1024)
static const size_t OFF_ZF  = 2686976;    // f16 Z   [16][1024][192]   (x1024)
static const size_t OFF_HT  = 4259840;    // f16 Ht  [16][64][1024]
static const size_t OFF_YT  = 4784128;    // f16 Yt  [16][192][1024]
static const size_t OFF_S1  = 6356992;    // f16 S1  [3][192][1024]
static const size_t OFF_WGT = 6651904;    // f16 wghT [128][192] (/1024)
static const size_t OFF_WUT = 6664192;    // f16 wuhT [64][192]  (/1024)
static const size_t OFF_WX  = 6670336;    // f32 wx: [0..383]=gate [3][128], [384..575]=upd [3][64] (/1024)

// Repack weights: transposed f16 h-part + f32 x-part rows, all pre-divided by 1024.
__global__ __launch_bounds__(256) void k_repack(const float* __restrict__ Wg,
                                                const float* __restrict__ Wu,
                                                _Float16* __restrict__ wghT,
                                                _Float16* __restrict__ wuhT,
                                                float* __restrict__ wx) {
    const float inv = 1.0f / 1024.0f;
    int idx = blockIdx.x * 256 + threadIdx.x;
    if (idx < 128 * 192) {                       // wghT[o][d], d = k*64+c
        int o = idx / 192, d = idx % 192;
        int k = d / 64, c = d % 64;
        wghT[idx] = (_Float16)(Wg[(size_t)(k * DIN + 1 + c) * OG + o] * inv);
    } else if (idx < 128 * 192 + 64 * 192) {     // wuhT[o][d]
        int j = idx - 128 * 192;
        int o = j / 192, d = j % 192;
        int k = d / 64, c = d % 64;
        wuhT[j] = (_Float16)(Wu[(size_t)(k * DIN + 1 + c) * H_ + o] * inv);
    } else if (idx < 128 * 192 + 64 * 192 + 576) {
        int j = idx - 128 * 192 - 64 * 192;
        if (j < 384) { int k = j >> 7, o = j & 127; wx[j] = Wg[(size_t)(k * DIN) * OG + o] * inv; }
        else { int j2 = j - 384; int k = j2 >> 6, o = j2 & 63; wx[j] = Wu[(size_t)(k * DIN) * H_ + o] * inv; }
    }
}

// S1[k][m][i] = sum_j G[k][i][j] x[m][j]  (f16 out). grid 96: kk*32 + it*2 + nh
__global__ __launch_bounds__(256) void k_s1b(const float* __restrict__ G,
                                             const float* __restrict__ x,
                                             _Float16* __restrict__ S1) {
    int bx = blockIdx.x;
    int nh = bx & 1, it = (bx >> 1) & 15, kk = bx >> 5;
    int i0 = it * 64, m0 = nh * 96;
    __shared__ _Float16 sA[64][72], sB[96][72];
    int tid = threadIdx.x, wid = tid >> 6, ln = tid & 15, kl = (tid & 63) >> 4;
    const float* Gk = G + (size_t)kk * N_ * N_;
    f32x4 acc[6];
    #pragma unroll
    for (int n = 0; n < 6; ++n) acc[n] = (f32x4){0.f, 0.f, 0.f, 0.f};
    for (int kc = 0; kc < N_; kc += 64) {
        #pragma unroll
        for (int it2 = 0; it2 < 4; ++it2) {
            int idx = it2 * 256 + tid; int row = idx >> 4, c4 = (idx & 15) * 4;
            float4 g = *(const float4*)&Gk[(size_t)(i0 + row) * N_ + kc + c4];
            f16x4 hv = {(_Float16)g.x, (_Float16)g.y, (_Float16)g.z, (_Float16)g.w};
            *(f16x4*)&sA[row][c4] = hv;
        }
        #pragma unroll
        for (int it2 = 0; it2 < 6; ++it2) {
            int idx = it2 * 256 + tid; int row = idx >> 4, c4 = (idx & 15) * 4;
            float4 g = *(const float4*)&x[(size_t)(m0 + row) * N_ + kc + c4];
            f16x4 hv = {(_Float16)g.x, (_Float16)g.y, (_Float16)g.z, (_Float16)g.w};
            *(f16x4*)&sB[row][c4] = hv;
        }
        __syncthreads();
        #pragma unroll
        for (int ks = 0; ks < 4; ++ks) {
            int ko = ks * 16 + kl * 4;
            f16x4 a = *(const f16x4*)&sA[wid * 16 + ln][ko];
            #pragma unroll
            for (int n = 0; n < 6; ++n) {
                f16x4 b = *(const f16x4*)&sB[n * 16 + ln][ko];
                acc[n] = __builtin_amdgcn_mfma_f32_16x16x16f16(a, b, acc[n], 0, 0, 0);
            }
        }
        __syncthreads();
    }
    #pragma unroll
    for (int n = 0; n < 6; ++n) {
        int m = m0 + n * 16 + ln;
        #pragma unroll
        for (int r = 0; r < 4; ++r) {
            int i = i0 + wid * 16 + kl * 4 + r;
            S1[(((size_t)kk * 192 + m) << 10) + i] = (_Float16)acc[n][r];
        }
    }
}

// S2[b][k][t][i] = sum_j (1024 A[b][i][j]) S1[k][b*12+t][j]  (f32 out). grid 256
__global__ __launch_bounds__(256) void k_s2b(const float* __restrict__ A,
                                             const _Float16* __restrict__ S1,
                                             float* __restrict__ S2) {
    int bx = blockIdx.x; int it = bx & 15, b = bx >> 4; int i0 = it * 64;
    __shared__ _Float16 sA[64][72], sB[48][72];
    int tid = threadIdx.x, wid = tid >> 6, ln = tid & 15, kl = (tid & 63) >> 4;
    const float* Ab = A + (size_t)b * N_ * N_;
    f32x4 acc[3];
    #pragma unroll
    for (int n = 0; n < 3; ++n) acc[n] = (f32x4){0.f, 0.f, 0.f, 0.f};
    for (int kc = 0; kc < N_; kc += 64) {
        #pragma unroll
        for (int it2 = 0; it2 < 4; ++it2) {
            int idx = it2 * 256 + tid; int row = idx >> 4, c4 = (idx & 15) * 4;
            float4 a4 = *(const float4*)&Ab[(size_t)(i0 + row) * N_ + kc + c4];
            f16x4 hv = {(_Float16)(a4.x * 1024.f), (_Float16)(a4.y * 1024.f),
                        (_Float16)(a4.z * 1024.f), (_Float16)(a4.w * 1024.f)};
            *(f16x4*)&sA[row][c4] = hv;
        }
        for (int idx = tid; idx < 288; idx += 256) {
            int row = idx >> 3, c8 = (idx & 7) * 8;
            int kq = row / 12, tq = row - kq * 12;
            *(uint4*)&sB[row][c8] = *(const uint4*)&S1[(((size_t)kq * 192 + b * T_ + tq) << 10) + kc + c8];
        }
        __syncthreads();
        #pragma unroll
        for (int ks = 0; ks < 4; ++ks) {
            int ko = ks * 16 + kl * 4;
            f16x4 a = *(const f16x4*)&sA[wid * 16 + ln][ko];
            #pragma unroll
            for (int n = 0; n < 3; ++n) {
                f16x4 b = *(const f16x4*)&sB[n * 16 + ln][ko];
                acc[n] = __builtin_amdgcn_mfma_f32_16x16x16f16(a, b, acc[n], 0, 0, 0);
            }
        }
        __syncthreads();
    }
    #pragma unroll
    for (int n = 0; n < 3; ++n) {
        int col = n * 16 + ln;
        if (col < 36) {
            int kq = col / 12, tq = col - kq * 12;
            #pragma unroll
            for (int r = 0; r < 4; ++r) {
                int i = i0 + wid * 16 + kl * 4 + r;
                S2[(((size_t)(b * 3 + kq) * T_ + tq) << 10) + i] = acc[n][r];
            }
        }
    }
}

// Stage 1: Yt[b][kk*64+c][i] = sum_j Ht[b][c][j] G[kk][i][j]. grid 768: (kk*16+it)*16+b
__global__ __launch_bounds__(256) void k_gh2(const float* __restrict__ G,
                                             const _Float16* __restrict__ Ht,
                                             _Float16* __restrict__ Yt) {
    int bx = blockIdx.x;
    int b = bx & 15, rest = bx >> 4;
    int it = rest & 15, kk = rest >> 4;
    int i0 = it * 64;
    __shared__ _Float16 sA[64][72], sB[64][72];
    int tid = threadIdx.x, wid = tid >> 6, ln = tid & 15, kl = (tid & 63) >> 4;
    const float* Gk = G + (size_t)kk * N_ * N_;
    const _Float16* Hb = Ht + ((size_t)b << 16);
    f32x4 acc[4];
    #pragma unroll
    for (int m = 0; m < 4; ++m) acc[m] = (f32x4){0.f, 0.f, 0.f, 0.f};
    for (int kc = 0; kc < N_; kc += 64) {
        #pragma unroll
        for (int it2 = 0; it2 < 2; ++it2) {          // Ht: 64x64 halves direct copy
            int idx = it2 * 256 + tid; int row = idx >> 3, c8 = (idx & 7) * 8;
            *(uint4*)&sA[row][c8] = *(const uint4*)&Hb[((size_t)row << 10) + kc + c8];
        }
        #pragma unroll
        for (int it2 = 0; it2 < 4; ++it2) {          // G: 64x64 f32 -> f16
            int idx = it2 * 256 + tid; int row = idx >> 4, c4 = (idx & 15) * 4;
            float4 g = *(const float4*)&Gk[(size_t)(i0 + row) * N_ + kc + c4];
            f16x4 hv = {(_Float16)g.x, (_Float16)g.y, (_Float16)g.z, (_Float16)g.w};
            *(f16x4*)&sB[row][c4] = hv;
        }
        __syncthreads();
        #pragma unroll
        for (int ks = 0; ks < 4; ++ks) {
            int ko = ks * 16 + kl * 4;
            f16x4 bfr = *(const f16x4*)&sB[wid * 16 + ln][ko];
            #pragma unroll
            for (int m = 0; m < 4; ++m) {
                f16x4 a = *(const f16x4*)&sA[m * 16 + ln][ko];
                acc[m] = __builtin_amdgcn_mfma_f32_16x16x16f16(a, bfr, acc[m], 0, 0, 0);
            }
        }
        __syncthreads();
    }
    int i = i0 + wid * 16 + ln;
    #pragma unroll
    for (int m = 0; m < 4; ++m)
        #pragma unroll
        for (int r = 0; r < 4; ++r) {
            int c = m * 16 + kl * 4 + r;
            Yt[(((size_t)b * 192 + kk * 64 + c) << 10) + i] = (_Float16)acc[m][r];
        }
}

// Stage 2: Zf[b][i][c] = sum_j (1024 A[b][i][j]) Yt[b][c][j]  (f16 out). grid 512
__global__ __launch_bounds__(256) void k_az2(const float* __restrict__ A,
                                             const _Float16* __restrict__ Yt,
                                             _Float16* __restrict__ Zf) {
    int bx = blockIdx.x;
    int nh = bx & 1, it = (bx >> 1) & 15, b = bx >> 5;
    int i0 = it * 64, c0 = nh * 96;
    __shared__ _Float16 sA[64][72], sB[96][72];
    int tid = threadIdx.x, wid = tid >> 6, ln = tid & 15, kl = (tid & 63) >> 4;
    const float* Ab = A + (size_t)b * N_ * N_;
    const _Float16* Yb = Yt + (((size_t)b * 192 + c0) << 10);
    f32x4 acc[6];
    #pragma unroll
    for (int n = 0; n < 6; ++n) acc[n] = (f32x4){0.f, 0.f, 0.f, 0.f};
    for (int kc = 0; kc < N_; kc += 64) {
        #pragma unroll
        for (int it2 = 0; it2 < 4; ++it2) {
            int idx = it2 * 256 + tid; int row = idx >> 4, c4 = (idx & 15) * 4;
            float4 a4 = *(const float4*)&Ab[(size_t)(i0 + row) * N_ + kc + c4];
            f16x4 hv = {(_Float16)(a4.x * 1024.f), (_Float16)(a4.y * 1024.f),
                        (_Float16)(a4.z * 1024.f), (_Float16)(a4.w * 1024.f)};
            *(f16x4*)&sA[row][c4] = hv;
        }
        #pragma unroll
        for (int it2 = 0; it2 < 3; ++it2) {
            int idx = it2 * 256 + tid; int row = idx >> 3, c8 = (idx & 7) * 8;
            *(uint4*)&sB[row][c8] = *(const uint4*)&Yb[((size_t)row << 10) + kc + c8];
        }
        __syncthreads();
        #pragma unroll
        for (int ks = 0; ks < 4; ++ks) {
            int ko = ks * 16 + kl * 4;
            f16x4 a = *(const f16x4*)&sA[wid * 16 + ln][ko];
            #pragma unroll
            for (int n = 0; n < 6; ++n) {
                f16x4 b = *(const f16x4*)&sB[n * 16 + ln][ko];
                acc[n] = __builtin_amdgcn_mfma_f32_16x16x16f16(a, b, acc[n], 0, 0, 0);
            }
        }
        __syncthreads();
    }
    #pragma unroll
    for (int n = 0; n < 6; ++n) {
        int c = c0 + n * 16 + ln;
        #pragma unroll
        for (int r = 0; r < 4; ++r) {
            int i = i0 + wid * 16 + kl * 4 + r;
            Zf[((size_t)((b << 10) + i)) * 192 + c] = (_Float16)acc[n][r];
        }
    }
}

// gate epilogue via MFMA: pre = Z@wghT^T + xt + bias; z->zb; r*h -> Ht. grid 256
__global__ __launch_bounds__(256) void k_zrm(const _Float16* __restrict__ Zf,
                                             const _Float16* __restrict__ wghT,
                                             const float* __restrict__ wx,
                                             const float* __restrict__ bg,
                                             const float* __restrict__ S2,
                                             const float* __restrict__ h,
                                             float* __restrict__ zb,
                                             _Float16* __restrict__ Ht, int t) {
    int bx = blockIdx.x; int it = bx & 15, b = bx >> 4; int i0 = it * 64;
    __shared__ _Float16 sZ[64][200];
    __shared__ _Float16 sW[128][72];
    __shared__ float sS2[3][64];
    __shared__ float sWX[3][128];
    __shared__ float sBias[128];
    int tid = threadIdx.x, wid = tid >> 6, ln = tid & 15, kl = (tid & 63) >> 4;
    #pragma unroll
    for (int it2 = 0; it2 < 6; ++it2) {
        int idx = it2 * 256 + tid; int row = idx / 24, c8 = (idx % 24) * 8;
        *(uint4*)&sZ[row][c8] = *(const uint4*)&Zf[((size_t)((b << 10) + i0 + row)) * 192 + c8];
    }
    if (tid < 192) { int k = tid >> 6, ii = tid & 63; sS2[k][ii] = S2[(((size_t)(b * 3 + k) * T_ + t) << 10) + i0 + ii]; }
    for (int q = tid; q < 384; q += 256) sWX[q >> 7][q & 127] = wx[q];
    if (tid < 128) sBias[tid] = bg[tid];
    f32x4 acc[4][2];
    #pragma unroll
    for (int m = 0; m < 4; ++m)
        #pragma unroll
        for (int n = 0; n < 2; ++n) acc[m][n] = (f32x4){0.f, 0.f, 0.f, 0.f};
    for (int kc = 0; kc < 192; kc += 64) {
        #pragma unroll
        for (int it2 = 0; it2 < 4; ++it2) {
            int idx = it2 * 256 + tid; int row = idx >> 3, c8 = (idx & 7) * 8;
            *(uint4*)&sW[row][c8] = *(const uint4*)&wghT[(size_t)row * 192 + kc + c8];
        }
        __syncthreads();
        #pragma unroll
        for (int ks = 0; ks < 4; ++ks) {
            int ko = ks * 16 + kl * 4;
            f16x4 a[4], bb[2];
            #pragma unroll
            for (int m = 0; m < 4; ++m) a[m] = *(const f16x4*)&sZ[m * 16 + ln][kc + ko];
            #pragma unroll
            for (int n = 0; n < 2; ++n) bb[n] = *(const f16x4*)&sW[wid * 32 + n * 16 + ln][ko];
            #pragma unroll
            for (int m = 0; m < 4; ++m)
                #pragma unroll
                for (int n = 0; n < 2; ++n)
                    acc[m][n] = __builtin_amdgcn_mfma_f32_16x16x16f16(a[m], bb[n], acc[m][n], 0, 0, 0);
        }
        __syncthreads();
    }
    #pragma unroll
    for (int n = 0; n < 2; ++n) {
        int o = wid * 32 + n * 16 + ln;
        float wx0 = sWX[0][o], wx1 = sWX[1][o], wx2 = sWX[2][o], bias = sBias[o];
        if (o < H_) {
            #pragma unroll
            for (int m = 0; m < 4; ++m)
                #pragma unroll
                for (int r = 0; r < 4; ++r) {
                    int il = m * 16 + kl * 4 + r;
                    float pre = acc[m][n][r] + wx0 * sS2[0][il] + wx1 * sS2[1][il] + wx2 * sS2[2][il] + bias;
                    float v = 1.0f / (1.0f + expf(-pre));
                    zb[((size_t)((b << 10) + i0 + il)) * H_ + o] = v;
                }
        } else {
            int c = o - H_;
            #pragma unroll
            for (int m = 0; m < 4; ++m) {
                alignas(8) _Float16 hb[4];
                #pragma unroll
                for (int r = 0; r < 4; ++r) {
                    int il = m * 16 + kl * 4 + r;
                    float pre = acc[m][n][r] + wx0 * sS2[0][il] + wx1 * sS2[1][il] + wx2 * sS2[2][il] + bias;
                    float v = 1.0f / (1.0f + expf(-pre));
                    hb[r] = (_Float16)(v * h[((size_t)((b << 10) + i0 + il)) * H_ + c]);
                }
                *(f16x4*)&Ht[(((size_t)(b * 64 + c)) << 10) + i0 + m * 16 + kl * 4] = *(f16x4*)&hb[0];
            }
        }
    }
}

// update epilogue via MFMA: hc = tanh(...); h = z*hc + (1-z)h; write h f32 + Ht f16. grid 256
__global__ __launch_bounds__(256) void k_updm(const _Float16* __restrict__ Zf,
                                              const _Float16* __restrict__ wuhT,
                                              const float* __restrict__ wx,
                                              const float* __restrict__ bu,
                                              const float* __restrict__ S2,
                                              const float* __restrict__ zb,
                                              float* __restrict__ h,
                                              _Float16* __restrict__ Ht, int t) {
    int bx = blockIdx.x; int it = bx & 15, b = bx >> 4; int i0 = it * 64;
    __shared__ _Float16 sZ[64][200];
    __shared__ _Float16 sW[64][72];
    __shared__ float sS2[3][64];
    __shared__ float sWX[3][64];
    __shared__ float sBias[64];
    int tid = threadIdx.x, wid = tid >> 6, ln = tid & 15, kl = (tid & 63) >> 4;
    #pragma unroll
    for (int it2 = 0; it2 < 6; ++it2) {
        int idx = it2 * 256 + tid; int row = idx / 24, c8 = (idx % 24) * 8;
        *(uint4*)&sZ[row][c8] = *(const uint4*)&Zf[((size_t)((b << 10) + i0 + row)) * 192 + c8];
    }
    if (tid < 192) { int k = tid >> 6, ii = tid & 63; sS2[k][ii] = S2[(((size_t)(b * 3 + k) * T_ + t) << 10) + i0 + ii]; }
    if (tid < 192) sWX[tid / 64][tid % 64] = wx[384 + tid];
    if (tid < 64) sBias[tid] = bu[tid];
    f32x4 acc[4];
    #pragma unroll
    for (int m = 0; m < 4; ++m) acc[m] = (f32x4){0.f, 0.f, 0.f, 0.f};
    for (int kc = 0; kc < 192; kc += 64) {
        #pragma unroll
        for (int it2 = 0; it2 < 2; ++it2) {
            int idx = it2 * 256 + tid; int row = idx >> 3, c8 = (idx & 7) * 8;
            *(uint4*)&sW[row][c8] = *(const uint4*)&wuhT[(size_t)row * 192 + kc + c8];
        }
        __syncthreads();
        #pragma unroll
        for (int ks = 0; ks < 4; ++ks) {
            int ko = ks * 16 + kl * 4;
            f16x4 bb = *(const f16x4*)&sW[wid * 16 + ln][ko];
            #pragma unroll
            for (int m = 0; m < 4; ++m) {
                f16x4 a = *(const f16x4*)&sZ[m * 16 + ln][kc + ko];
                acc[m] = __builtin_amdgcn_mfma_f32_16x16x16f16(a, bb, acc[m], 0, 0, 0);
            }
        }
        __syncthreads();
    }
    int o = wid * 16 + ln;
    float wx0 = sWX[0][o], wx1 = sWX[1][o], wx2 = sWX[2][o], bias = sBias[o];
    #pragma unroll
    for (int m = 0; m < 4; ++m) {
        alignas(8) _Float16 hb[4];
        #pragma unroll
        for (int r = 0; r < 4; ++r) {
            int il = m * 16 + kl * 4 + r;
            float pre = acc[m][r] + wx0 * sS2[0][il] + wx1 * sS2[1][il] + wx2 * sS2[2][il] + bias;
            float hc = tanhf(pre);
            size_t gi = ((size_t)((b << 10) + i0 + il)) * H_ + o;
            float z = zb[gi], hold = h[gi];
            float hn = z * hc + (1.0f - z) * hold;
            h[gi] = hn;
            hb[r] = (_Float16)hn;
        }
        *(f16x4*)&Ht[(((size_t)(b * 64 + o)) << 10) + i0 + m * 16 + kl * 4] = *(f16x4*)&hb[0];
    }
}

// out[(b*12+tt)*1024 + i] = h[b][i][:] @ W_dec[:,tt] + b_dec[tt]
__global__ __launch_bounds__(256) void k_dec(const float* __restrict__ h,
                                             const float* __restrict__ Wd,
                                             const float* __restrict__ bd,
                                             float* __restrict__ out) {
    int bx = blockIdx.x;
    int b = bx >> 4, it = bx & 15; int i0 = it * 64;
    __shared__ float hs[64][65];
    __shared__ float Wds[64][12];
    __shared__ float bds[12];
    int tid = threadIdx.x;
    for (int idx = tid; idx < 4096; idx += 256) {
        int r = idx >> 6, c = idx & 63;
        hs[r][c] = h[(size_t)(b * N_ + i0 + r) * H_ + c];
    }
    for (int idx = tid; idx < 768; idx += 256)
        Wds[idx / 12][idx % 12] = Wd[idx];
    if (tid < 12) bds[tid] = bd[tid];
    __syncthreads();
    for (int oidx = tid; oidx < 768; oidx += 256) {
        int i = oidx & 63, tt = oidx >> 6;
        float acc = bds[tt];
        #pragma unroll
        for (int c = 0; c < 64; ++c) acc += hs[i][c] * Wds[c][tt];
        out[(size_t)(b * T_ + tt) * N_ + i0 + i] = acc;
    }
}

extern "C" void kernel_launch(void* const* d_in, const int* in_sizes, int n_in,
                              void* d_out, int out_size, void* d_ws, size_t ws_size,
                              hipStream_t stream) {
    const float* x  = (const float*)d_in[0];
    const float* G  = (const float*)d_in[1];
    const float* A  = (const float*)d_in[2];
    const float* Wg = (const float*)d_in[3];
    const float* bg = (const float*)d_in[4];
    const float* Wu = (const float*)d_in[5];
    const float* bu = (const float*)d_in[6];
    const float* Wd = (const float*)d_in[7];
    const float* bd = (const float*)d_in[8];
    float* out = (float*)d_out;
    float* ws  = (float*)d_ws;

    float* h   = ws + OFF_H;
    float* zb  = ws + OFF_ZB;
    float* S2  = ws + OFF_S2;
    float* wxb = ws + OFF_WX;
    _Float16* Zf   = (_Float16*)(ws + OFF_ZF);
    _Float16* Ht   = (_Float16*)(ws + OFF_HT);
    _Float16* Yt   = (_Float16*)(ws + OFF_YT);
    _Float16* S1   = (_Float16*)(ws + OFF_S1);
    _Float16* wghT = (_Float16*)(ws + OFF_WGT);
    _Float16* wuhT = (_Float16*)(ws + OFF_WUT);

    hipMemsetAsync(h, 0, (size_t)B_ * N_ * H_ * sizeof(float), stream);
    hipMemsetAsync((void*)Ht, 0, (size_t)B_ * N_ * H_ * sizeof(_Float16), stream);
    k_repack<<<147, 256, 0, stream>>>(Wg, Wu, wghT, wuhT, wxb);
    k_s1b<<<96, 256, 0, stream>>>(G, x, S1);
    k_s2b<<<256, 256, 0, stream>>>(A, S1, S2);

    for (int t = 0; t < T_; ++t) {
        k_gh2<<<768, 256, 0, stream>>>(G, Ht, Yt);
        k_az2<<<512, 256, 0, stream>>>(A, Yt, Zf);
        k_zrm<<<256, 256, 0, stream>>>(Zf, wghT, wxb, bg, S2, h, zb, Ht, t);
        k_gh2<<<768, 256, 0, stream>>>(G, Ht, Yt);
        k_az2<<<512, 256, 0, stream>>>(A, Yt, Zf);
        k_updm<<<256, 256, 0, stream>>>(Zf, wuhT, wxb, bu, S2, zb, h, Ht, t);
    }
    k_dec<<<256, 256, 0, stream>>>(h, Wd, bd, out);
}

// Round 9
// 1294.689 us; speedup vs baseline: 1.5151x; 1.5112x over previous
//
#include <hip/hip_runtime.h>

#define B_  16
#define T_  12
#define N_  1024
#define K_  3
#define H_  64
#define DIN 65
#define KH  192   // K_*H_
#define OG  128   // 2*H_

typedef _Float16 f16x4 __attribute__((ext_vector_type(4)));
typedef _Float16 f16x8 __attribute__((ext_vector_type(8)));
typedef float    f32x4 __attribute__((ext_vector_type(4)));

// ---- workspace offsets (float units), total 8,243,776 f = 33.0 MB (< proven 42.6 MB) ----
static const size_t OFF_H   = 0;          // f32 h   [16][1024][64]
static const size_t OFF_ZB  = 1048576;    // f32 z   [16][1024][64]
static const size_t OFF_S2  = 2097152;    // f32 S2  [16][3][12][1024] (x1024)
static const size_t OFF_ZF  = 2686976;    // f16 Z   [16][1024][192]   (x1024)
static const size_t OFF_HT  = 4259840;    // f16 Ht  [16][64][1024]
static const size_t OFF_YT  = 4784128;    // f16 Yt  [16][192][1024]
static const size_t OFF_S1  = 6356992;    // f16 S1  [3][192][1024]
static const size_t OFF_WGT = 6651904;    // f16 wghT [128][192] (/1024)
static const size_t OFF_WUT = 6664192;    // f16 wuhT [64][192]  (/1024)
static const size_t OFF_WX  = 6670336;    // f32 wx (576)
static const size_t OFF_GF  = 6670912;    // f16 Gf16 [3][1024][1024] (1,572,864 f)

// Repack weights: transposed f16 h-part + f32 x-part rows, all pre-divided by 1024.
__global__ __launch_bounds__(256) void k_repack(const float* __restrict__ Wg,
                                                const float* __restrict__ Wu,
                                                _Float16* __restrict__ wghT,
                                                _Float16* __restrict__ wuhT,
                                                float* __restrict__ wx) {
    const float inv = 1.0f / 1024.0f;
    int idx = blockIdx.x * 256 + threadIdx.x;
    if (idx < 128 * 192) {
        int o = idx / 192, d = idx % 192;
        int k = d / 64, c = d % 64;
        wghT[idx] = (_Float16)(Wg[(size_t)(k * DIN + 1 + c) * OG + o] * inv);
    } else if (idx < 128 * 192 + 64 * 192) {
        int j = idx - 128 * 192;
        int o = j / 192, d = j % 192;
        int k = d / 64, c = d % 64;
        wuhT[j] = (_Float16)(Wu[(size_t)(k * DIN + 1 + c) * H_ + o] * inv);
    } else if (idx < 128 * 192 + 64 * 192 + 576) {
        int j = idx - 128 * 192 - 64 * 192;
        if (j < 384) { int k = j >> 7, o = j & 127; wx[j] = Wg[(size_t)(k * DIN) * OG + o] * inv; }
        else { int j2 = j - 384; int k = j2 >> 6, o = j2 & 63; wx[j] = Wu[(size_t)(k * DIN) * H_ + o] * inv; }
    }
}

// G f32 -> f16, once. grid 1536.
__global__ __launch_bounds__(256) void k_gcvt(const float* __restrict__ G,
                                              _Float16* __restrict__ Gf) {
    size_t idx = ((size_t)blockIdx.x * 256 + threadIdx.x) * 8;
    float4 a = *(const float4*)&G[idx];
    float4 c = *(const float4*)&G[idx + 4];
    f16x8 v = {(_Float16)a.x, (_Float16)a.y, (_Float16)a.z, (_Float16)a.w,
               (_Float16)c.x, (_Float16)c.y, (_Float16)c.z, (_Float16)c.w};
    *(f16x8*)&Gf[idx] = v;
}

// S1[k][m][i] = sum_j G[k][i][j] x[m][j]  (f16 out). grid 96
__global__ __launch_bounds__(256) void k_s1b(const float* __restrict__ G,
                                             const float* __restrict__ x,
                                             _Float16* __restrict__ S1) {
    int bx = blockIdx.x;
    int nh = bx & 1, it = (bx >> 1) & 15, kk = bx >> 5;
    int i0 = it * 64, m0 = nh * 96;
    __shared__ _Float16 sA[64][72], sB[96][72];
    int tid = threadIdx.x, wid = tid >> 6, ln = tid & 15, kl = (tid & 63) >> 4;
    const float* Gk = G + (size_t)kk * N_ * N_;
    f32x4 acc[6];
    #pragma unroll
    for (int n = 0; n < 6; ++n) acc[n] = (f32x4){0.f, 0.f, 0.f, 0.f};
    for (int kc = 0; kc < N_; kc += 64) {
        #pragma unroll
        for (int it2 = 0; it2 < 4; ++it2) {
            int idx = it2 * 256 + tid; int row = idx >> 4, c4 = (idx & 15) * 4;
            float4 g = *(const float4*)&Gk[(size_t)(i0 + row) * N_ + kc + c4];
            f16x4 hv = {(_Float16)g.x, (_Float16)g.y, (_Float16)g.z, (_Float16)g.w};
            *(f16x4*)&sA[row][c4] = hv;
        }
        #pragma unroll
        for (int it2 = 0; it2 < 6; ++it2) {
            int idx = it2 * 256 + tid; int row = idx >> 4, c4 = (idx & 15) * 4;
            float4 g = *(const float4*)&x[(size_t)(m0 + row) * N_ + kc + c4];
            f16x4 hv = {(_Float16)g.x, (_Float16)g.y, (_Float16)g.z, (_Float16)g.w};
            *(f16x4*)&sB[row][c4] = hv;
        }
        __syncthreads();
        #pragma unroll
        for (int ks = 0; ks < 4; ++ks) {
            int ko = ks * 16 + kl * 4;
            f16x4 a = *(const f16x4*)&sA[wid * 16 + ln][ko];
            #pragma unroll
            for (int n = 0; n < 6; ++n) {
                f16x4 b = *(const f16x4*)&sB[n * 16 + ln][ko];
                acc[n] = __builtin_amdgcn_mfma_f32_16x16x16f16(a, b, acc[n], 0, 0, 0);
            }
        }
        __syncthreads();
    }
    #pragma unroll
    for (int n = 0; n < 6; ++n) {
        int m = m0 + n * 16 + ln;
        #pragma unroll
        for (int r = 0; r < 4; ++r) {
            int i = i0 + wid * 16 + kl * 4 + r;
            S1[(((size_t)kk * 192 + m) << 10) + i] = (_Float16)acc[n][r];
        }
    }
}

// S2[b][k][t][i] = sum_j (1024 A[b][i][j]) S1[k][b*12+t][j]  (f32 out). grid 256
__global__ __launch_bounds__(256) void k_s2b(const float* __restrict__ A,
                                             const _Float16* __restrict__ S1,
                                             float* __restrict__ S2) {
    int bx = blockIdx.x; int it = bx & 15, b = bx >> 4; int i0 = it * 64;
    __shared__ _Float16 sA[64][72], sB[48][72];
    int tid = threadIdx.x, wid = tid >> 6, ln = tid & 15, kl = (tid & 63) >> 4;
    const float* Ab = A + (size_t)b * N_ * N_;
    f32x4 acc[3];
    #pragma unroll
    for (int n = 0; n < 3; ++n) acc[n] = (f32x4){0.f, 0.f, 0.f, 0.f};
    for (int kc = 0; kc < N_; kc += 64) {
        #pragma unroll
        for (int it2 = 0; it2 < 4; ++it2) {
            int idx = it2 * 256 + tid; int row = idx >> 4, c4 = (idx & 15) * 4;
            float4 a4 = *(const float4*)&Ab[(size_t)(i0 + row) * N_ + kc + c4];
            f16x4 hv = {(_Float16)(a4.x * 1024.f), (_Float16)(a4.y * 1024.f),
                        (_Float16)(a4.z * 1024.f), (_Float16)(a4.w * 1024.f)};
            *(f16x4*)&sA[row][c4] = hv;
        }
        for (int idx = tid; idx < 288; idx += 256) {
            int row = idx >> 3, c8 = (idx & 7) * 8;
            int kq = row / 12, tq = row - kq * 12;
            *(uint4*)&sB[row][c8] = *(const uint4*)&S1[(((size_t)kq * 192 + b * T_ + tq) << 10) + kc + c8];
        }
        __syncthreads();
        #pragma unroll
        for (int ks = 0; ks < 4; ++ks) {
            int ko = ks * 16 + kl * 4;
            f16x4 a = *(const f16x4*)&sA[wid * 16 + ln][ko];
            #pragma unroll
            for (int n = 0; n < 3; ++n) {
                f16x4 b = *(const f16x4*)&sB[n * 16 + ln][ko];
                acc[n] = __builtin_amdgcn_mfma_f32_16x16x16f16(a, b, acc[n], 0, 0, 0);
            }
        }
        __syncthreads();
    }
    #pragma unroll
    for (int n = 0; n < 3; ++n) {
        int col = n * 16 + ln;
        if (col < 36) {
            int kq = col / 12, tq = col - kq * 12;
            #pragma unroll
            for (int r = 0; r < 4; ++r) {
                int i = i0 + wid * 16 + kl * 4 + r;
                S2[(((size_t)(b * 3 + kq) * T_ + tq) << 10) + i] = acc[n][r];
            }
        }
    }
}

// Stage 1: Yt[b][kk*64+c][i] = sum_j Ht[b][c][j] Gf[kk][i][j].
// x32 MFMA, double-buffered reg-staging, grid 768: bx = (kk*16+it)*16+b
__global__ __launch_bounds__(256) void k_gh2(const _Float16* __restrict__ Gf,
                                             const _Float16* __restrict__ Ht,
                                             _Float16* __restrict__ Yt) {
    int bx = blockIdx.x;
    int b = bx & 15, rest = bx >> 4;
    int it = rest & 15, kk = rest >> 4;
    int i0 = it * 64;
    __shared__ _Float16 sA[2][64][72], sB[2][64][72];
    int tid = threadIdx.x;
    int w = tid >> 6, lane = tid & 63, ln = lane & 15, kg = lane >> 4;
    int mh = (w & 1) * 2, nh = (w >> 1) * 2;
    const _Float16* Hb = Ht + ((size_t)b << 16);
    const _Float16* Gk = Gf + ((size_t)kk << 20) + ((size_t)i0 << 10);
    int srow = tid >> 3, sc8 = (tid & 7) * 8;
    const _Float16* pa0 = Hb + ((size_t)srow << 10) + sc8;
    const _Float16* pa1 = Hb + ((size_t)(srow + 32) << 10) + sc8;
    const _Float16* pb0 = Gk + ((size_t)srow << 10) + sc8;
    const _Float16* pb1 = Gk + ((size_t)(srow + 32) << 10) + sc8;

    f32x4 acc[2][2];
    #pragma unroll
    for (int mi = 0; mi < 2; ++mi)
        #pragma unroll
        for (int ni = 0; ni < 2; ++ni) acc[mi][ni] = (f32x4){0.f, 0.f, 0.f, 0.f};

    f16x8 rA0 = *(const f16x8*)pa0;
    f16x8 rA1 = *(const f16x8*)pa1;
    f16x8 rB0 = *(const f16x8*)pb0;
    f16x8 rB1 = *(const f16x8*)pb1;
    *(f16x8*)&sA[0][srow][sc8] = rA0;
    *(f16x8*)&sA[0][srow + 32][sc8] = rA1;
    *(f16x8*)&sB[0][srow][sc8] = rB0;
    *(f16x8*)&sB[0][srow + 32][sc8] = rB1;
    __syncthreads();

    for (int t = 0; t < 16; ++t) {
        int cur = t & 1;
        if (t < 15) {                       // issue next-chunk loads BEFORE compute
            int kn = (t + 1) * 64;
            rA0 = *(const f16x8*)&pa0[kn];
            rA1 = *(const f16x8*)&pa1[kn];
            rB0 = *(const f16x8*)&pb0[kn];
            rB1 = *(const f16x8*)&pb1[kn];
        }
        #pragma unroll
        for (int ks = 0; ks < 2; ++ks) {
            int ko = ks * 32 + kg * 8;
            f16x8 a0 = *(const f16x8*)&sA[cur][(mh + 0) * 16 + ln][ko];
            f16x8 a1 = *(const f16x8*)&sA[cur][(mh + 1) * 16 + ln][ko];
            f16x8 b0 = *(const f16x8*)&sB[cur][(nh + 0) * 16 + ln][ko];
            f16x8 b1 = *(const f16x8*)&sB[cur][(nh + 1) * 16 + ln][ko];
            acc[0][0] = __builtin_amdgcn_mfma_f32_16x16x32_f16(a0, b0, acc[0][0], 0, 0, 0);
            acc[0][1] = __builtin_amdgcn_mfma_f32_16x16x32_f16(a0, b1, acc[0][1], 0, 0, 0);
            acc[1][0] = __builtin_amdgcn_mfma_f32_16x16x32_f16(a1, b0, acc[1][0], 0, 0, 0);
            acc[1][1] = __builtin_amdgcn_mfma_f32_16x16x32_f16(a1, b1, acc[1][1], 0, 0, 0);
        }
        if (t < 15) {                       // write-late; one barrier per chunk
            int nb = cur ^ 1;
            *(f16x8*)&sA[nb][srow][sc8] = rA0;
            *(f16x8*)&sA[nb][srow + 32][sc8] = rA1;
            *(f16x8*)&sB[nb][srow][sc8] = rB0;
            *(f16x8*)&sB[nb][srow + 32][sc8] = rB1;
            __syncthreads();
        }
    }

    size_t ybase = (size_t)b * 192 + kk * 64;
    #pragma unroll
    for (int mi = 0; mi < 2; ++mi)
        #pragma unroll
        for (int ni = 0; ni < 2; ++ni) {
            int i = i0 + (nh + ni) * 16 + ln;
            #pragma unroll
            for (int r = 0; r < 4; ++r) {
                int c = (mh + mi) * 16 + kg * 4 + r;
                Yt[((ybase + c) << 10) + i] = (_Float16)acc[mi][ni][r];
            }
        }
}

// Stage 2: Zf[b][i][c] = sum_j (1024 A[b][i][j]) Yt[b][c][j]  (f16 out).
// x32 MFMA, double-buffered reg-staging, grid 512: bx = b*32 + it*2 + ch
__global__ __launch_bounds__(256) void k_az2(const float* __restrict__ A,
                                             const _Float16* __restrict__ Yt,
                                             _Float16* __restrict__ Zf) {
    int bx = blockIdx.x;
    int ch = bx & 1, it = (bx >> 1) & 15, b = bx >> 5;
    int i0 = it * 64, c0 = ch * 96;
    __shared__ _Float16 sA[2][64][72], sB[2][96][72];
    int tid = threadIdx.x;
    int w = tid >> 6, lane = tid & 63, ln = lane & 15, kg = lane >> 4;
    int mh = (w & 1) * 2, nh = (w >> 1) * 3;
    const float* Ab = A + ((size_t)b << 20) + ((size_t)i0 << 10);
    const _Float16* Yb = Yt + (((size_t)b * 192 + c0) << 10);
    int srow = tid >> 3, sc8 = (tid & 7) * 8;
    const float* qa0 = Ab + ((size_t)srow << 10) + sc8;
    const float* qa1 = Ab + ((size_t)(srow + 32) << 10) + sc8;
    const _Float16* qb0 = Yb + ((size_t)srow << 10) + sc8;
    const _Float16* qb1 = Yb + ((size_t)(srow + 32) << 10) + sc8;
    const _Float16* qb2 = Yb + ((size_t)(srow + 64) << 10) + sc8;

    f32x4 acc[2][3];
    #pragma unroll
    for (int mi = 0; mi < 2; ++mi)
        #pragma unroll
        for (int ni = 0; ni < 3; ++ni) acc[mi][ni] = (f32x4){0.f, 0.f, 0.f, 0.f};

    float4 ra0a = *(const float4*)qa0, ra0b = *(const float4*)(qa0 + 4);
    float4 ra1a = *(const float4*)qa1, ra1b = *(const float4*)(qa1 + 4);
    f16x8 rb0 = *(const f16x8*)qb0;
    f16x8 rb1 = *(const f16x8*)qb1;
    f16x8 rb2 = *(const f16x8*)qb2;
    {
        f16x8 va0 = {(_Float16)(ra0a.x*1024.f), (_Float16)(ra0a.y*1024.f), (_Float16)(ra0a.z*1024.f), (_Float16)(ra0a.w*1024.f),
                     (_Float16)(ra0b.x*1024.f), (_Float16)(ra0b.y*1024.f), (_Float16)(ra0b.z*1024.f), (_Float16)(ra0b.w*1024.f)};
        f16x8 va1 = {(_Float16)(ra1a.x*1024.f), (_Float16)(ra1a.y*1024.f), (_Float16)(ra1a.z*1024.f), (_Float16)(ra1a.w*1024.f),
                     (_Float16)(ra1b.x*1024.f), (_Float16)(ra1b.y*1024.f), (_Float16)(ra1b.z*1024.f), (_Float16)(ra1b.w*1024.f)};
        *(f16x8*)&sA[0][srow][sc8] = va0;
        *(f16x8*)&sA[0][srow + 32][sc8] = va1;
        *(f16x8*)&sB[0][srow][sc8] = rb0;
        *(f16x8*)&sB[0][srow + 32][sc8] = rb1;
        *(f16x8*)&sB[0][srow + 64][sc8] = rb2;
    }
    __syncthreads();

    for (int t = 0; t < 16; ++t) {
        int cur = t & 1;
        if (t < 15) {
            int kn = (t + 1) * 64;
            ra0a = *(const float4*)&qa0[kn]; ra0b = *(const float4*)&qa0[kn + 4];
            ra1a = *(const float4*)&qa1[kn]; ra1b = *(const float4*)&qa1[kn + 4];
            rb0 = *(const f16x8*)&qb0[kn];
            rb1 = *(const f16x8*)&qb1[kn];
            rb2 = *(const f16x8*)&qb2[kn];
        }
        #pragma unroll
        for (int ks = 0; ks < 2; ++ks) {
            int ko = ks * 32 + kg * 8;
            f16x8 a0 = *(const f16x8*)&sA[cur][(mh + 0) * 16 + ln][ko];
            f16x8 a1 = *(const f16x8*)&sA[cur][(mh + 1) * 16 + ln][ko];
            f16x8 b0 = *(const f16x8*)&sB[cur][(nh + 0) * 16 + ln][ko];
            f16x8 b1 = *(const f16x8*)&sB[cur][(nh + 1) * 16 + ln][ko];
            f16x8 b2 = *(const f16x8*)&sB[cur][(nh + 2) * 16 + ln][ko];
            acc[0][0] = __builtin_amdgcn_mfma_f32_16x16x32_f16(a0, b0, acc[0][0], 0, 0, 0);
            acc[0][1] = __builtin_amdgcn_mfma_f32_16x16x32_f16(a0, b1, acc[0][1], 0, 0, 0);
            acc[0][2] = __builtin_amdgcn_mfma_f32_16x16x32_f16(a0, b2, acc[0][2], 0, 0, 0);
            acc[1][0] = __builtin_amdgcn_mfma_f32_16x16x32_f16(a1, b0, acc[1][0], 0, 0, 0);
            acc[1][1] = __builtin_amdgcn_mfma_f32_16x16x32_f16(a1, b1, acc[1][1], 0, 0, 0);
            acc[1][2] = __builtin_amdgcn_mfma_f32_16x16x32_f16(a1, b2, acc[1][2], 0, 0, 0);
        }
        if (t < 15) {
            int nb = cur ^ 1;
            f16x8 va0 = {(_Float16)(ra0a.x*1024.f), (_Float16)(ra0a.y*1024.f), (_Float16)(ra0a.z*1024.f), (_Float16)(ra0a.w*1024.f),
                         (_Float16)(ra0b.x*1024.f), (_Float16)(ra0b.y*1024.f), (_Float16)(ra0b.z*1024.f), (_Float16)(ra0b.w*1024.f)};
            f16x8 va1 = {(_Float16)(ra1a.x*1024.f), (_Float16)(ra1a.y*1024.f), (_Float16)(ra1a.z*1024.f), (_Float16)(ra1a.w*1024.f),
                         (_Float16)(ra1b.x*1024.f), (_Float16)(ra1b.y*1024.f), (_Float16)(ra1b.z*1024.f), (_Float16)(ra1b.w*1024.f)};
            *(f16x8*)&sA[nb][srow][sc8] = va0;
            *(f16x8*)&sA[nb][srow + 32][sc8] = va1;
            *(f16x8*)&sB[nb][srow][sc8] = rb0;
            *(f16x8*)&sB[nb][srow + 32][sc8] = rb1;
            *(f16x8*)&sB[nb][srow + 64][sc8] = rb2;
            __syncthreads();
        }
    }

    #pragma unroll
    for (int mi = 0; mi < 2; ++mi)
        #pragma unroll
        for (int r = 0; r < 4; ++r) {
            int i = i0 + (mh + mi) * 16 + kg * 4 + r;
            #pragma unroll
            for (int ni = 0; ni < 3; ++ni) {
                int c = c0 + (nh + ni) * 16 + ln;
                Zf[((size_t)((b << 10) + i)) * 192 + c] = (_Float16)acc[mi][ni][r];
            }
        }
}

// gate epilogue via MFMA: pre = Z@wghT^T + xt + bias; z->zb; r*h -> Ht. grid 256
__global__ __launch_bounds__(256) void k_zrm(const _Float16* __restrict__ Zf,
                                             const _Float16* __restrict__ wghT,
                                             const float* __restrict__ wx,
                                             const float* __restrict__ bg,
                                             const float* __restrict__ S2,
                                             const float* __restrict__ h,
                                             float* __restrict__ zb,
                                             _Float16* __restrict__ Ht, int t) {
    int bx = blockIdx.x; int it = bx & 15, b = bx >> 4; int i0 = it * 64;
    __shared__ _Float16 sZ[64][200];
    __shared__ _Float16 sW[128][72];
    __shared__ float sS2[3][64];
    __shared__ float sWX[3][128];
    __shared__ float sBias[128];
    int tid = threadIdx.x, wid = tid >> 6, ln = tid & 15, kl = (tid & 63) >> 4;
    #pragma unroll
    for (int it2 = 0; it2 < 6; ++it2) {
        int idx = it2 * 256 + tid; int row = idx / 24, c8 = (idx % 24) * 8;
        *(uint4*)&sZ[row][c8] = *(const uint4*)&Zf[((size_t)((b << 10) + i0 + row)) * 192 + c8];
    }
    if (tid < 192) { int k = tid >> 6, ii = tid & 63; sS2[k][ii] = S2[(((size_t)(b * 3 + k) * T_ + t) << 10) + i0 + ii]; }
    for (int q = tid; q < 384; q += 256) sWX[q >> 7][q & 127] = wx[q];
    if (tid < 128) sBias[tid] = bg[tid];
    f32x4 acc[4][2];
    #pragma unroll
    for (int m = 0; m < 4; ++m)
        #pragma unroll
        for (int n = 0; n < 2; ++n) acc[m][n] = (f32x4){0.f, 0.f, 0.f, 0.f};
    for (int kc = 0; kc < 192; kc += 64) {
        #pragma unroll
        for (int it2 = 0; it2 < 4; ++it2) {
            int idx = it2 * 256 + tid; int row = idx >> 3, c8 = (idx & 7) * 8;
            *(uint4*)&sW[row][c8] = *(const uint4*)&wghT[(size_t)row * 192 + kc + c8];
        }
        __syncthreads();
        #pragma unroll
        for (int ks = 0; ks < 4; ++ks) {
            int ko = ks * 16 + kl * 4;
            f16x4 a[4], bb[2];
            #pragma unroll
            for (int m = 0; m < 4; ++m) a[m] = *(const f16x4*)&sZ[m * 16 + ln][kc + ko];
            #pragma unroll
            for (int n = 0; n < 2; ++n) bb[n] = *(const f16x4*)&sW[wid * 32 + n * 16 + ln][ko];
            #pragma unroll
            for (int m = 0; m < 4; ++m)
                #pragma unroll
                for (int n = 0; n < 2; ++n)
                    acc[m][n] = __builtin_amdgcn_mfma_f32_16x16x16f16(a[m], bb[n], acc[m][n], 0, 0, 0);
        }
        __syncthreads();
    }
    #pragma unroll
    for (int n = 0; n < 2; ++n) {
        int o = wid * 32 + n * 16 + ln;
        float wx0 = sWX[0][o], wx1 = sWX[1][o], wx2 = sWX[2][o], bias = sBias[o];
        if (o < H_) {
            #pragma unroll
            for (int m = 0; m < 4; ++m)
                #pragma unroll
                for (int r = 0; r < 4; ++r) {
                    int il = m * 16 + kl * 4 + r;
                    float pre = acc[m][n][r] + wx0 * sS2[0][il] + wx1 * sS2[1][il] + wx2 * sS2[2][il] + bias;
                    float v = 1.0f / (1.0f + expf(-pre));
                    zb[((size_t)((b << 10) + i0 + il)) * H_ + o] = v;
                }
        } else {
            int c = o - H_;
            #pragma unroll
            for (int m = 0; m < 4; ++m) {
                alignas(8) _Float16 hb[4];
                #pragma unroll
                for (int r = 0; r < 4; ++r) {
                    int il = m * 16 + kl * 4 + r;
                    float pre = acc[m][n][r] + wx0 * sS2[0][il] + wx1 * sS2[1][il] + wx2 * sS2[2][il] + bias;
                    float v = 1.0f / (1.0f + expf(-pre));
                    hb[r] = (_Float16)(v * h[((size_t)((b << 10) + i0 + il)) * H_ + c]);
                }
                *(f16x4*)&Ht[(((size_t)(b * 64 + c)) << 10) + i0 + m * 16 + kl * 4] = *(f16x4*)&hb[0];
            }
        }
    }
}

// update epilogue via MFMA. grid 256
__global__ __launch_bounds__(256) void k_updm(const _Float16* __restrict__ Zf,
                                              const _Float16* __restrict__ wuhT,
                                              const float* __restrict__ wx,
                                              const float* __restrict__ bu,
                                              const float* __restrict__ S2,
                                              const float* __restrict__ zb,
                                              float* __restrict__ h,
                                              _Float16* __restrict__ Ht, int t) {
    int bx = blockIdx.x; int it = bx & 15, b = bx >> 4; int i0 = it * 64;
    __shared__ _Float16 sZ[64][200];
    __shared__ _Float16 sW[64][72];
    __shared__ float sS2[3][64];
    __shared__ float sWX[3][64];
    __shared__ float sBias[64];
    int tid = threadIdx.x, wid = tid >> 6, ln = tid & 15, kl = (tid & 63) >> 4;
    #pragma unroll
    for (int it2 = 0; it2 < 6; ++it2) {
        int idx = it2 * 256 + tid; int row = idx / 24, c8 = (idx % 24) * 8;
        *(uint4*)&sZ[row][c8] = *(const uint4*)&Zf[((size_t)((b << 10) + i0 + row)) * 192 + c8];
    }
    if (tid < 192) { int k = tid >> 6, ii = tid & 63; sS2[k][ii] = S2[(((size_t)(b * 3 + k) * T_ + t) << 10) + i0 + ii]; }
    if (tid < 192) sWX[tid / 64][tid % 64] = wx[384 + tid];
    if (tid < 64) sBias[tid] = bu[tid];
    f32x4 acc[4];
    #pragma unroll
    for (int m = 0; m < 4; ++m) acc[m] = (f32x4){0.f, 0.f, 0.f, 0.f};
    for (int kc = 0; kc < 192; kc += 64) {
        #pragma unroll
        for (int it2 = 0; it2 < 2; ++it2) {
            int idx = it2 * 256 + tid; int row = idx >> 3, c8 = (idx & 7) * 8;
            *(uint4*)&sW[row][c8] = *(const uint4*)&wuhT[(size_t)row * 192 + kc + c8];
        }
        __syncthreads();
        #pragma unroll
        for (int ks = 0; ks < 4; ++ks) {
            int ko = ks * 16 + kl * 4;
            f16x4 bb = *(const f16x4*)&sW[wid * 16 + ln][ko];
            #pragma unroll
            for (int m = 0; m < 4; ++m) {
                f16x4 a = *(const f16x4*)&sZ[m * 16 + ln][kc + ko];
                acc[m] = __builtin_amdgcn_mfma_f32_16x16x16f16(a, bb, acc[m], 0, 0, 0);
            }
        }
        __syncthreads();
    }
    int o = wid * 16 + ln;
    float wx0 = sWX[0][o], wx1 = sWX[1][o], wx2 = sWX[2][o], bias = sBias[o];
    #pragma unroll
    for (int m = 0; m < 4; ++m) {
        alignas(8) _Float16 hb[4];
        #pragma unroll
        for (int r = 0; r < 4; ++r) {
            int il = m * 16 + kl * 4 + r;
            float pre = acc[m][r] + wx0 * sS2[0][il] + wx1 * sS2[1][il] + wx2 * sS2[2][il] + bias;
            float hc = tanhf(pre);
            size_t gi = ((size_t)((b << 10) + i0 + il)) * H_ + o;
            float z = zb[gi], hold = h[gi];
            float hn = z * hc + (1.0f - z) * hold;
            h[gi] = hn;
            hb[r] = (_Float16)hn;
        }
        *(f16x4*)&Ht[(((size_t)(b * 64 + o)) << 10) + i0 + m * 16 + kl * 4] = *(f16x4*)&hb[0];
    }
}

// out[(b*12+tt)*1024 + i] = h[b][i][:] @ W_dec[:,tt] + b_dec[tt]
__global__ __launch_bounds__(256) void k_dec(const float* __restrict__ h,
                                             const float* __restrict__ Wd,
                                             const float* __restrict__ bd,
                                             float* __restrict__ out) {
    int bx = blockIdx.x;
    int b = bx >> 4, it = bx & 15; int i0 = it * 64;
    __shared__ float hs[64][65];
    __shared__ float Wds[64][12];
    __shared__ float bds[12];
    int tid = threadIdx.x;
    for (int idx = tid; idx < 4096; idx += 256) {
        int r = idx >> 6, c = idx & 63;
        hs[r][c] = h[(size_t)(b * N_ + i0 + r) * H_ + c];
    }
    for (int idx = tid; idx < 768; idx += 256)
        Wds[idx / 12][idx % 12] = Wd[idx];
    if (tid < 12) bds[tid] = bd[tid];
    __syncthreads();
    for (int oidx = tid; oidx < 768; oidx += 256) {
        int i = oidx & 63, tt = oidx >> 6;
        float acc = bds[tt];
        #pragma unroll
        for (int c = 0; c < 64; ++c) acc += hs[i][c] * Wds[c][tt];
        out[(size_t)(b * T_ + tt) * N_ + i0 + i] = acc;
    }
}

extern "C" void kernel_launch(void* const* d_in, const int* in_sizes, int n_in,
                              void* d_out, int out_size, void* d_ws, size_t ws_size,
                              hipStream_t stream) {
    const float* x  = (const float*)d_in[0];
    const float* G  = (const float*)d_in[1];
    const float* A  = (const float*)d_in[2];
    const float* Wg = (const float*)d_in[3];
    const float* bg = (const float*)d_in[4];
    const float* Wu = (const float*)d_in[5];
    const float* bu = (const float*)d_in[6];
    const float* Wd = (const float*)d_in[7];
    const float* bd = (const float*)d_in[8];
    float* out = (float*)d_out;
    float* ws  = (float*)d_ws;

    float* h   = ws + OFF_H;
    float* zb  = ws + OFF_ZB;
    float* S2  = ws + OFF_S2;
    float* wxb = ws + OFF_WX;
    _Float16* Zf   = (_Float16*)(ws + OFF_ZF);
    _Float16* Ht   = (_Float16*)(ws + OFF_HT);
    _Float16* Yt   = (_Float16*)(ws + OFF_YT);
    _Float16* S1   = (_Float16*)(ws + OFF_S1);
    _Float16* wghT = (_Float16*)(ws + OFF_WGT);
    _Float16* wuhT = (_Float16*)(ws + OFF_WUT);
    _Float16* Gf   = (_Float16*)(ws + OFF_GF);

    hipMemsetAsync(h, 0, (size_t)B_ * N_ * H_ * sizeof(float), stream);
    hipMemsetAsync((void*)Ht, 0, (size_t)B_ * N_ * H_ * sizeof(_Float16), stream);
    k_repack<<<147, 256, 0, stream>>>(Wg, Wu, wghT, wuhT, wxb);
    k_gcvt<<<1536, 256, 0, stream>>>(G, Gf);
    k_s1b<<<96, 256, 0, stream>>>(G, x, S1);
    k_s2b<<<256, 256, 0, stream>>>(A, S1, S2);

    for (int t = 0; t < T_; ++t) {
        k_gh2<<<768, 256, 0, stream>>>(Gf, Ht, Yt);
        k_az2<<<512, 256, 0, stream>>>(A, Yt, Zf);
        k_zrm<<<256, 256, 0, stream>>>(Zf, wghT, wxb, bg, S2, h, zb, Ht, t);
        k_gh2<<<768, 256, 0, stream>>>(Gf, Ht, Yt);
        k_az2<<<512, 256, 0, stream>>>(A, Yt, Zf);
        k_updm<<<256, 256, 0, stream>>>(Zf, wuhT, wxb, bu, S2, zb, h, Ht, t);
    }
    k_dec<<<256, 256, 0, stream>>>(h, Wd, bd, out);
}

// Round 10
// 960.703 us; speedup vs baseline: 2.0418x; 1.3476x over previous
//
#include <hip/hip_runtime.h>

#define B_  16
#define T_  12
#define N_  1024
#define K_  3
#define H_  64
#define DIN 65
#define KH  192   // K_*H_
#define OG  128   // 2*H_

typedef _Float16 f16x4 __attribute__((ext_vector_type(4)));
typedef _Float16 f16x8 __attribute__((ext_vector_type(8)));
typedef float    f32x4 __attribute__((ext_vector_type(4)));

// ---- workspace offsets (float units), total 30,788,160 f = 123.2 MB
// (ws_size evidenced ~268 MB by the harness poison fill of 262144 KB)
static const size_t OFF_H   = 0;          // f32 h    [16][1024][64]
static const size_t OFF_ZB  = 1048576;    // f32 z    [16][1024][64]
static const size_t OFF_S2  = 2097152;    // f32 S2   [16][3][12][1024] (x1024)
static const size_t OFF_HTA = 2686976;    // f16 HtA  [16][64][1024]
static const size_t OFF_HTB = 3211264;    // f16 HtB  [16][64][1024]
static const size_t OFF_S1  = 3735552;    // f16 S1   [3][192][1024]
static const size_t OFF_WGT = 4030464;    // f16 wghT [128][192] (/1024)
static const size_t OFF_WUT = 4042752;    // f16 wuhT [64][192]  (/1024)
static const size_t OFF_WX  = 4048896;    // f32 wx (576)
static const size_t OFF_GT  = 4049472;    // f16 GfT  [3][1024][1024]  (G transposed)
static const size_t OFF_AG  = 5622336;    // f16 AG   [16][3][1024][1024] = 1024*A@G

// Repack weights: transposed f16 h-part + f32 x-part rows, all pre-divided by 1024.
__global__ __launch_bounds__(256) void k_repack(const float* __restrict__ Wg,
                                                const float* __restrict__ Wu,
                                                _Float16* __restrict__ wghT,
                                                _Float16* __restrict__ wuhT,
                                                float* __restrict__ wx) {
    const float inv = 1.0f / 1024.0f;
    int idx = blockIdx.x * 256 + threadIdx.x;
    if (idx < 128 * 192) {
        int o = idx / 192, d = idx % 192;
        int k = d / 64, c = d % 64;
        wghT[idx] = (_Float16)(Wg[(size_t)(k * DIN + 1 + c) * OG + o] * inv);
    } else if (idx < 128 * 192 + 64 * 192) {
        int j = idx - 128 * 192;
        int o = j / 192, d = j % 192;
        int k = d / 64, c = d % 64;
        wuhT[j] = (_Float16)(Wu[(size_t)(k * DIN + 1 + c) * H_ + o] * inv);
    } else if (idx < 128 * 192 + 64 * 192 + 576) {
        int j = idx - 128 * 192 - 64 * 192;
        if (j < 384) { int k = j >> 7, o = j & 127; wx[j] = Wg[(size_t)(k * DIN) * OG + o] * inv; }
        else { int j2 = j - 384; int k = j2 >> 6, o = j2 & 63; wx[j] = Wu[(size_t)(k * DIN) * H_ + o] * inv; }
    }
}

// G transpose-convert: GfT[k][j][p] = f16(G[k][p][j]). grid 768 = 3*16*16.
__global__ __launch_bounds__(256) void k_gtr(const float* __restrict__ G,
                                             _Float16* __restrict__ GfT) {
    int bx = blockIdx.x;
    int kk = bx >> 8, rem = bx & 255, ti = rem >> 4, tj = rem & 15;
    int i0 = ti * 64, j0 = tj * 64;
    __shared__ _Float16 s[64][72];
    int tid = threadIdx.x;
    int r = tid >> 2, cb = (tid & 3) * 16;
    const float* Gp = G + ((size_t)kk << 20) + ((size_t)(i0 + r) << 10) + j0 + cb;
    #pragma unroll
    for (int q = 0; q < 4; ++q) {
        float4 v = *(const float4*)&Gp[q * 4];
        f16x4 hv = {(_Float16)v.x, (_Float16)v.y, (_Float16)v.z, (_Float16)v.w};
        *(f16x4*)&s[r][cb + q * 4] = hv;
    }
    __syncthreads();
    alignas(16) _Float16 tmp[16];
    #pragma unroll
    for (int q = 0; q < 16; ++q) tmp[q] = s[cb + q][r];
    _Float16* outp = GfT + ((size_t)kk << 20) + ((size_t)(j0 + r) << 10) + i0 + cb;
    *(f16x8*)&outp[0] = *(f16x8*)&tmp[0];
    *(f16x8*)&outp[8] = *(f16x8*)&tmp[8];
}

// AG[b][k] = (1024*A[b]) @ G[k]  in f16. 128x128 tiles, K-chunk 64, reg-staged dbuf.
// grid 3072: inst = bx>>6 (b=inst/3, k=inst%3); tile = bx&63 (ti=tile>>3, tj=tile&7)
__global__ __launch_bounds__(256) void k_ag(const float* __restrict__ A,
                                            const _Float16* __restrict__ GfT,
                                            _Float16* __restrict__ AG) {
    int bx = blockIdx.x;
    int inst = bx >> 6, tile = bx & 63;
    int b = inst / 3, kk = inst % 3;
    int i0 = (tile >> 3) * 128, j0 = (tile & 7) * 128;
    __shared__ _Float16 sA[2][128][72], sB[2][128][72];
    int tid = threadIdx.x;
    int w = tid >> 6, lane = tid & 63, ln = lane & 15, kg = lane >> 4;
    int mq = (w & 1) * 64, nq = (w >> 1) * 64;
    int srow = tid >> 1, cb = (tid & 1) * 32;
    const float*    qa = A   + ((size_t)b << 20)  + ((size_t)(i0 + srow) << 10) + cb;
    const _Float16* qb = GfT + ((size_t)kk << 20) + ((size_t)(j0 + srow) << 10) + cb;

    f32x4 acc[4][4];
    #pragma unroll
    for (int mt = 0; mt < 4; ++mt)
        #pragma unroll
        for (int nt = 0; nt < 4; ++nt) acc[mt][nt] = (f32x4){0.f, 0.f, 0.f, 0.f};

    float4 ra[8]; f16x8 rb[4];
    #pragma unroll
    for (int q = 0; q < 8; ++q) ra[q] = *(const float4*)&qa[q * 4];
    #pragma unroll
    for (int q = 0; q < 4; ++q) rb[q] = *(const f16x8*)&qb[q * 8];
    #pragma unroll
    for (int q = 0; q < 4; ++q) {
        float4 u = ra[2*q], v = ra[2*q+1];
        f16x8 hv = {(_Float16)(u.x*1024.f), (_Float16)(u.y*1024.f), (_Float16)(u.z*1024.f), (_Float16)(u.w*1024.f),
                    (_Float16)(v.x*1024.f), (_Float16)(v.y*1024.f), (_Float16)(v.z*1024.f), (_Float16)(v.w*1024.f)};
        *(f16x8*)&sA[0][srow][cb + q * 8] = hv;
        *(f16x8*)&sB[0][srow][cb + q * 8] = rb[q];
    }
    __syncthreads();

    for (int tt = 0; tt < 16; ++tt) {
        int cur = tt & 1;
        if (tt < 15) {
            int kn = (tt + 1) * 64;
            #pragma unroll
            for (int q = 0; q < 8; ++q) ra[q] = *(const float4*)&qa[kn + q * 4];
            #pragma unroll
            for (int q = 0; q < 4; ++q) rb[q] = *(const f16x8*)&qb[kn + q * 8];
        }
        #pragma unroll
        for (int ks = 0; ks < 2; ++ks) {
            int ko = ks * 32 + kg * 8;
            f16x8 a[4], bfr[4];
            #pragma unroll
            for (int mt = 0; mt < 4; ++mt) a[mt] = *(const f16x8*)&sA[cur][mq + mt * 16 + ln][ko];
            #pragma unroll
            for (int nt = 0; nt < 4; ++nt) bfr[nt] = *(const f16x8*)&sB[cur][nq + nt * 16 + ln][ko];
            #pragma unroll
            for (int mt = 0; mt < 4; ++mt)
                #pragma unroll
                for (int nt = 0; nt < 4; ++nt)
                    acc[mt][nt] = __builtin_amdgcn_mfma_f32_16x16x32_f16(a[mt], bfr[nt], acc[mt][nt], 0, 0, 0);
        }
        if (tt < 15) {
            int nb = cur ^ 1;
            #pragma unroll
            for (int q = 0; q < 4; ++q) {
                float4 u = ra[2*q], v = ra[2*q+1];
                f16x8 hv = {(_Float16)(u.x*1024.f), (_Float16)(u.y*1024.f), (_Float16)(u.z*1024.f), (_Float16)(u.w*1024.f),
                            (_Float16)(v.x*1024.f), (_Float16)(v.y*1024.f), (_Float16)(v.z*1024.f), (_Float16)(v.w*1024.f)};
                *(f16x8*)&sA[nb][srow][cb + q * 8] = hv;
                *(f16x8*)&sB[nb][srow][cb + q * 8] = rb[q];
            }
            __syncthreads();
        }
    }

    _Float16* outp = AG + ((size_t)(b * 3 + kk) << 20);
    #pragma unroll
    for (int mt = 0; mt < 4; ++mt)
        #pragma unroll
        for (int r = 0; r < 4; ++r) {
            int i = i0 + mq + mt * 16 + kg * 4 + r;
            #pragma unroll
            for (int nt = 0; nt < 4; ++nt) {
                int j = j0 + nq + nt * 16 + ln;
                outp[((size_t)i << 10) + j] = (_Float16)acc[mt][nt][r];
            }
        }
}

// S1[k][m][i] = sum_j G[k][i][j] x[m][j]  (f16 out). grid 96
__global__ __launch_bounds__(256) void k_s1b(const float* __restrict__ G,
                                             const float* __restrict__ x,
                                             _Float16* __restrict__ S1) {
    int bx = blockIdx.x;
    int nh = bx & 1, it = (bx >> 1) & 15, kk = bx >> 5;
    int i0 = it * 64, m0 = nh * 96;
    __shared__ _Float16 sA[64][72], sB[96][72];
    int tid = threadIdx.x, wid = tid >> 6, ln = tid & 15, kl = (tid & 63) >> 4;
    const float* Gk = G + (size_t)kk * N_ * N_;
    f32x4 acc[6];
    #pragma unroll
    for (int n = 0; n < 6; ++n) acc[n] = (f32x4){0.f, 0.f, 0.f, 0.f};
    for (int kc = 0; kc < N_; kc += 64) {
        #pragma unroll
        for (int it2 = 0; it2 < 4; ++it2) {
            int idx = it2 * 256 + tid; int row = idx >> 4, c4 = (idx & 15) * 4;
            float4 g = *(const float4*)&Gk[(size_t)(i0 + row) * N_ + kc + c4];
            f16x4 hv = {(_Float16)g.x, (_Float16)g.y, (_Float16)g.z, (_Float16)g.w};
            *(f16x4*)&sA[row][c4] = hv;
        }
        #pragma unroll
        for (int it2 = 0; it2 < 6; ++it2) {
            int idx = it2 * 256 + tid; int row = idx >> 4, c4 = (idx & 15) * 4;
            float4 g = *(const float4*)&x[(size_t)(m0 + row) * N_ + kc + c4];
            f16x4 hv = {(_Float16)g.x, (_Float16)g.y, (_Float16)g.z, (_Float16)g.w};
            *(f16x4*)&sB[row][c4] = hv;
        }
        __syncthreads();
        #pragma unroll
        for (int ks = 0; ks < 4; ++ks) {
            int ko = ks * 16 + kl * 4;
            f16x4 a = *(const f16x4*)&sA[wid * 16 + ln][ko];
            #pragma unroll
            for (int n = 0; n < 6; ++n) {
                f16x4 b = *(const f16x4*)&sB[n * 16 + ln][ko];
                acc[n] = __builtin_amdgcn_mfma_f32_16x16x16f16(a, b, acc[n], 0, 0, 0);
            }
        }
        __syncthreads();
    }
    #pragma unroll
    for (int n = 0; n < 6; ++n) {
        int m = m0 + n * 16 + ln;
        #pragma unroll
        for (int r = 0; r < 4; ++r) {
            int i = i0 + wid * 16 + kl * 4 + r;
            S1[(((size_t)kk * 192 + m) << 10) + i] = (_Float16)acc[n][r];
        }
    }
}

// S2[b][k][t][i] = sum_j (1024 A[b][i][j]) S1[k][b*12+t][j]  (f32 out). grid 256
__global__ __launch_bounds__(256) void k_s2b(const float* __restrict__ A,
                                             const _Float16* __restrict__ S1,
                                             float* __restrict__ S2) {
    int bx = blockIdx.x; int it = bx & 15, b = bx >> 4; int i0 = it * 64;
    __shared__ _Float16 sA[64][72], sB[48][72];
    int tid = threadIdx.x, wid = tid >> 6, ln = tid & 15, kl = (tid & 63) >> 4;
    const float* Ab = A + (size_t)b * N_ * N_;
    f32x4 acc[3];
    #pragma unroll
    for (int n = 0; n < 3; ++n) acc[n] = (f32x4){0.f, 0.f, 0.f, 0.f};
    for (int kc = 0; kc < N_; kc += 64) {
        #pragma unroll
        for (int it2 = 0; it2 < 4; ++it2) {
            int idx = it2 * 256 + tid; int row = idx >> 4, c4 = (idx & 15) * 4;
            float4 a4 = *(const float4*)&Ab[(size_t)(i0 + row) * N_ + kc + c4];
            f16x4 hv = {(_Float16)(a4.x * 1024.f), (_Float16)(a4.y * 1024.f),
                        (_Float16)(a4.z * 1024.f), (_Float16)(a4.w * 1024.f)};
            *(f16x4*)&sA[row][c4] = hv;
        }
        for (int idx = tid; idx < 288; idx += 256) {
            int row = idx >> 3, c8 = (idx & 7) * 8;
            int kq = row / 12, tq = row - kq * 12;
            *(uint4*)&sB[row][c8] = *(const uint4*)&S1[(((size_t)kq * 192 + b * T_ + tq) << 10) + kc + c8];
        }
        __syncthreads();
        #pragma unroll
        for (int ks = 0; ks < 4; ++ks) {
            int ko = ks * 16 + kl * 4;
            f16x4 a = *(const f16x4*)&sA[wid * 16 + ln][ko];
            #pragma unroll
            for (int n = 0; n < 3; ++n) {
                f16x4 b = *(const f16x4*)&sB[n * 16 + ln][ko];
                acc[n] = __builtin_amdgcn_mfma_f32_16x16x16f16(a, b, acc[n], 0, 0, 0);
            }
        }
        __syncthreads();
    }
    #pragma unroll
    for (int n = 0; n < 3; ++n) {
        int col = n * 16 + ln;
        if (col < 36) {
            int kq = col / 12, tq = col - kq * 12;
            #pragma unroll
            for (int r = 0; r < 4; ++r) {
                int i = i0 + wid * 16 + kl * 4 + r;
                S2[(((size_t)(b * 3 + kq) * T_ + tq) << 10) + i] = acc[n][r];
            }
        }
    }
}

// Fused gate half-step: Z(32x192) = sum_k AG[b,k][rows]@HtIn; epi -> zb, HtOut = f16(r*h).
// grid 512: it = bx&31, b = bx>>5.
__global__ __launch_bounds__(256) void k_fzr(const _Float16* __restrict__ AG,
                                             const _Float16* __restrict__ HtIn,
                                             const _Float16* __restrict__ wghT,
                                             const float* __restrict__ wx,
                                             const float* __restrict__ bg,
                                             const float* __restrict__ S2,
                                             const float* __restrict__ h,
                                             float* __restrict__ zb,
                                             _Float16* __restrict__ HtOut, int t) {
    int bx = blockIdx.x; int it = bx & 31, b = bx >> 5; int i0 = it * 32;
    __shared__ __align__(16) char smem[46080];
    _Float16 (*sA)[96][72] = reinterpret_cast<_Float16(*)[96][72]>(smem);          // phase 1
    _Float16 (*sB)[64][72] = reinterpret_cast<_Float16(*)[64][72]>(smem + 27648);
    _Float16 (*sZ)[200]    = reinterpret_cast<_Float16(*)[200]>(smem);             // phase 2
    _Float16 (*sW)[72]     = reinterpret_cast<_Float16(*)[72]>(smem + 12800);
    __shared__ float sS2[3][32];
    __shared__ float sWX[384];
    __shared__ float sBias[128];
    int tid = threadIdx.x;
    int w = tid >> 6, lane = tid & 63, ln = lane & 15, kg = lane >> 4;
    if (tid < 96) { int k = tid >> 5, il = tid & 31; sS2[k][il] = S2[(((size_t)(b * 3 + k) * T_ + t) << 10) + i0 + il]; }
    for (int q = tid; q < 384; q += 256) sWX[q] = wx[q];
    if (tid < 128) sBias[tid] = bg[tid];

    int srow = tid >> 3, sc8 = (tid & 7) * 8;
    const _Float16* pa0 = AG + ((size_t)(b * 3 + 0) << 20) + ((size_t)(i0 + srow) << 10) + sc8;
    const _Float16* pa1 = AG + ((size_t)(b * 3 + 1) << 20) + ((size_t)(i0 + srow) << 10) + sc8;
    const _Float16* pa2 = AG + ((size_t)(b * 3 + 2) << 20) + ((size_t)(i0 + srow) << 10) + sc8;
    const _Float16* pb0 = HtIn + ((size_t)b << 16) + ((size_t)srow << 10) + sc8;
    const _Float16* pb1 = HtIn + ((size_t)b << 16) + ((size_t)(srow + 32) << 10) + sc8;

    f32x4 acc[2][3];
    #pragma unroll
    for (int m = 0; m < 2; ++m)
        #pragma unroll
        for (int n = 0; n < 3; ++n) acc[m][n] = (f32x4){0.f, 0.f, 0.f, 0.f};

    f16x8 rA0 = *(const f16x8*)pa0, rA1 = *(const f16x8*)pa1, rA2 = *(const f16x8*)pa2;
    f16x8 rB0 = *(const f16x8*)pb0, rB1 = *(const f16x8*)pb1;
    *(f16x8*)&sA[0][srow][sc8] = rA0;
    *(f16x8*)&sA[0][32 + srow][sc8] = rA1;
    *(f16x8*)&sA[0][64 + srow][sc8] = rA2;
    *(f16x8*)&sB[0][srow][sc8] = rB0;
    *(f16x8*)&sB[0][srow + 32][sc8] = rB1;
    __syncthreads();

    int kbF = (w * 3) >> 2, kbL = (w * 3 + 2) >> 2;
    for (int tt = 0; tt < 16; ++tt) {
        int cur = tt & 1;
        if (tt < 15) {
            int kn = (tt + 1) * 64;
            rA0 = *(const f16x8*)&pa0[kn]; rA1 = *(const f16x8*)&pa1[kn]; rA2 = *(const f16x8*)&pa2[kn];
            rB0 = *(const f16x8*)&pb0[kn]; rB1 = *(const f16x8*)&pb1[kn];
        }
        #pragma unroll
        for (int ks = 0; ks < 2; ++ks) {
            int ko = ks * 32 + kg * 8;
            f16x8 aF0 = *(const f16x8*)&sA[cur][kbF * 32 + ln][ko];
            f16x8 aF1 = *(const f16x8*)&sA[cur][kbF * 32 + 16 + ln][ko];
            f16x8 aL0 = *(const f16x8*)&sA[cur][kbL * 32 + ln][ko];
            f16x8 aL1 = *(const f16x8*)&sA[cur][kbL * 32 + 16 + ln][ko];
            #pragma unroll
            for (int ni = 0; ni < 3; ++ni) {
                int ct = w * 3 + ni;
                f16x8 bb = *(const f16x8*)&sB[cur][(ct & 3) * 16 + ln][ko];
                bool late = (ct >> 2) != kbF;
                f16x8 a0 = late ? aL0 : aF0;
                f16x8 a1 = late ? aL1 : aF1;
                acc[0][ni] = __builtin_amdgcn_mfma_f32_16x16x32_f16(a0, bb, acc[0][ni], 0, 0, 0);
                acc[1][ni] = __builtin_amdgcn_mfma_f32_16x16x32_f16(a1, bb, acc[1][ni], 0, 0, 0);
            }
        }
        if (tt < 15) {
            int nb = cur ^ 1;
            *(f16x8*)&sA[nb][srow][sc8] = rA0;
            *(f16x8*)&sA[nb][32 + srow][sc8] = rA1;
            *(f16x8*)&sA[nb][64 + srow][sc8] = rA2;
            *(f16x8*)&sB[nb][srow][sc8] = rB0;
            *(f16x8*)&sB[nb][srow + 32][sc8] = rB1;
            __syncthreads();
        }
    }
    __syncthreads();   // drain last chunk's LDS reads before aliasing writes

    #pragma unroll
    for (int m = 0; m < 2; ++m)
        #pragma unroll
        for (int ni = 0; ni < 3; ++ni)
            #pragma unroll
            for (int r = 0; r < 4; ++r)
                sZ[m * 16 + kg * 4 + r][(w * 3 + ni) * 16 + ln] = (_Float16)acc[m][ni][r];

    f32x4 e[2][2];
    #pragma unroll
    for (int m = 0; m < 2; ++m)
        #pragma unroll
        for (int n = 0; n < 2; ++n) e[m][n] = (f32x4){0.f, 0.f, 0.f, 0.f};
    for (int kc = 0; kc < 192; kc += 64) {
        #pragma unroll
        for (int it2 = 0; it2 < 4; ++it2) {
            int idx = it2 * 256 + tid; int row = idx >> 3, c8 = (idx & 7) * 8;
            *(f16x8*)&sW[row][c8] = *(const f16x8*)&wghT[(size_t)row * 192 + kc + c8];
        }
        __syncthreads();
        #pragma unroll
        for (int ks = 0; ks < 4; ++ks) {
            int ko = ks * 16 + kg * 4;
            f16x4 az0 = *(const f16x4*)&sZ[ln][kc + ko];
            f16x4 az1 = *(const f16x4*)&sZ[16 + ln][kc + ko];
            f16x4 bw0 = *(const f16x4*)&sW[w * 32 + ln][ko];
            f16x4 bw1 = *(const f16x4*)&sW[w * 32 + 16 + ln][ko];
            e[0][0] = __builtin_amdgcn_mfma_f32_16x16x16f16(az0, bw0, e[0][0], 0, 0, 0);
            e[0][1] = __builtin_amdgcn_mfma_f32_16x16x16f16(az0, bw1, e[0][1], 0, 0, 0);
            e[1][0] = __builtin_amdgcn_mfma_f32_16x16x16f16(az1, bw0, e[1][0], 0, 0, 0);
            e[1][1] = __builtin_amdgcn_mfma_f32_16x16x16f16(az1, bw1, e[1][1], 0, 0, 0);
        }
        __syncthreads();
    }

    #pragma unroll
    for (int n = 0; n < 2; ++n) {
        int o = w * 32 + n * 16 + ln;
        float w0 = sWX[o], w1 = sWX[128 + o], w2 = sWX[256 + o], bi = sBias[o];
        if (o < H_) {
            #pragma unroll
            for (int m = 0; m < 2; ++m)
                #pragma unroll
                for (int r = 0; r < 4; ++r) {
                    int il = m * 16 + kg * 4 + r;
                    float pre = e[m][n][r] + w0 * sS2[0][il] + w1 * sS2[1][il] + w2 * sS2[2][il] + bi;
                    float v = 1.0f / (1.0f + expf(-pre));
                    zb[((size_t)((b << 10) + i0 + il)) * H_ + o] = v;
                }
        } else {
            int c = o - H_;
            #pragma unroll
            for (int m = 0; m < 2; ++m) {
                alignas(8) _Float16 hb[4];
                #pragma unroll
                for (int r = 0; r < 4; ++r) {
                    int il = m * 16 + kg * 4 + r;
                    float pre = e[m][n][r] + w0 * sS2[0][il] + w1 * sS2[1][il] + w2 * sS2[2][il] + bi;
                    float v = 1.0f / (1.0f + expf(-pre));
                    hb[r] = (_Float16)(v * h[((size_t)((b << 10) + i0 + il)) * H_ + c]);
                }
                *(f16x4*)&HtOut[((size_t)(b * 64 + c) << 10) + i0 + m * 16 + kg * 4] = *(f16x4*)&hb[0];
            }
        }
    }
}

// Fused update half-step: Z = sum_k AG@HtIn(r*h); epi -> h = z*tanh+(1-z)h, HtOut = f16(h).
__global__ __launch_bounds__(256) void k_fup(const _Float16* __restrict__ AG,
                                             const _Float16* __restrict__ HtIn,
                                             const _Float16* __restrict__ wuhT,
                                             const float* __restrict__ wx,
                                             const float* __restrict__ bu,
                                             const float* __restrict__ S2,
                                             const float* __restrict__ zb,
                                             float* __restrict__ h,
                                             _Float16* __restrict__ HtOut, int t) {
    int bx = blockIdx.x; int it = bx & 31, b = bx >> 5; int i0 = it * 32;
    __shared__ __align__(16) char smem[46080];
    _Float16 (*sA)[96][72] = reinterpret_cast<_Float16(*)[96][72]>(smem);
    _Float16 (*sB)[64][72] = reinterpret_cast<_Float16(*)[64][72]>(smem + 27648);
    _Float16 (*sZ)[200]    = reinterpret_cast<_Float16(*)[200]>(smem);
    _Float16 (*sW)[72]     = reinterpret_cast<_Float16(*)[72]>(smem + 12800);
    __shared__ float sS2[3][32];
    __shared__ float sWX[192];
    __shared__ float sBias[64];
    int tid = threadIdx.x;
    int w = tid >> 6, lane = tid & 63, ln = lane & 15, kg = lane >> 4;
    if (tid < 96) { int k = tid >> 5, il = tid & 31; sS2[k][il] = S2[(((size_t)(b * 3 + k) * T_ + t) << 10) + i0 + il]; }
    if (tid < 192) sWX[tid] = wx[384 + tid];
    if (tid < 64) sBias[tid] = bu[tid];

    int srow = tid >> 3, sc8 = (tid & 7) * 8;
    const _Float16* pa0 = AG + ((size_t)(b * 3 + 0) << 20) + ((size_t)(i0 + srow) << 10) + sc8;
    const _Float16* pa1 = AG + ((size_t)(b * 3 + 1) << 20) + ((size_t)(i0 + srow) << 10) + sc8;
    const _Float16* pa2 = AG + ((size_t)(b * 3 + 2) << 20) + ((size_t)(i0 + srow) << 10) + sc8;
    const _Float16* pb0 = HtIn + ((size_t)b << 16) + ((size_t)srow << 10) + sc8;
    const _Float16* pb1 = HtIn + ((size_t)b << 16) + ((size_t)(srow + 32) << 10) + sc8;

    f32x4 acc[2][3];
    #pragma unroll
    for (int m = 0; m < 2; ++m)
        #pragma unroll
        for (int n = 0; n < 3; ++n) acc[m][n] = (f32x4){0.f, 0.f, 0.f, 0.f};

    f16x8 rA0 = *(const f16x8*)pa0, rA1 = *(const f16x8*)pa1, rA2 = *(const f16x8*)pa2;
    f16x8 rB0 = *(const f16x8*)pb0, rB1 = *(const f16x8*)pb1;
    *(f16x8*)&sA[0][srow][sc8] = rA0;
    *(f16x8*)&sA[0][32 + srow][sc8] = rA1;
    *(f16x8*)&sA[0][64 + srow][sc8] = rA2;
    *(f16x8*)&sB[0][srow][sc8] = rB0;
    *(f16x8*)&sB[0][srow + 32][sc8] = rB1;
    __syncthreads();

    int kbF = (w * 3) >> 2, kbL = (w * 3 + 2) >> 2;
    for (int tt = 0; tt < 16; ++tt) {
        int cur = tt & 1;
        if (tt < 15) {
            int kn = (tt + 1) * 64;
            rA0 = *(const f16x8*)&pa0[kn]; rA1 = *(const f16x8*)&pa1[kn]; rA2 = *(const f16x8*)&pa2[kn];
            rB0 = *(const f16x8*)&pb0[kn]; rB1 = *(const f16x8*)&pb1[kn];
        }
        #pragma unroll
        for (int ks = 0; ks < 2; ++ks) {
            int ko = ks * 32 + kg * 8;
            f16x8 aF0 = *(const f16x8*)&sA[cur][kbF * 32 + ln][ko];
            f16x8 aF1 = *(const f16x8*)&sA[cur][kbF * 32 + 16 + ln][ko];
            f16x8 aL0 = *(const f16x8*)&sA[cur][kbL * 32 + ln][ko];
            f16x8 aL1 = *(const f16x8*)&sA[cur][kbL * 32 + 16 + ln][ko];
            #pragma unroll
            for (int ni = 0; ni < 3; ++ni) {
                int ct = w * 3 + ni;
                f16x8 bb = *(const f16x8*)&sB[cur][(ct & 3) * 16 + ln][ko];
                bool late = (ct >> 2) != kbF;
                f16x8 a0 = late ? aL0 : aF0;
                f16x8 a1 = late ? aL1 : aF1;
                acc[0][ni] = __builtin_amdgcn_mfma_f32_16x16x32_f16(a0, bb, acc[0][ni], 0, 0, 0);
                acc[1][ni] = __builtin_amdgcn_mfma_f32_16x16x32_f16(a1, bb, acc[1][ni], 0, 0, 0);
            }
        }
        if (tt < 15) {
            int nb = cur ^ 1;
            *(f16x8*)&sA[nb][srow][sc8] = rA0;
            *(f16x8*)&sA[nb][32 + srow][sc8] = rA1;
            *(f16x8*)&sA[nb][64 + srow][sc8] = rA2;
            *(f16x8*)&sB[nb][srow][sc8] = rB0;
            *(f16x8*)&sB[nb][srow + 32][sc8] = rB1;
            __syncthreads();
        }
    }
    __syncthreads();

    #pragma unroll
    for (int m = 0; m < 2; ++m)
        #pragma unroll
        for (int ni = 0; ni < 3; ++ni)
            #pragma unroll
            for (int r = 0; r < 4; ++r)
                sZ[m * 16 + kg * 4 + r][(w * 3 + ni) * 16 + ln] = (_Float16)acc[m][ni][r];

    f32x4 e[2];
    e[0] = (f32x4){0.f, 0.f, 0.f, 0.f};
    e[1] = (f32x4){0.f, 0.f, 0.f, 0.f};
    for (int kc = 0; kc < 192; kc += 64) {
        #pragma unroll
        for (int it2 = 0; it2 < 2; ++it2) {
            int idx = it2 * 256 + tid; int row = idx >> 3, c8 = (idx & 7) * 8;
            *(f16x8*)&sW[row][c8] = *(const f16x8*)&wuhT[(size_t)row * 192 + kc + c8];
        }
        __syncthreads();
        #pragma unroll
        for (int ks = 0; ks < 4; ++ks) {
            int ko = ks * 16 + kg * 4;
            f16x4 az0 = *(const f16x4*)&sZ[ln][kc + ko];
            f16x4 az1 = *(const f16x4*)&sZ[16 + ln][kc + ko];
            f16x4 bw  = *(const f16x4*)&sW[w * 16 + ln][ko];
            e[0] = __builtin_amdgcn_mfma_f32_16x16x16f16(az0, bw, e[0], 0, 0, 0);
            e[1] = __builtin_amdgcn_mfma_f32_16x16x16f16(az1, bw, e[1], 0, 0, 0);
        }
        __syncthreads();
    }

    int o = w * 16 + ln;
    float w0 = sWX[o], w1 = sWX[64 + o], w2 = sWX[128 + o], bi = sBias[o];
    #pragma unroll
    for (int m = 0; m < 2; ++m) {
        alignas(8) _Float16 hb[4];
        #pragma unroll
        for (int r = 0; r < 4; ++r) {
            int il = m * 16 + kg * 4 + r;
            float pre = e[m][r] + w0 * sS2[0][il] + w1 * sS2[1][il] + w2 * sS2[2][il] + bi;
            float hc = tanhf(pre);
            size_t gi = ((size_t)((b << 10) + i0 + il)) * H_ + o;
            float z = zb[gi], hold = h[gi];
            float hn = z * hc + (1.0f - z) * hold;
            h[gi] = hn;
            hb[r] = (_Float16)hn;
        }
        *(f16x4*)&HtOut[((size_t)(b * 64 + o) << 10) + i0 + m * 16 + kg * 4] = *(f16x4*)&hb[0];
    }
}

// out[(b*12+tt)*1024 + i] = h[b][i][:] @ W_dec[:,tt] + b_dec[tt]
__global__ __launch_bounds__(256) void k_dec(const float* __restrict__ h,
                                             const float* __restrict__ Wd,
                                             const float* __restrict__ bd,
                                             float* __restrict__ out) {
    int bx = blockIdx.x;
    int b = bx >> 4, it = bx & 15; int i0 = it * 64;
    __shared__ float hs[64][65];
    __shared__ float Wds[64][12];
    __shared__ float bds[12];
    int tid = threadIdx.x;
    for (int idx = tid; idx < 4096; idx += 256) {
        int r = idx >> 6, c = idx & 63;
        hs[r][c] = h[(size_t)(b * N_ + i0 + r) * H_ + c];
    }
    for (int idx = tid; idx < 768; idx += 256)
        Wds[idx / 12][idx % 12] = Wd[idx];
    if (tid < 12) bds[tid] = bd[tid];
    __syncthreads();
    for (int oidx = tid; oidx < 768; oidx += 256) {
        int i = oidx & 63, tt = oidx >> 6;
        float acc = bds[tt];
        #pragma unroll
        for (int c = 0; c < 64; ++c) acc += hs[i][c] * Wds[c][tt];
        out[(size_t)(b * T_ + tt) * N_ + i0 + i] = acc;
    }
}

extern "C" void kernel_launch(void* const* d_in, const int* in_sizes, int n_in,
                              void* d_out, int out_size, void* d_ws, size_t ws_size,
                              hipStream_t stream) {
    const float* x  = (const float*)d_in[0];
    const float* G  = (const float*)d_in[1];
    const float* A  = (const float*)d_in[2];
    const float* Wg = (const float*)d_in[3];
    const float* bg = (const float*)d_in[4];
    const float* Wu = (const float*)d_in[5];
    const float* bu = (const float*)d_in[6];
    const float* Wd = (const float*)d_in[7];
    const float* bd = (const float*)d_in[8];
    float* out = (float*)d_out;
    float* ws  = (float*)d_ws;

    float* h   = ws + OFF_H;
    float* zb  = ws + OFF_ZB;
    float* S2  = ws + OFF_S2;
    float* wxb = ws + OFF_WX;
    _Float16* HtA  = (_Float16*)(ws + OFF_HTA);
    _Float16* HtB  = (_Float16*)(ws + OFF_HTB);
    _Float16* S1   = (_Float16*)(ws + OFF_S1);
    _Float16* wghT = (_Float16*)(ws + OFF_WGT);
    _Float16* wuhT = (_Float16*)(ws + OFF_WUT);
    _Float16* GfT  = (_Float16*)(ws + OFF_GT);
    _Float16* AG   = (_Float16*)(ws + OFF_AG);

    hipMemsetAsync(h, 0, (size_t)B_ * N_ * H_ * sizeof(float), stream);
    hipMemsetAsync((void*)HtA, 0, (size_t)B_ * N_ * H_ * sizeof(_Float16), stream);
    k_repack<<<147, 256, 0, stream>>>(Wg, Wu, wghT, wuhT, wxb);
    k_gtr<<<768, 256, 0, stream>>>(G, GfT);
    k_ag<<<3072, 256, 0, stream>>>(A, GfT, AG);
    k_s1b<<<96, 256, 0, stream>>>(G, x, S1);
    k_s2b<<<256, 256, 0, stream>>>(A, S1, S2);

    for (int t = 0; t < T_; ++t) {
        k_fzr<<<512, 256, 0, stream>>>(AG, HtA, wghT, wxb, bg, S2, h, zb, HtB, t);
        k_fup<<<512, 256, 0, stream>>>(AG, HtB, wuhT, wxb, bu, S2, zb, h, HtA, t);
    }
    k_dec<<<256, 256, 0, stream>>>(h, Wd, bd, out);
}

// Round 11
// 823.291 us; speedup vs baseline: 2.3826x; 1.1669x over previous
//
#include <hip/hip_runtime.h>

#define B_  16
#define T_  12
#define N_  1024
#define K_  3
#define H_  64
#define DIN 65
#define KH  192   // K_*H_
#define OG  128   // 2*H_

typedef _Float16 f16x4 __attribute__((ext_vector_type(4)));
typedef _Float16 f16x8 __attribute__((ext_vector_type(8)));
typedef float    f32x4 __attribute__((ext_vector_type(4)));

// ---- workspace offsets (float units), total 39,176,768 f = 156.7 MB (< ~268 MB evidenced) ----
static const size_t OFF_H   = 0;          // f32 h    [16][1024][64]
static const size_t OFF_ZB  = 1048576;    // f32 z    [16][1024][64]
static const size_t OFF_S2  = 2097152;    // f32 S2   [16][3][12][1024] (x1024)
static const size_t OFF_HTA = 2686976;    // f16 HtA  [16][64][1024]
static const size_t OFF_HTB = 3211264;    // f16 HtB  [16][64][1024]
static const size_t OFF_S1  = 3735552;    // f16 S1   [3][192][1024]
static const size_t OFF_WGT = 4030464;    // f16 wghT [128][192] (/1024)
static const size_t OFF_WUT = 4042752;    // f16 wuhT [64][192]  (/1024)
static const size_t OFF_WX  = 4048896;    // f32 wx (576)
static const size_t OFF_GT  = 4049472;    // f16 GfT  [3][1024][1024]  (G transposed)
static const size_t OFF_AG  = 5622336;    // f16 AG   [16][3][1024][1024] = 1024*A@G
static const size_t OFF_AF  = 30788160;   // f16 Af   [16][1024][1024]   = 1024*A

// Repack weights: transposed f16 h-part + f32 x-part rows, all pre-divided by 1024.
__global__ __launch_bounds__(256) void k_repack(const float* __restrict__ Wg,
                                                const float* __restrict__ Wu,
                                                _Float16* __restrict__ wghT,
                                                _Float16* __restrict__ wuhT,
                                                float* __restrict__ wx) {
    const float inv = 1.0f / 1024.0f;
    int idx = blockIdx.x * 256 + threadIdx.x;
    if (idx < 128 * 192) {
        int o = idx / 192, d = idx % 192;
        int k = d / 64, c = d % 64;
        wghT[idx] = (_Float16)(Wg[(size_t)(k * DIN + 1 + c) * OG + o] * inv);
    } else if (idx < 128 * 192 + 64 * 192) {
        int j = idx - 128 * 192;
        int o = j / 192, d = j % 192;
        int k = d / 64, c = d % 64;
        wuhT[j] = (_Float16)(Wu[(size_t)(k * DIN + 1 + c) * H_ + o] * inv);
    } else if (idx < 128 * 192 + 64 * 192 + 576) {
        int j = idx - 128 * 192 - 64 * 192;
        if (j < 384) { int k = j >> 7, o = j & 127; wx[j] = Wg[(size_t)(k * DIN) * OG + o] * inv; }
        else { int j2 = j - 384; int k = j2 >> 6, o = j2 & 63; wx[j] = Wu[(size_t)(k * DIN) * H_ + o] * inv; }
    }
}

// A f32 -> f16 (x1024), once. grid 8192.
__global__ __launch_bounds__(256) void k_acvt(const float* __restrict__ A,
                                              _Float16* __restrict__ Af) {
    size_t idx = ((size_t)blockIdx.x * 256 + threadIdx.x) * 8;
    float4 a = *(const float4*)&A[idx];
    float4 c = *(const float4*)&A[idx + 4];
    f16x8 v = {(_Float16)(a.x*1024.f), (_Float16)(a.y*1024.f), (_Float16)(a.z*1024.f), (_Float16)(a.w*1024.f),
               (_Float16)(c.x*1024.f), (_Float16)(c.y*1024.f), (_Float16)(c.z*1024.f), (_Float16)(c.w*1024.f)};
    *(f16x8*)&Af[idx] = v;
}

// G transpose-convert: GfT[k][j][p] = f16(G[k][p][j]). grid 768 = 3*16*16.
__global__ __launch_bounds__(256) void k_gtr(const float* __restrict__ G,
                                             _Float16* __restrict__ GfT) {
    int bx = blockIdx.x;
    int kk = bx >> 8, rem = bx & 255, ti = rem >> 4, tj = rem & 15;
    int i0 = ti * 64, j0 = tj * 64;
    __shared__ _Float16 s[64][72];
    int tid = threadIdx.x;
    int r = tid >> 2, cb = (tid & 3) * 16;
    const float* Gp = G + ((size_t)kk << 20) + ((size_t)(i0 + r) << 10) + j0 + cb;
    #pragma unroll
    for (int q = 0; q < 4; ++q) {
        float4 v = *(const float4*)&Gp[q * 4];
        f16x4 hv = {(_Float16)v.x, (_Float16)v.y, (_Float16)v.z, (_Float16)v.w};
        *(f16x4*)&s[r][cb + q * 4] = hv;
    }
    __syncthreads();
    alignas(16) _Float16 tmp[16];
    #pragma unroll
    for (int q = 0; q < 16; ++q) tmp[q] = s[cb + q][r];
    _Float16* outp = GfT + ((size_t)kk << 20) + ((size_t)(j0 + r) << 10) + i0 + cb;
    *(f16x8*)&outp[0] = *(f16x8*)&tmp[0];
    *(f16x8*)&outp[8] = *(f16x8*)&tmp[8];
}

// AG[b][k] = Af[b] @ G[k]  in f16 (Af pre-scaled x1024). 128x128 tiles, reg-staged dbuf.
// XCD-chunked swizzle: 3072 blocks, 8 XCDs, 384-block contiguous chunks per XCD.
__global__ __launch_bounds__(256) void k_ag(const _Float16* __restrict__ Af,
                                            const _Float16* __restrict__ GfT,
                                            _Float16* __restrict__ AG) {
    int bxr = blockIdx.x;
    int bx = (bxr & 7) * 384 + (bxr >> 3);     // bijective (3072 % 8 == 0)
    int inst = bx >> 6, tile = bx & 63;
    int b = inst / 3, kk = inst % 3;
    int i0 = (tile >> 3) * 128, j0 = (tile & 7) * 128;
    __shared__ _Float16 sA[2][128][72], sB[2][128][72];
    int tid = threadIdx.x;
    int w = tid >> 6, lane = tid & 63, ln = lane & 15, kg = lane >> 4;
    int mq = (w & 1) * 64, nq = (w >> 1) * 64;
    int srow = tid >> 1, cb = (tid & 1) * 32;
    const _Float16* qa = Af  + ((size_t)b << 20)  + ((size_t)(i0 + srow) << 10) + cb;
    const _Float16* qb = GfT + ((size_t)kk << 20) + ((size_t)(j0 + srow) << 10) + cb;

    f32x4 acc[4][4];
    #pragma unroll
    for (int mt = 0; mt < 4; ++mt)
        #pragma unroll
        for (int nt = 0; nt < 4; ++nt) acc[mt][nt] = (f32x4){0.f, 0.f, 0.f, 0.f};

    f16x8 ra[4], rb[4];
    #pragma unroll
    for (int q = 0; q < 4; ++q) { ra[q] = *(const f16x8*)&qa[q * 8]; rb[q] = *(const f16x8*)&qb[q * 8]; }
    #pragma unroll
    for (int q = 0; q < 4; ++q) {
        *(f16x8*)&sA[0][srow][cb + q * 8] = ra[q];
        *(f16x8*)&sB[0][srow][cb + q * 8] = rb[q];
    }
    __syncthreads();

    for (int tt = 0; tt < 16; ++tt) {
        int cur = tt & 1;
        if (tt < 15) {
            int kn = (tt + 1) * 64;
            #pragma unroll
            for (int q = 0; q < 4; ++q) { ra[q] = *(const f16x8*)&qa[kn + q * 8]; rb[q] = *(const f16x8*)&qb[kn + q * 8]; }
        }
        #pragma unroll
        for (int ks = 0; ks < 2; ++ks) {
            int ko = ks * 32 + kg * 8;
            f16x8 a[4], bfr[4];
            #pragma unroll
            for (int mt = 0; mt < 4; ++mt) a[mt] = *(const f16x8*)&sA[cur][mq + mt * 16 + ln][ko];
            #pragma unroll
            for (int nt = 0; nt < 4; ++nt) bfr[nt] = *(const f16x8*)&sB[cur][nq + nt * 16 + ln][ko];
            #pragma unroll
            for (int mt = 0; mt < 4; ++mt)
                #pragma unroll
                for (int nt = 0; nt < 4; ++nt)
                    acc[mt][nt] = __builtin_amdgcn_mfma_f32_16x16x32_f16(a[mt], bfr[nt], acc[mt][nt], 0, 0, 0);
        }
        if (tt < 15) {
            int nb = cur ^ 1;
            #pragma unroll
            for (int q = 0; q < 4; ++q) {
                *(f16x8*)&sA[nb][srow][cb + q * 8] = ra[q];
                *(f16x8*)&sB[nb][srow][cb + q * 8] = rb[q];
            }
            __syncthreads();
        }
    }

    _Float16* outp = AG + ((size_t)(b * 3 + kk) << 20);
    #pragma unroll
    for (int mt = 0; mt < 4; ++mt)
        #pragma unroll
        for (int r = 0; r < 4; ++r) {
            int i = i0 + mq + mt * 16 + kg * 4 + r;
            #pragma unroll
            for (int nt = 0; nt < 4; ++nt) {
                int j = j0 + nq + nt * 16 + ln;
                outp[((size_t)i << 10) + j] = (_Float16)acc[mt][nt][r];
            }
        }
}

// S1[k][m][i] = sum_j G[k][i][j] x[m][j]  (f16 out). grid 96
__global__ __launch_bounds__(256) void k_s1b(const float* __restrict__ G,
                                             const float* __restrict__ x,
                                             _Float16* __restrict__ S1) {
    int bx = blockIdx.x;
    int nh = bx & 1, it = (bx >> 1) & 15, kk = bx >> 5;
    int i0 = it * 64, m0 = nh * 96;
    __shared__ _Float16 sA[64][72], sB[96][72];
    int tid = threadIdx.x, wid = tid >> 6, ln = tid & 15, kl = (tid & 63) >> 4;
    const float* Gk = G + (size_t)kk * N_ * N_;
    f32x4 acc[6];
    #pragma unroll
    for (int n = 0; n < 6; ++n) acc[n] = (f32x4){0.f, 0.f, 0.f, 0.f};
    for (int kc = 0; kc < N_; kc += 64) {
        #pragma unroll
        for (int it2 = 0; it2 < 4; ++it2) {
            int idx = it2 * 256 + tid; int row = idx >> 4, c4 = (idx & 15) * 4;
            float4 g = *(const float4*)&Gk[(size_t)(i0 + row) * N_ + kc + c4];
            f16x4 hv = {(_Float16)g.x, (_Float16)g.y, (_Float16)g.z, (_Float16)g.w};
            *(f16x4*)&sA[row][c4] = hv;
        }
        #pragma unroll
        for (int it2 = 0; it2 < 6; ++it2) {
            int idx = it2 * 256 + tid; int row = idx >> 4, c4 = (idx & 15) * 4;
            float4 g = *(const float4*)&x[(size_t)(m0 + row) * N_ + kc + c4];
            f16x4 hv = {(_Float16)g.x, (_Float16)g.y, (_Float16)g.z, (_Float16)g.w};
            *(f16x4*)&sB[row][c4] = hv;
        }
        __syncthreads();
        #pragma unroll
        for (int ks = 0; ks < 4; ++ks) {
            int ko = ks * 16 + kl * 4;
            f16x4 a = *(const f16x4*)&sA[wid * 16 + ln][ko];
            #pragma unroll
            for (int n = 0; n < 6; ++n) {
                f16x4 b = *(const f16x4*)&sB[n * 16 + ln][ko];
                acc[n] = __builtin_amdgcn_mfma_f32_16x16x16f16(a, b, acc[n], 0, 0, 0);
            }
        }
        __syncthreads();
    }
    #pragma unroll
    for (int n = 0; n < 6; ++n) {
        int m = m0 + n * 16 + ln;
        #pragma unroll
        for (int r = 0; r < 4; ++r) {
            int i = i0 + wid * 16 + kl * 4 + r;
            S1[(((size_t)kk * 192 + m) << 10) + i] = (_Float16)acc[n][r];
        }
    }
}

// S2[b][k][t][i] = sum_j Af[b][i][j] S1[k][b*12+t][j]  (f32 out, Af pre-scaled). grid 256
__global__ __launch_bounds__(256) void k_s2b(const _Float16* __restrict__ Af,
                                             const _Float16* __restrict__ S1,
                                             float* __restrict__ S2) {
    int bx = blockIdx.x; int it = bx & 15, b = bx >> 4; int i0 = it * 64;
    __shared__ _Float16 sA[64][72], sB[48][72];
    int tid = threadIdx.x, wid = tid >> 6, ln = tid & 15, kl = (tid & 63) >> 4;
    f32x4 acc[3];
    #pragma unroll
    for (int n = 0; n < 3; ++n) acc[n] = (f32x4){0.f, 0.f, 0.f, 0.f};
    for (int kc = 0; kc < N_; kc += 64) {
        #pragma unroll
        for (int it2 = 0; it2 < 2; ++it2) {
            int idx = it2 * 256 + tid; int row = idx >> 3, c8 = (idx & 7) * 8;
            *(uint4*)&sA[row][c8] = *(const uint4*)&Af[((size_t)b << 20) + ((size_t)(i0 + row) << 10) + kc + c8];
        }
        for (int idx = tid; idx < 288; idx += 256) {
            int row = idx >> 3, c8 = (idx & 7) * 8;
            int kq = row / 12, tq = row - kq * 12;
            *(uint4*)&sB[row][c8] = *(const uint4*)&S1[(((size_t)kq * 192 + b * T_ + tq) << 10) + kc + c8];
        }
        __syncthreads();
        #pragma unroll
        for (int ks = 0; ks < 4; ++ks) {
            int ko = ks * 16 + kl * 4;
            f16x4 a = *(const f16x4*)&sA[wid * 16 + ln][ko];
            #pragma unroll
            for (int n = 0; n < 3; ++n) {
                f16x4 b = *(const f16x4*)&sB[n * 16 + ln][ko];
                acc[n] = __builtin_amdgcn_mfma_f32_16x16x16f16(a, b, acc[n], 0, 0, 0);
            }
        }
        __syncthreads();
    }
    #pragma unroll
    for (int n = 0; n < 3; ++n) {
        int col = n * 16 + ln;
        if (col < 36) {
            int kq = col / 12, tq = col - kq * 12;
            #pragma unroll
            for (int r = 0; r < 4; ++r) {
                int i = i0 + wid * 16 + kl * 4 + r;
                S2[(((size_t)(b * 3 + kq) * T_ + tq) << 10) + i] = acc[n][r];
            }
        }
    }
}

// Fused gate half-step, 16 rows/block: Z(16x192) = sum_k AG[b,k]@HtIn; epi -> zb, HtOut.
// grid 1024: it = bx&63, b = bx>>6.
__global__ __launch_bounds__(256) void k_fzr(const _Float16* __restrict__ AG,
                                             const _Float16* __restrict__ HtIn,
                                             const _Float16* __restrict__ wghT,
                                             const float* __restrict__ wx,
                                             const float* __restrict__ bg,
                                             const float* __restrict__ S2,
                                             const float* __restrict__ h,
                                             float* __restrict__ zb,
                                             _Float16* __restrict__ HtOut, int t) {
    int bx = blockIdx.x; int it = bx & 63, b = bx >> 6; int i0 = it * 16;
    __shared__ __align__(16) char smem[32256];
    _Float16 (*sA)[48][72] = reinterpret_cast<_Float16(*)[48][72]>(smem);          // 13824 B
    _Float16 (*sB)[64][72] = reinterpret_cast<_Float16(*)[64][72]>(smem + 13824);  // 18432 B
    _Float16 (*sZ)[200]    = reinterpret_cast<_Float16(*)[200]>(smem);             // 6400 B (phase 2)
    _Float16 (*sW)[72]     = reinterpret_cast<_Float16(*)[72]>(smem + 6400);       // 18432 B
    __shared__ float sS2[3][16];
    __shared__ float sWX[384];
    __shared__ float sBias[128];
    int tid = threadIdx.x;
    int w = tid >> 6, lane = tid & 63, ln = lane & 15, kg = lane >> 4;
    if (tid < 48) { int k = tid >> 4, il = tid & 15; sS2[k][il] = S2[(((size_t)(b * 3 + k) * T_ + t) << 10) + i0 + il]; }
    for (int q = tid; q < 384; q += 256) sWX[q] = wx[q];
    if (tid < 128) sBias[tid] = bg[tid];

    // A staging: 3 f16x4/thread. idx = q*256+tid -> row 0..47 (kb = row>>4), c4
    const _Float16* pA[3]; int c4A[3], rowA[3];
    #pragma unroll
    for (int q = 0; q < 3; ++q) {
        int idx = q * 256 + tid; rowA[q] = idx >> 4; c4A[q] = (idx & 15) * 4;
        int kb = rowA[q] >> 4, rloc = rowA[q] & 15;
        pA[q] = AG + ((size_t)(b * 3 + kb) << 20) + ((size_t)(i0 + rloc) << 10) + c4A[q];
    }
    // B staging: 2 f16x8/thread. idx = q*256+tid -> row 0..63, c8
    const _Float16* pB[2]; int c8B[2], rowB[2];
    #pragma unroll
    for (int q = 0; q < 2; ++q) {
        int idx = q * 256 + tid; rowB[q] = idx >> 3; c8B[q] = (idx & 7) * 8;
        pB[q] = HtIn + ((size_t)b << 16) + ((size_t)rowB[q] << 10) + c8B[q];
    }

    f32x4 acc[3];
    #pragma unroll
    for (int n = 0; n < 3; ++n) acc[n] = (f32x4){0.f, 0.f, 0.f, 0.f};

    f16x4 ra[3]; f16x8 rb[2];
    #pragma unroll
    for (int q = 0; q < 3; ++q) ra[q] = *(const f16x4*)pA[q];
    #pragma unroll
    for (int q = 0; q < 2; ++q) rb[q] = *(const f16x8*)pB[q];
    #pragma unroll
    for (int q = 0; q < 3; ++q) *(f16x4*)&sA[0][rowA[q]][c4A[q]] = ra[q];
    #pragma unroll
    for (int q = 0; q < 2; ++q) *(f16x8*)&sB[0][rowB[q]][c8B[q]] = rb[q];
    __syncthreads();

    int kbF = (w * 3) >> 2, kbL = (w * 3 + 2) >> 2;
    for (int tt = 0; tt < 16; ++tt) {
        int cur = tt & 1;
        if (tt < 15) {
            int kn = (tt + 1) * 64;
            #pragma unroll
            for (int q = 0; q < 3; ++q) ra[q] = *(const f16x4*)&pA[q][kn];
            #pragma unroll
            for (int q = 0; q < 2; ++q) rb[q] = *(const f16x8*)&pB[q][kn];
        }
        #pragma unroll
        for (int ks = 0; ks < 2; ++ks) {
            int ko = ks * 32 + kg * 8;
            f16x8 aF = *(const f16x8*)&sA[cur][kbF * 16 + ln][ko];
            f16x8 aL = *(const f16x8*)&sA[cur][kbL * 16 + ln][ko];
            #pragma unroll
            for (int ni = 0; ni < 3; ++ni) {
                int ct = w * 3 + ni;
                f16x8 bb = *(const f16x8*)&sB[cur][(ct & 3) * 16 + ln][ko];
                f16x8 a = ((ct >> 2) != kbF) ? aL : aF;
                acc[ni] = __builtin_amdgcn_mfma_f32_16x16x32_f16(a, bb, acc[ni], 0, 0, 0);
            }
        }
        if (tt < 15) {
            int nb = cur ^ 1;
            #pragma unroll
            for (int q = 0; q < 3; ++q) *(f16x4*)&sA[nb][rowA[q]][c4A[q]] = ra[q];
            #pragma unroll
            for (int q = 0; q < 2; ++q) *(f16x8*)&sB[nb][rowB[q]][c8B[q]] = rb[q];
            __syncthreads();
        }
    }
    __syncthreads();   // drain last chunk before aliasing writes

    #pragma unroll
    for (int ni = 0; ni < 3; ++ni)
        #pragma unroll
        for (int r = 0; r < 4; ++r)
            sZ[kg * 4 + r][(w * 3 + ni) * 16 + ln] = (_Float16)acc[ni][r];

    f32x4 e[2];
    e[0] = (f32x4){0.f, 0.f, 0.f, 0.f};
    e[1] = (f32x4){0.f, 0.f, 0.f, 0.f};
    for (int kc = 0; kc < 192; kc += 64) {
        #pragma unroll
        for (int it2 = 0; it2 < 4; ++it2) {
            int idx = it2 * 256 + tid; int row = idx >> 3, c8 = (idx & 7) * 8;
            *(f16x8*)&sW[row][c8] = *(const f16x8*)&wghT[(size_t)row * 192 + kc + c8];
        }
        __syncthreads();
        #pragma unroll
        for (int ks = 0; ks < 4; ++ks) {
            int ko = ks * 16 + kg * 4;
            f16x4 az  = *(const f16x4*)&sZ[ln][kc + ko];
            f16x4 bw0 = *(const f16x4*)&sW[w * 32 + ln][ko];
            f16x4 bw1 = *(const f16x4*)&sW[w * 32 + 16 + ln][ko];
            e[0] = __builtin_amdgcn_mfma_f32_16x16x16f16(az, bw0, e[0], 0, 0, 0);
            e[1] = __builtin_amdgcn_mfma_f32_16x16x16f16(az, bw1, e[1], 0, 0, 0);
        }
        __syncthreads();
    }

    #pragma unroll
    for (int n = 0; n < 2; ++n) {
        int o = w * 32 + n * 16 + ln;
        float w0 = sWX[o], w1 = sWX[128 + o], w2 = sWX[256 + o], bi = sBias[o];
        if (o < H_) {
            #pragma unroll
            for (int r = 0; r < 4; ++r) {
                int il = kg * 4 + r;
                float pre = e[n][r] + w0 * sS2[0][il] + w1 * sS2[1][il] + w2 * sS2[2][il] + bi;
                float v = 1.0f / (1.0f + expf(-pre));
                zb[((size_t)((b << 10) + i0 + il)) * H_ + o] = v;
            }
        } else {
            int c = o - H_;
            alignas(8) _Float16 hb[4];
            #pragma unroll
            for (int r = 0; r < 4; ++r) {
                int il = kg * 4 + r;
                float pre = e[n][r] + w0 * sS2[0][il] + w1 * sS2[1][il] + w2 * sS2[2][il] + bi;
                float v = 1.0f / (1.0f + expf(-pre));
                hb[r] = (_Float16)(v * h[((size_t)((b << 10) + i0 + il)) * H_ + c]);
            }
            *(f16x4*)&HtOut[((size_t)(b * 64 + c) << 10) + i0 + kg * 4] = *(f16x4*)&hb[0];
        }
    }
}

// Fused update half-step, 16 rows/block. grid 1024.
__global__ __launch_bounds__(256) void k_fup(const _Float16* __restrict__ AG,
                                             const _Float16* __restrict__ HtIn,
                                             const _Float16* __restrict__ wuhT,
                                             const float* __restrict__ wx,
                                             const float* __restrict__ bu,
                                             const float* __restrict__ S2,
                                             const float* __restrict__ zb,
                                             float* __restrict__ h,
                                             _Float16* __restrict__ HtOut, int t) {
    int bx = blockIdx.x; int it = bx & 63, b = bx >> 6; int i0 = it * 16;
    __shared__ __align__(16) char smem[32256];
    _Float16 (*sA)[48][72] = reinterpret_cast<_Float16(*)[48][72]>(smem);
    _Float16 (*sB)[64][72] = reinterpret_cast<_Float16(*)[64][72]>(smem + 13824);
    _Float16 (*sZ)[200]    = reinterpret_cast<_Float16(*)[200]>(smem);
    _Float16 (*sW)[72]     = reinterpret_cast<_Float16(*)[72]>(smem + 6400);
    __shared__ float sS2[3][16];
    __shared__ float sWX[192];
    __shared__ float sBias[64];
    int tid = threadIdx.x;
    int w = tid >> 6, lane = tid & 63, ln = lane & 15, kg = lane >> 4;
    if (tid < 48) { int k = tid >> 4, il = tid & 15; sS2[k][il] = S2[(((size_t)(b * 3 + k) * T_ + t) << 10) + i0 + il]; }
    if (tid < 192) sWX[tid] = wx[384 + tid];
    if (tid < 64) sBias[tid] = bu[tid];

    const _Float16* pA[3]; int c4A[3], rowA[3];
    #pragma unroll
    for (int q = 0; q < 3; ++q) {
        int idx = q * 256 + tid; rowA[q] = idx >> 4; c4A[q] = (idx & 15) * 4;
        int kb = rowA[q] >> 4, rloc = rowA[q] & 15;
        pA[q] = AG + ((size_t)(b * 3 + kb) << 20) + ((size_t)(i0 + rloc) << 10) + c4A[q];
    }
    const _Float16* pB[2]; int c8B[2], rowB[2];
    #pragma unroll
    for (int q = 0; q < 2; ++q) {
        int idx = q * 256 + tid; rowB[q] = idx >> 3; c8B[q] = (idx & 7) * 8;
        pB[q] = HtIn + ((size_t)b << 16) + ((size_t)rowB[q] << 10) + c8B[q];
    }

    f32x4 acc[3];
    #pragma unroll
    for (int n = 0; n < 3; ++n) acc[n] = (f32x4){0.f, 0.f, 0.f, 0.f};

    f16x4 ra[3]; f16x8 rb[2];
    #pragma unroll
    for (int q = 0; q < 3; ++q) ra[q] = *(const f16x4*)pA[q];
    #pragma unroll
    for (int q = 0; q < 2; ++q) rb[q] = *(const f16x8*)pB[q];
    #pragma unroll
    for (int q = 0; q < 3; ++q) *(f16x4*)&sA[0][rowA[q]][c4A[q]] = ra[q];
    #pragma unroll
    for (int q = 0; q < 2; ++q) *(f16x8*)&sB[0][rowB[q]][c8B[q]] = rb[q];
    __syncthreads();

    int kbF = (w * 3) >> 2, kbL = (w * 3 + 2) >> 2;
    for (int tt = 0; tt < 16; ++tt) {
        int cur = tt & 1;
        if (tt < 15) {
            int kn = (tt + 1) * 64;
            #pragma unroll
            for (int q = 0; q < 3; ++q) ra[q] = *(const f16x4*)&pA[q][kn];
            #pragma unroll
            for (int q = 0; q < 2; ++q) rb[q] = *(const f16x8*)&pB[q][kn];
        }
        #pragma unroll
        for (int ks = 0; ks < 2; ++ks) {
            int ko = ks * 32 + kg * 8;
            f16x8 aF = *(const f16x8*)&sA[cur][kbF * 16 + ln][ko];
            f16x8 aL = *(const f16x8*)&sA[cur][kbL * 16 + ln][ko];
            #pragma unroll
            for (int ni = 0; ni < 3; ++ni) {
                int ct = w * 3 + ni;
                f16x8 bb = *(const f16x8*)&sB[cur][(ct & 3) * 16 + ln][ko];
                f16x8 a = ((ct >> 2) != kbF) ? aL : aF;
                acc[ni] = __builtin_amdgcn_mfma_f32_16x16x32_f16(a, bb, acc[ni], 0, 0, 0);
            }
        }
        if (tt < 15) {
            int nb = cur ^ 1;
            #pragma unroll
            for (int q = 0; q < 3; ++q) *(f16x4*)&sA[nb][rowA[q]][c4A[q]] = ra[q];
            #pragma unroll
            for (int q = 0; q < 2; ++q) *(f16x8*)&sB[nb][rowB[q]][c8B[q]] = rb[q];
            __syncthreads();
        }
    }
    __syncthreads();

    #pragma unroll
    for (int ni = 0; ni < 3; ++ni)
        #pragma unroll
        for (int r = 0; r < 4; ++r)
            sZ[kg * 4 + r][(w * 3 + ni) * 16 + ln] = (_Float16)acc[ni][r];

    f32x4 e = (f32x4){0.f, 0.f, 0.f, 0.f};
    for (int kc = 0; kc < 192; kc += 64) {
        #pragma unroll
        for (int it2 = 0; it2 < 2; ++it2) {
            int idx = it2 * 256 + tid; int row = idx >> 3, c8 = (idx & 7) * 8;
            *(f16x8*)&sW[row][c8] = *(const f16x8*)&wuhT[(size_t)row * 192 + kc + c8];
        }
        __syncthreads();
        #pragma unroll
        for (int ks = 0; ks < 4; ++ks) {
            int ko = ks * 16 + kg * 4;
            f16x4 az = *(const f16x4*)&sZ[ln][kc + ko];
            f16x4 bw = *(const f16x4*)&sW[w * 16 + ln][ko];
            e = __builtin_amdgcn_mfma_f32_16x16x16f16(az, bw, e, 0, 0, 0);
        }
        __syncthreads();
    }

    int o = w * 16 + ln;
    float w0 = sWX[o], w1 = sWX[64 + o], w2 = sWX[128 + o], bi = sBias[o];
    alignas(8) _Float16 hb[4];
    #pragma unroll
    for (int r = 0; r < 4; ++r) {
        int il = kg * 4 + r;
        float pre = e[r] + w0 * sS2[0][il] + w1 * sS2[1][il] + w2 * sS2[2][il] + bi;
        float hc = tanhf(pre);
        size_t gi = ((size_t)((b << 10) + i0 + il)) * H_ + o;
        float z = zb[gi], hold = h[gi];
        float hn = z * hc + (1.0f - z) * hold;
        h[gi] = hn;
        hb[r] = (_Float16)hn;
    }
    *(f16x4*)&HtOut[((size_t)(b * 64 + o) << 10) + i0 + kg * 4] = *(f16x4*)&hb[0];
}

// out[(b*12+tt)*1024 + i] = h[b][i][:] @ W_dec[:,tt] + b_dec[tt]
__global__ __launch_bounds__(256) void k_dec(const float* __restrict__ h,
                                             const float* __restrict__ Wd,
                                             const float* __restrict__ bd,
                                             float* __restrict__ out) {
    int bx = blockIdx.x;
    int b = bx >> 4, it = bx & 15; int i0 = it * 64;
    __shared__ float hs[64][65];
    __shared__ float Wds[64][12];
    __shared__ float bds[12];
    int tid = threadIdx.x;
    for (int idx = tid; idx < 4096; idx += 256) {
        int r = idx >> 6, c = idx & 63;
        hs[r][c] = h[(size_t)(b * N_ + i0 + r) * H_ + c];
    }
    for (int idx = tid; idx < 768; idx += 256)
        Wds[idx / 12][idx % 12] = Wd[idx];
    if (tid < 12) bds[tid] = bd[tid];
    __syncthreads();
    for (int oidx = tid; oidx < 768; oidx += 256) {
        int i = oidx & 63, tt = oidx >> 6;
        float acc = bds[tt];
        #pragma unroll
        for (int c = 0; c < 64; ++c) acc += hs[i][c] * Wds[c][tt];
        out[(size_t)(b * T_ + tt) * N_ + i0 + i] = acc;
    }
}

extern "C" void kernel_launch(void* const* d_in, const int* in_sizes, int n_in,
                              void* d_out, int out_size, void* d_ws, size_t ws_size,
                              hipStream_t stream) {
    const float* x  = (const float*)d_in[0];
    const float* G  = (const float*)d_in[1];
    const float* A  = (const float*)d_in[2];
    const float* Wg = (const float*)d_in[3];
    const float* bg = (const float*)d_in[4];
    const float* Wu = (const float*)d_in[5];
    const float* bu = (const float*)d_in[6];
    const float* Wd = (const float*)d_in[7];
    const float* bd = (const float*)d_in[8];
    float* out = (float*)d_out;
    float* ws  = (float*)d_ws;

    float* h   = ws + OFF_H;
    float* zb  = ws + OFF_ZB;
    float* S2  = ws + OFF_S2;
    float* wxb = ws + OFF_WX;
    _Float16* HtA  = (_Float16*)(ws + OFF_HTA);
    _Float16* HtB  = (_Float16*)(ws + OFF_HTB);
    _Float16* S1   = (_Float16*)(ws + OFF_S1);
    _Float16* wghT = (_Float16*)(ws + OFF_WGT);
    _Float16* wuhT = (_Float16*)(ws + OFF_WUT);
    _Float16* GfT  = (_Float16*)(ws + OFF_GT);
    _Float16* AG   = (_Float16*)(ws + OFF_AG);
    _Float16* Af   = (_Float16*)(ws + OFF_AF);

    hipMemsetAsync(h, 0, (size_t)B_ * N_ * H_ * sizeof(float), stream);
    hipMemsetAsync((void*)HtA, 0, (size_t)B_ * N_ * H_ * sizeof(_Float16), stream);
    k_repack<<<147, 256, 0, stream>>>(Wg, Wu, wghT, wuhT, wxb);
    k_gtr<<<768, 256, 0, stream>>>(G, GfT);
    k_acvt<<<8192, 256, 0, stream>>>(A, Af);
    k_ag<<<3072, 256, 0, stream>>>(Af, GfT, AG);
    k_s1b<<<96, 256, 0, stream>>>(G, x, S1);
    k_s2b<<<256, 256, 0, stream>>>(Af, S1, S2);

    for (int t = 0; t < T_; ++t) {
        k_fzr<<<1024, 256, 0, stream>>>(AG, HtA, wghT, wxb, bg, S2, h, zb, HtB, t);
        k_fup<<<1024, 256, 0, stream>>>(AG, HtB, wuhT, wxb, bu, S2, zb, h, HtA, t);
    }
    k_dec<<<256, 256, 0, stream>>>(h, Wd, bd, out);
}

// Round 13
// 800.113 us; speedup vs baseline: 2.4516x; 1.0290x over previous
//
#include <hip/hip_runtime.h>
#include <hip/hip_cooperative_groups.h>

namespace cg = cooperative_groups;

#define B_  16
#define T_  12
#define N_  1024
#define K_  3
#define H_  64
#define DIN 65
#define KH  192
#define OG  128

typedef _Float16 f16x4 __attribute__((ext_vector_type(4)));
typedef _Float16 f16x8 __attribute__((ext_vector_type(8)));
typedef float    f32x4 __attribute__((ext_vector_type(4)));

// ---- workspace offsets (float units), total ~156.7 MB (< ~268 MB evidenced) ----
static const size_t OFF_H   = 0;          // f32 h    [16][1024][64]  (fallback only)
static const size_t OFF_ZF  = 1048576;    // f16 zf   [16][64][1024]  (fallback only)
static const size_t OFF_S2  = 2097152;    // f32 S2   [16][3][12][1024] (x1024)
static const size_t OFF_HTA = 2686976;    // f16 HtA  [16][64][1024]
static const size_t OFF_HTB = 3211264;    // f16 HtB  [16][64][1024]
static const size_t OFF_S1  = 3735552;    // f16 S1   [3][192][1024]
static const size_t OFF_WGT = 4030464;    // f16 wghT [128][192] (/1024)
static const size_t OFF_WUT = 4042752;    // f16 wuhT [64][192]  (/1024)
static const size_t OFF_WX  = 4048896;    // f32 wx (576)
static const size_t OFF_GT  = 4049472;    // f16 GfT  [3][1024][1024]
static const size_t OFF_AG  = 5622336;    // f16 AG   [16][3][1024][1024]
static const size_t OFF_AF  = 30788160;   // f16 Af   [16][1024][1024] = 1024*A

// ============================================================================
// Fused preamble phase A: [s1b | gtr | repack | acvt] (mutually independent).
// s1b first so its latency-bound tail overlaps the BW-bound rest.
// grid = 96 + 768 + 147 + 8192 = 9203
// ============================================================================
__global__ __launch_bounds__(256) void k_pre(const float* __restrict__ A,
                                             const float* __restrict__ G,
                                             const float* __restrict__ x,
                                             const float* __restrict__ Wg,
                                             const float* __restrict__ Wu,
                                             _Float16* __restrict__ Af,
                                             _Float16* __restrict__ GfT,
                                             _Float16* __restrict__ S1,
                                             _Float16* __restrict__ wghT,
                                             _Float16* __restrict__ wuhT,
                                             float* __restrict__ wx) {
    __shared__ __align__(16) char smem[23040];
    int bx0 = blockIdx.x, tid = threadIdx.x;
    if (bx0 < 96) {
        // ---- s1b: S1[k][m][i] = sum_j G[k][i][j] x[m][j] ----
        int bx = bx0;
        int nh = bx & 1, it = (bx >> 1) & 15, kk = bx >> 5;
        int i0 = it * 64, m0 = nh * 96;
        _Float16 (*sA)[72] = reinterpret_cast<_Float16(*)[72]>(smem);
        _Float16 (*sB)[72] = reinterpret_cast<_Float16(*)[72]>(smem + 9216);
        int wid = tid >> 6, ln = tid & 15, kl = (tid & 63) >> 4;
        const float* Gk = G + (size_t)kk * N_ * N_;
        f32x4 acc[6];
        #pragma unroll
        for (int n = 0; n < 6; ++n) acc[n] = (f32x4){0.f, 0.f, 0.f, 0.f};
        for (int kc = 0; kc < N_; kc += 64) {
            #pragma unroll
            for (int it2 = 0; it2 < 4; ++it2) {
                int idx = it2 * 256 + tid; int row = idx >> 4, c4 = (idx & 15) * 4;
                float4 g = *(const float4*)&Gk[(size_t)(i0 + row) * N_ + kc + c4];
                f16x4 hv = {(_Float16)g.x, (_Float16)g.y, (_Float16)g.z, (_Float16)g.w};
                *(f16x4*)&sA[row][c4] = hv;
            }
            #pragma unroll
            for (int it2 = 0; it2 < 6; ++it2) {
                int idx = it2 * 256 + tid; int row = idx >> 4, c4 = (idx & 15) * 4;
                float4 g = *(const float4*)&x[(size_t)(m0 + row) * N_ + kc + c4];
                f16x4 hv = {(_Float16)g.x, (_Float16)g.y, (_Float16)g.z, (_Float16)g.w};
                *(f16x4*)&sB[row][c4] = hv;
            }
            __syncthreads();
            #pragma unroll
            for (int ks = 0; ks < 4; ++ks) {
                int ko = ks * 16 + kl * 4;
                f16x4 a = *(const f16x4*)&sA[wid * 16 + ln][ko];
                #pragma unroll
                for (int n = 0; n < 6; ++n) {
                    f16x4 b = *(const f16x4*)&sB[n * 16 + ln][ko];
                    acc[n] = __builtin_amdgcn_mfma_f32_16x16x16f16(a, b, acc[n], 0, 0, 0);
                }
            }
            __syncthreads();
        }
        #pragma unroll
        for (int n = 0; n < 6; ++n) {
            int m = m0 + n * 16 + ln;
            #pragma unroll
            for (int r = 0; r < 4; ++r) {
                int i = i0 + wid * 16 + kl * 4 + r;
                S1[(((size_t)kk * 192 + m) << 10) + i] = (_Float16)acc[n][r];
            }
        }
    } else if (bx0 < 864) {
        // ---- gtr: GfT[k][j][p] = f16(G[k][p][j]) ----
        int bx = bx0 - 96;
        int kk = bx >> 8, rem = bx & 255, ti = rem >> 4, tj = rem & 15;
        int i0 = ti * 64, j0 = tj * 64;
        _Float16 (*s)[72] = reinterpret_cast<_Float16(*)[72]>(smem);
        int r = tid >> 2, cb = (tid & 3) * 16;
        const float* Gp = G + ((size_t)kk << 20) + ((size_t)(i0 + r) << 10) + j0 + cb;
        #pragma unroll
        for (int q = 0; q < 4; ++q) {
            float4 v = *(const float4*)&Gp[q * 4];
            f16x4 hv = {(_Float16)v.x, (_Float16)v.y, (_Float16)v.z, (_Float16)v.w};
            *(f16x4*)&s[r][cb + q * 4] = hv;
        }
        __syncthreads();
        alignas(16) _Float16 tmp[16];
        #pragma unroll
        for (int q = 0; q < 16; ++q) tmp[q] = s[cb + q][r];
        _Float16* outp = GfT + ((size_t)kk << 20) + ((size_t)(j0 + r) << 10) + i0 + cb;
        *(f16x8*)&outp[0] = *(f16x8*)&tmp[0];
        *(f16x8*)&outp[8] = *(f16x8*)&tmp[8];
    } else if (bx0 < 1011) {
        // ---- repack ----
        const float inv = 1.0f / 1024.0f;
        int idx = (bx0 - 864) * 256 + tid;
        if (idx < 128 * 192) {
            int o = idx / 192, d = idx % 192;
            int k = d / 64, c = d % 64;
            wghT[idx] = (_Float16)(Wg[(size_t)(k * DIN + 1 + c) * OG + o] * inv);
        } else if (idx < 128 * 192 + 64 * 192) {
            int j = idx - 128 * 192;
            int o = j / 192, d = j % 192;
            int k = d / 64, c = d % 64;
            wuhT[j] = (_Float16)(Wu[(size_t)(k * DIN + 1 + c) * H_ + o] * inv);
        } else if (idx < 128 * 192 + 64 * 192 + 576) {
            int j = idx - 128 * 192 - 64 * 192;
            if (j < 384) { int k = j >> 7, o = j & 127; wx[j] = Wg[(size_t)(k * DIN) * OG + o] * inv; }
            else { int j2 = j - 384; int k = j2 >> 6, o = j2 & 63; wx[j] = Wu[(size_t)(k * DIN) * H_ + o] * inv; }
        }
    } else {
        // ---- acvt: Af = f16(1024*A) ----
        size_t idx = ((size_t)(bx0 - 1011) * 256 + tid) * 8;
        float4 a = *(const float4*)&A[idx];
        float4 c = *(const float4*)&A[idx + 4];
        f16x8 v = {(_Float16)(a.x*1024.f), (_Float16)(a.y*1024.f), (_Float16)(a.z*1024.f), (_Float16)(a.w*1024.f),
                   (_Float16)(c.x*1024.f), (_Float16)(c.y*1024.f), (_Float16)(c.z*1024.f), (_Float16)(c.w*1024.f)};
        *(f16x8*)&Af[idx] = v;
    }
}

// ============================================================================
// Fused phase B: [s2b | ag]. s2b first (small), ag with XCD-chunked swizzle.
// grid = 256 + 3072 = 3328
// ============================================================================
__global__ __launch_bounds__(256) void k_main(const _Float16* __restrict__ Af,
                                              const _Float16* __restrict__ GfT,
                                              _Float16* __restrict__ AG,
                                              const _Float16* __restrict__ S1,
                                              float* __restrict__ S2) {
    __shared__ __align__(16) char smem[73728];
    int bx0 = blockIdx.x, tid = threadIdx.x;
    if (bx0 < 256) {
        // ---- s2b ----
        int bx = bx0; int it = bx & 15, b = bx >> 4; int i0 = it * 64;
        _Float16 (*sA)[72] = reinterpret_cast<_Float16(*)[72]>(smem);
        _Float16 (*sB)[72] = reinterpret_cast<_Float16(*)[72]>(smem + 9216);
        int wid = tid >> 6, ln = tid & 15, kl = (tid & 63) >> 4;
        f32x4 acc[3];
        #pragma unroll
        for (int n = 0; n < 3; ++n) acc[n] = (f32x4){0.f, 0.f, 0.f, 0.f};
        for (int kc = 0; kc < N_; kc += 64) {
            #pragma unroll
            for (int it2 = 0; it2 < 2; ++it2) {
                int idx = it2 * 256 + tid; int row = idx >> 3, c8 = (idx & 7) * 8;
                *(uint4*)&sA[row][c8] = *(const uint4*)&Af[((size_t)b << 20) + ((size_t)(i0 + row) << 10) + kc + c8];
            }
            for (int idx = tid; idx < 288; idx += 256) {
                int row = idx >> 3, c8 = (idx & 7) * 8;
                int kq = row / 12, tq = row - kq * 12;
                *(uint4*)&sB[row][c8] = *(const uint4*)&S1[(((size_t)kq * 192 + b * T_ + tq) << 10) + kc + c8];
            }
            __syncthreads();
            #pragma unroll
            for (int ks = 0; ks < 4; ++ks) {
                int ko = ks * 16 + kl * 4;
                f16x4 a = *(const f16x4*)&sA[wid * 16 + ln][ko];
                #pragma unroll
                for (int n = 0; n < 3; ++n) {
                    f16x4 b = *(const f16x4*)&sB[n * 16 + ln][ko];
                    acc[n] = __builtin_amdgcn_mfma_f32_16x16x16f16(a, b, acc[n], 0, 0, 0);
                }
            }
            __syncthreads();
        }
        #pragma unroll
        for (int n = 0; n < 3; ++n) {
            int col = n * 16 + ln;
            if (col < 36) {
                int kq = col / 12, tq = col - kq * 12;
                #pragma unroll
                for (int r = 0; r < 4; ++r) {
                    int i = i0 + wid * 16 + kl * 4 + r;
                    S2[(((size_t)(b * 3 + kq) * T_ + tq) << 10) + i] = acc[n][r];
                }
            }
        }
    } else {
        // ---- ag: AG[b][k] = Af[b] @ G[k], 128x128 tiles, reg-staged dbuf ----
        int bxr = bx0 - 256;
        int bx = (bxr & 7) * 384 + (bxr >> 3);     // bijective (3072 % 8 == 0)
        int inst = bx >> 6, tile = bx & 63;
        int b = inst / 3, kk = inst % 3;
        int i0 = (tile >> 3) * 128, j0 = (tile & 7) * 128;
        _Float16 (*sA)[128][72] = reinterpret_cast<_Float16(*)[128][72]>(smem);
        _Float16 (*sB)[128][72] = reinterpret_cast<_Float16(*)[128][72]>(smem + 36864);
        int w = tid >> 6, lane = tid & 63, ln = lane & 15, kg = lane >> 4;
        int mq = (w & 1) * 64, nq = (w >> 1) * 64;
        int srow = tid >> 1, cb = (tid & 1) * 32;
        const _Float16* qa = Af  + ((size_t)b << 20)  + ((size_t)(i0 + srow) << 10) + cb;
        const _Float16* qb = GfT + ((size_t)kk << 20) + ((size_t)(j0 + srow) << 10) + cb;

        f32x4 acc[4][4];
        #pragma unroll
        for (int mt = 0; mt < 4; ++mt)
            #pragma unroll
            for (int nt = 0; nt < 4; ++nt) acc[mt][nt] = (f32x4){0.f, 0.f, 0.f, 0.f};

        f16x8 ra[4], rb[4];
        #pragma unroll
        for (int q = 0; q < 4; ++q) { ra[q] = *(const f16x8*)&qa[q * 8]; rb[q] = *(const f16x8*)&qb[q * 8]; }
        #pragma unroll
        for (int q = 0; q < 4; ++q) {
            *(f16x8*)&sA[0][srow][cb + q * 8] = ra[q];
            *(f16x8*)&sB[0][srow][cb + q * 8] = rb[q];
        }
        __syncthreads();

        for (int tt = 0; tt < 16; ++tt) {
            int cur = tt & 1;
            if (tt < 15) {
                int kn = (tt + 1) * 64;
                #pragma unroll
                for (int q = 0; q < 4; ++q) { ra[q] = *(const f16x8*)&qa[kn + q * 8]; rb[q] = *(const f16x8*)&qb[kn + q * 8]; }
            }
            #pragma unroll
            for (int ks = 0; ks < 2; ++ks) {
                int ko = ks * 32 + kg * 8;
                f16x8 a[4], bfr[4];
                #pragma unroll
                for (int mt = 0; mt < 4; ++mt) a[mt] = *(const f16x8*)&sA[cur][mq + mt * 16 + ln][ko];
                #pragma unroll
                for (int nt = 0; nt < 4; ++nt) bfr[nt] = *(const f16x8*)&sB[cur][nq + nt * 16 + ln][ko];
                #pragma unroll
                for (int mt = 0; mt < 4; ++mt)
                    #pragma unroll
                    for (int nt = 0; nt < 4; ++nt)
                        acc[mt][nt] = __builtin_amdgcn_mfma_f32_16x16x32_f16(a[mt], bfr[nt], acc[mt][nt], 0, 0, 0);
            }
            if (tt < 15) {
                int nb = cur ^ 1;
                #pragma unroll
                for (int q = 0; q < 4; ++q) {
                    *(f16x8*)&sA[nb][srow][cb + q * 8] = ra[q];
                    *(f16x8*)&sB[nb][srow][cb + q * 8] = rb[q];
                }
                __syncthreads();
            }
        }

        _Float16* outp = AG + ((size_t)(b * 3 + kk) << 20);
        #pragma unroll
        for (int mt = 0; mt < 4; ++mt)
            #pragma unroll
            for (int r = 0; r < 4; ++r) {
                int i = i0 + mq + mt * 16 + kg * 4 + r;
                #pragma unroll
                for (int nt = 0; nt < 4; ++nt) {
                    int j = j0 + nq + nt * 16 + ln;
                    outp[((size_t)i << 10) + j] = (_Float16)acc[mt][nt][r];
                }
            }
    }
}

// ============================================================================
// Cooperative fused scan (preferred path): 12 x (gate, update) + decoder.
// grid 512, block 256, __launch_bounds__(256,2) to force 2 blocks/CU.
// LDS 50.6 KB/block. h carried in f32 registers; z in LDS; f16 HtA/HtB exchange.
// ============================================================================
__global__ __launch_bounds__(256, 2) void k_loop(const _Float16* __restrict__ AG,
                                                 _Float16* __restrict__ HtA,
                                                 _Float16* __restrict__ HtB,
                                                 const _Float16* __restrict__ wghT,
                                                 const _Float16* __restrict__ wuhT,
                                                 const float* __restrict__ wx,
                                                 const float* __restrict__ bg,
                                                 const float* __restrict__ bu,
                                                 const float* __restrict__ S2,
                                                 const float* __restrict__ Wd,
                                                 const float* __restrict__ bd,
                                                 float* __restrict__ out) {
    cg::grid_group grid = cg::this_grid();
    int bx = blockIdx.x; int it = bx & 31, b = bx >> 5; int i0 = it * 32;
    __shared__ __align__(16) char smem[46080];
    _Float16 (*sAm)[96][72] = reinterpret_cast<_Float16(*)[96][72]>(smem);
    _Float16 (*sBm)[64][72] = reinterpret_cast<_Float16(*)[64][72]>(smem + 27648);
    _Float16 (*sZ)[200]     = reinterpret_cast<_Float16(*)[200]>(smem);
    _Float16 (*sW)[72]      = reinterpret_cast<_Float16(*)[72]>(smem + 12800);
    __shared__ _Float16 zS[32][64];   // persistent gate output
    __shared__ float sS2[3][32];
    int tid = threadIdx.x;
    int w = tid >> 6, lane = tid & 63, ln = lane & 15, kg = lane >> 4;

    float h_reg[2][4] = {{0.f, 0.f, 0.f, 0.f}, {0.f, 0.f, 0.f, 0.f}};
    float wxg0[2], wxg1[2], wxg2[2], bgr[2];
    #pragma unroll
    for (int n = 0; n < 2; ++n) {
        int o = w * 32 + n * 16 + ln;
        wxg0[n] = wx[o]; wxg1[n] = wx[128 + o]; wxg2[n] = wx[256 + o]; bgr[n] = bg[o];
    }
    int ou = w * 16 + ln;
    float wxu0 = wx[384 + ou], wxu1 = wx[448 + ou], wxu2 = wx[512 + ou], bur = bu[ou];

    int srow = tid >> 3, sc8 = (tid & 7) * 8;
    const _Float16* pa0 = AG + ((size_t)(b * 3 + 0) << 20) + ((size_t)(i0 + srow) << 10) + sc8;
    const _Float16* pa1 = AG + ((size_t)(b * 3 + 1) << 20) + ((size_t)(i0 + srow) << 10) + sc8;
    const _Float16* pa2 = AG + ((size_t)(b * 3 + 2) << 20) + ((size_t)(i0 + srow) << 10) + sc8;
    size_t hoff0 = ((size_t)b << 16) + ((size_t)srow << 10) + sc8;
    size_t hoff1 = ((size_t)b << 16) + ((size_t)(srow + 32) << 10) + sc8;
    int kbF = (w * 3) >> 2, kbL = (w * 3 + 2) >> 2;

    for (int t = 0; t < T_; ++t) {
        #pragma unroll
        for (int phase = 0; phase < 2; ++phase) {
            const _Float16* HtIn = phase ? HtB : HtA;
            if (tid < 96) { int k = tid >> 5, il = tid & 31; sS2[k][il] = S2[(((size_t)(b * 3 + k) * T_ + t) << 10) + i0 + il]; }
            const _Float16* pb0 = HtIn + hoff0;
            const _Float16* pb1 = HtIn + hoff1;

            f32x4 acc[2][3];
            #pragma unroll
            for (int m = 0; m < 2; ++m)
                #pragma unroll
                for (int n = 0; n < 3; ++n) acc[m][n] = (f32x4){0.f, 0.f, 0.f, 0.f};

            f16x8 rA0 = *(const f16x8*)pa0, rA1 = *(const f16x8*)pa1, rA2 = *(const f16x8*)pa2;
            f16x8 rB0 = *(const f16x8*)pb0, rB1 = *(const f16x8*)pb1;
            *(f16x8*)&sAm[0][srow][sc8] = rA0;
            *(f16x8*)&sAm[0][32 + srow][sc8] = rA1;
            *(f16x8*)&sAm[0][64 + srow][sc8] = rA2;
            *(f16x8*)&sBm[0][srow][sc8] = rB0;
            *(f16x8*)&sBm[0][srow + 32][sc8] = rB1;
            __syncthreads();

            for (int tt = 0; tt < 16; ++tt) {
                int cur = tt & 1;
                if (tt < 15) {
                    int kn = (tt + 1) * 64;
                    rA0 = *(const f16x8*)&pa0[kn]; rA1 = *(const f16x8*)&pa1[kn]; rA2 = *(const f16x8*)&pa2[kn];
                    rB0 = *(const f16x8*)&pb0[kn]; rB1 = *(const f16x8*)&pb1[kn];
                }
                #pragma unroll
                for (int ks = 0; ks < 2; ++ks) {
                    int ko = ks * 32 + kg * 8;
                    f16x8 aF0 = *(const f16x8*)&sAm[cur][kbF * 32 + ln][ko];
                    f16x8 aF1 = *(const f16x8*)&sAm[cur][kbF * 32 + 16 + ln][ko];
                    f16x8 aL0 = *(const f16x8*)&sAm[cur][kbL * 32 + ln][ko];
                    f16x8 aL1 = *(const f16x8*)&sAm[cur][kbL * 32 + 16 + ln][ko];
                    #pragma unroll
                    for (int ni = 0; ni < 3; ++ni) {
                        int ct = w * 3 + ni;
                        f16x8 bb = *(const f16x8*)&sBm[cur][(ct & 3) * 16 + ln][ko];
                        bool late = (ct >> 2) != kbF;
                        f16x8 a0 = late ? aL0 : aF0;
                        f16x8 a1 = late ? aL1 : aF1;
                        acc[0][ni] = __builtin_amdgcn_mfma_f32_16x16x32_f16(a0, bb, acc[0][ni], 0, 0, 0);
                        acc[1][ni] = __builtin_amdgcn_mfma_f32_16x16x32_f16(a1, bb, acc[1][ni], 0, 0, 0);
                    }
                }
                if (tt < 15) {
                    int nb = cur ^ 1;
                    *(f16x8*)&sAm[nb][srow][sc8] = rA0;
                    *(f16x8*)&sAm[nb][32 + srow][sc8] = rA1;
                    *(f16x8*)&sAm[nb][64 + srow][sc8] = rA2;
                    *(f16x8*)&sBm[nb][srow][sc8] = rB0;
                    *(f16x8*)&sBm[nb][srow + 32][sc8] = rB1;
                    __syncthreads();
                }
            }
            __syncthreads();

            #pragma unroll
            for (int m = 0; m < 2; ++m)
                #pragma unroll
                for (int ni = 0; ni < 3; ++ni)
                    #pragma unroll
                    for (int r = 0; r < 4; ++r)
                        sZ[m * 16 + kg * 4 + r][(w * 3 + ni) * 16 + ln] = (_Float16)acc[m][ni][r];

            if (phase == 0) {
                f32x4 e[2][2];
                #pragma unroll
                for (int m = 0; m < 2; ++m)
                    #pragma unroll
                    for (int n = 0; n < 2; ++n) e[m][n] = (f32x4){0.f, 0.f, 0.f, 0.f};
                for (int kc = 0; kc < 192; kc += 64) {
                    #pragma unroll
                    for (int it2 = 0; it2 < 4; ++it2) {
                        int idx = it2 * 256 + tid; int row = idx >> 3, c8 = (idx & 7) * 8;
                        *(f16x8*)&sW[row][c8] = *(const f16x8*)&wghT[(size_t)row * 192 + kc + c8];
                    }
                    __syncthreads();
                    #pragma unroll
                    for (int ks = 0; ks < 4; ++ks) {
                        int ko = ks * 16 + kg * 4;
                        f16x4 az0 = *(const f16x4*)&sZ[ln][kc + ko];
                        f16x4 az1 = *(const f16x4*)&sZ[16 + ln][kc + ko];
                        f16x4 bw0 = *(const f16x4*)&sW[w * 32 + ln][ko];
                        f16x4 bw1 = *(const f16x4*)&sW[w * 32 + 16 + ln][ko];
                        e[0][0] = __builtin_amdgcn_mfma_f32_16x16x16f16(az0, bw0, e[0][0], 0, 0, 0);
                        e[0][1] = __builtin_amdgcn_mfma_f32_16x16x16f16(az0, bw1, e[0][1], 0, 0, 0);
                        e[1][0] = __builtin_amdgcn_mfma_f32_16x16x16f16(az1, bw0, e[1][0], 0, 0, 0);
                        e[1][1] = __builtin_amdgcn_mfma_f32_16x16x16f16(az1, bw1, e[1][1], 0, 0, 0);
                    }
                    __syncthreads();
                }
                #pragma unroll
                for (int n = 0; n < 2; ++n) {
                    int o = w * 32 + n * 16 + ln;
                    if (o < H_) {
                        #pragma unroll
                        for (int m = 0; m < 2; ++m)
                            #pragma unroll
                            for (int r = 0; r < 4; ++r) {
                                int il = m * 16 + kg * 4 + r;
                                float pre = e[m][n][r] + wxg0[n] * sS2[0][il] + wxg1[n] * sS2[1][il] + wxg2[n] * sS2[2][il] + bgr[n];
                                zS[il][o] = (_Float16)(1.0f / (1.0f + expf(-pre)));
                            }
                    } else {
                        int c = o - H_;
                        #pragma unroll
                        for (int m = 0; m < 2; ++m) {
                            f16x4 hold4 = *(const f16x4*)&HtA[((size_t)(b * 64 + c) << 10) + i0 + m * 16 + kg * 4];
                            alignas(8) _Float16 hb[4];
                            #pragma unroll
                            for (int r = 0; r < 4; ++r) {
                                int il = m * 16 + kg * 4 + r;
                                float pre = e[m][n][r] + wxg0[n] * sS2[0][il] + wxg1[n] * sS2[1][il] + wxg2[n] * sS2[2][il] + bgr[n];
                                float v = 1.0f / (1.0f + expf(-pre));
                                hb[r] = (_Float16)(v * (float)hold4[r]);
                            }
                            *(f16x4*)&HtB[((size_t)(b * 64 + c) << 10) + i0 + m * 16 + kg * 4] = *(f16x4*)&hb[0];
                        }
                    }
                }
            } else {
                f32x4 e[2];
                e[0] = (f32x4){0.f, 0.f, 0.f, 0.f};
                e[1] = (f32x4){0.f, 0.f, 0.f, 0.f};
                for (int kc = 0; kc < 192; kc += 64) {
                    #pragma unroll
                    for (int it2 = 0; it2 < 2; ++it2) {
                        int idx = it2 * 256 + tid; int row = idx >> 3, c8 = (idx & 7) * 8;
                        *(f16x8*)&sW[row][c8] = *(const f16x8*)&wuhT[(size_t)row * 192 + kc + c8];
                    }
                    __syncthreads();
                    #pragma unroll
                    for (int ks = 0; ks < 4; ++ks) {
                        int ko = ks * 16 + kg * 4;
                        f16x4 az0 = *(const f16x4*)&sZ[ln][kc + ko];
                        f16x4 az1 = *(const f16x4*)&sZ[16 + ln][kc + ko];
                        f16x4 bw  = *(const f16x4*)&sW[w * 16 + ln][ko];
                        e[0] = __builtin_amdgcn_mfma_f32_16x16x16f16(az0, bw, e[0], 0, 0, 0);
                        e[1] = __builtin_amdgcn_mfma_f32_16x16x16f16(az1, bw, e[1], 0, 0, 0);
                    }
                    __syncthreads();
                }
                #pragma unroll
                for (int m = 0; m < 2; ++m) {
                    alignas(8) _Float16 hb[4];
                    #pragma unroll
                    for (int r = 0; r < 4; ++r) {
                        int il = m * 16 + kg * 4 + r;
                        float pre = e[m][r] + wxu0 * sS2[0][il] + wxu1 * sS2[1][il] + wxu2 * sS2[2][il] + bur;
                        float hc = tanhf(pre);
                        float z = (float)zS[il][ou];
                        float hn = z * hc + (1.0f - z) * h_reg[m][r];
                        h_reg[m][r] = hn;
                        hb[r] = (_Float16)hn;
                    }
                    *(f16x4*)&HtA[((size_t)(b * 64 + ou) << 10) + i0 + m * 16 + kg * 4] = *(f16x4*)&hb[0];
                }
            }
            if (t < T_ - 1 || phase == 0) {
                __threadfence();
                grid.sync();
            }
        }
    }

    // ---- decoder from f32 h_reg ----
    __syncthreads();
    float* hF  = (float*)smem;              // [32][64]
    float* wds = (float*)(smem + 8192);     // [768]
    float* bds = (float*)(smem + 11264);    // [12]
    #pragma unroll
    for (int m = 0; m < 2; ++m)
        #pragma unroll
        for (int r = 0; r < 4; ++r)
            hF[(m * 16 + kg * 4 + r) * 64 + ou] = h_reg[m][r];
    for (int idx = tid; idx < 768; idx += 256) wds[idx] = Wd[idx];
    if (tid < 12) bds[tid] = bd[tid];
    __syncthreads();
    for (int oidx = tid; oidx < 384; oidx += 256) {
        int il = oidx & 31, tt = oidx >> 5;
        float acc = bds[tt];
        #pragma unroll
        for (int c = 0; c < 64; ++c) acc += hF[il * 64 + c] * wds[c * 12 + tt];
        out[(((size_t)(b * T_ + tt)) << 10) + i0 + il] = acc;
    }
}

// ============================================================================
// Fallback path (proven round-11 structure): per-step kernels, grid 1024.
// zf is f16; h stays f32 (proven numerics). Decoder folded into fup at t=11.
// ============================================================================
__global__ __launch_bounds__(256) void k_fzr2(const _Float16* __restrict__ AG,
                                              const _Float16* __restrict__ HtIn,
                                              const _Float16* __restrict__ wghT,
                                              const float* __restrict__ wx,
                                              const float* __restrict__ bg,
                                              const float* __restrict__ S2,
                                              const float* __restrict__ h,
                                              _Float16* __restrict__ zf,
                                              _Float16* __restrict__ HtOut, int t) {
    int bx = blockIdx.x; int it = bx & 63, b = bx >> 6; int i0 = it * 16;
    __shared__ __align__(16) char smem[32256];
    _Float16 (*sA)[48][72] = reinterpret_cast<_Float16(*)[48][72]>(smem);
    _Float16 (*sB)[64][72] = reinterpret_cast<_Float16(*)[64][72]>(smem + 13824);
    _Float16 (*sZ)[200]    = reinterpret_cast<_Float16(*)[200]>(smem);
    _Float16 (*sW)[72]     = reinterpret_cast<_Float16(*)[72]>(smem + 6400);
    __shared__ float sS2[3][16];
    __shared__ float sWX[384];
    __shared__ float sBias[128];
    int tid = threadIdx.x;
    int w = tid >> 6, lane = tid & 63, ln = lane & 15, kg = lane >> 4;
    if (tid < 48) { int k = tid >> 4, il = tid & 15; sS2[k][il] = S2[(((size_t)(b * 3 + k) * T_ + t) << 10) + i0 + il]; }
    for (int q = tid; q < 384; q += 256) sWX[q] = wx[q];
    if (tid < 128) sBias[tid] = bg[tid];

    const _Float16* pA[3]; int c4A[3], rowA[3];
    #pragma unroll
    for (int q = 0; q < 3; ++q) {
        int idx = q * 256 + tid; rowA[q] = idx >> 4; c4A[q] = (idx & 15) * 4;
        int kb = rowA[q] >> 4, rloc = rowA[q] & 15;
        pA[q] = AG + ((size_t)(b * 3 + kb) << 20) + ((size_t)(i0 + rloc) << 10) + c4A[q];
    }
    const _Float16* pB[2]; int c8B[2], rowB[2];
    #pragma unroll
    for (int q = 0; q < 2; ++q) {
        int idx = q * 256 + tid; rowB[q] = idx >> 3; c8B[q] = (idx & 7) * 8;
        pB[q] = HtIn + ((size_t)b << 16) + ((size_t)rowB[q] << 10) + c8B[q];
    }

    f32x4 acc[3];
    #pragma unroll
    for (int n = 0; n < 3; ++n) acc[n] = (f32x4){0.f, 0.f, 0.f, 0.f};

    f16x4 ra[3]; f16x8 rb[2];
    #pragma unroll
    for (int q = 0; q < 3; ++q) ra[q] = *(const f16x4*)pA[q];
    #pragma unroll
    for (int q = 0; q < 2; ++q) rb[q] = *(const f16x8*)pB[q];
    #pragma unroll
    for (int q = 0; q < 3; ++q) *(f16x4*)&sA[0][rowA[q]][c4A[q]] = ra[q];
    #pragma unroll
    for (int q = 0; q < 2; ++q) *(f16x8*)&sB[0][rowB[q]][c8B[q]] = rb[q];
    __syncthreads();

    int kbF = (w * 3) >> 2, kbL = (w * 3 + 2) >> 2;
    for (int tt = 0; tt < 16; ++tt) {
        int cur = tt & 1;
        if (tt < 15) {
            int kn = (tt + 1) * 64;
            #pragma unroll
            for (int q = 0; q < 3; ++q) ra[q] = *(const f16x4*)&pA[q][kn];
            #pragma unroll
            for (int q = 0; q < 2; ++q) rb[q] = *(const f16x8*)&pB[q][kn];
        }
        #pragma unroll
        for (int ks = 0; ks < 2; ++ks) {
            int ko = ks * 32 + kg * 8;
            f16x8 aF = *(const f16x8*)&sA[cur][kbF * 16 + ln][ko];
            f16x8 aL = *(const f16x8*)&sA[cur][kbL * 16 + ln][ko];
            #pragma unroll
            for (int ni = 0; ni < 3; ++ni) {
                int ct = w * 3 + ni;
                f16x8 bb = *(const f16x8*)&sB[cur][(ct & 3) * 16 + ln][ko];
                f16x8 a = ((ct >> 2) != kbF) ? aL : aF;
                acc[ni] = __builtin_amdgcn_mfma_f32_16x16x32_f16(a, bb, acc[ni], 0, 0, 0);
            }
        }
        if (tt < 15) {
            int nb = cur ^ 1;
            #pragma unroll
            for (int q = 0; q < 3; ++q) *(f16x4*)&sA[nb][rowA[q]][c4A[q]] = ra[q];
            #pragma unroll
            for (int q = 0; q < 2; ++q) *(f16x8*)&sB[nb][rowB[q]][c8B[q]] = rb[q];
            __syncthreads();
        }
    }
    __syncthreads();

    #pragma unroll
    for (int ni = 0; ni < 3; ++ni)
        #pragma unroll
        for (int r = 0; r < 4; ++r)
            sZ[kg * 4 + r][(w * 3 + ni) * 16 + ln] = (_Float16)acc[ni][r];

    f32x4 e[2];
    e[0] = (f32x4){0.f, 0.f, 0.f, 0.f};
    e[1] = (f32x4){0.f, 0.f, 0.f, 0.f};
    for (int kc = 0; kc < 192; kc += 64) {
        #pragma unroll
        for (int it2 = 0; it2 < 4; ++it2) {
            int idx = it2 * 256 + tid; int row = idx >> 3, c8 = (idx & 7) * 8;
            *(f16x8*)&sW[row][c8] = *(const f16x8*)&wghT[(size_t)row * 192 + kc + c8];
        }
        __syncthreads();
        #pragma unroll
        for (int ks = 0; ks < 4; ++ks) {
            int ko = ks * 16 + kg * 4;
            f16x4 az  = *(const f16x4*)&sZ[ln][kc + ko];
            f16x4 bw0 = *(const f16x4*)&sW[w * 32 + ln][ko];
            f16x4 bw1 = *(const f16x4*)&sW[w * 32 + 16 + ln][ko];
            e[0] = __builtin_amdgcn_mfma_f32_16x16x16f16(az, bw0, e[0], 0, 0, 0);
            e[1] = __builtin_amdgcn_mfma_f32_16x16x16f16(az, bw1, e[1], 0, 0, 0);
        }
        __syncthreads();
    }

    #pragma unroll
    for (int n = 0; n < 2; ++n) {
        int o = w * 32 + n * 16 + ln;
        float w0 = sWX[o], w1 = sWX[128 + o], w2 = sWX[256 + o], bi = sBias[o];
        if (o < H_) {
            alignas(8) _Float16 zv[4];
            #pragma unroll
            for (int r = 0; r < 4; ++r) {
                int il = kg * 4 + r;
                float pre = e[n][r] + w0 * sS2[0][il] + w1 * sS2[1][il] + w2 * sS2[2][il] + bi;
                zv[r] = (_Float16)(1.0f / (1.0f + expf(-pre)));
            }
            *(f16x4*)&zf[((size_t)(b * 64 + o) << 10) + i0 + kg * 4] = *(f16x4*)&zv[0];
        } else {
            int c = o - H_;
            alignas(8) _Float16 hb[4];
            #pragma unroll
            for (int r = 0; r < 4; ++r) {
                int il = kg * 4 + r;
                float pre = e[n][r] + w0 * sS2[0][il] + w1 * sS2[1][il] + w2 * sS2[2][il] + bi;
                float v = 1.0f / (1.0f + expf(-pre));
                hb[r] = (_Float16)(v * h[((size_t)((b << 10) + i0 + il)) * H_ + c]);
            }
            *(f16x4*)&HtOut[((size_t)(b * 64 + c) << 10) + i0 + kg * 4] = *(f16x4*)&hb[0];
        }
    }
}

__global__ __launch_bounds__(256) void k_fup2(const _Float16* __restrict__ AG,
                                              const _Float16* __restrict__ HtIn,
                                              const _Float16* __restrict__ wuhT,
                                              const float* __restrict__ wx,
                                              const float* __restrict__ bu,
                                              const float* __restrict__ S2,
                                              const _Float16* __restrict__ zf,
                                              float* __restrict__ h,
                                              _Float16* __restrict__ HtOut,
                                              const float* __restrict__ Wd,
                                              const float* __restrict__ bd,
                                              float* __restrict__ out, int t) {
    int bx = blockIdx.x; int it = bx & 63, b = bx >> 6; int i0 = it * 16;
    __shared__ __align__(16) char smem[32256];
    _Float16 (*sA)[48][72] = reinterpret_cast<_Float16(*)[48][72]>(smem);
    _Float16 (*sB)[64][72] = reinterpret_cast<_Float16(*)[64][72]>(smem + 13824);
    _Float16 (*sZ)[200]    = reinterpret_cast<_Float16(*)[200]>(smem);
    _Float16 (*sW)[72]     = reinterpret_cast<_Float16(*)[72]>(smem + 6400);
    __shared__ float sS2[3][16];
    __shared__ float sWX[192];
    __shared__ float sBias[64];
    int tid = threadIdx.x;
    int w = tid >> 6, lane = tid & 63, ln = lane & 15, kg = lane >> 4;
    if (tid < 48) { int k = tid >> 4, il = tid & 15; sS2[k][il] = S2[(((size_t)(b * 3 + k) * T_ + t) << 10) + i0 + il]; }
    if (tid < 192) sWX[tid] = wx[384 + tid];
    if (tid < 64) sBias[tid] = bu[tid];

    const _Float16* pA[3]; int c4A[3], rowA[3];
    #pragma unroll
    for (int q = 0; q < 3; ++q) {
        int idx = q * 256 + tid; rowA[q] = idx >> 4; c4A[q] = (idx & 15) * 4;
        int kb = rowA[q] >> 4, rloc = rowA[q] & 15;
        pA[q] = AG + ((size_t)(b * 3 + kb) << 20) + ((size_t)(i0 + rloc) << 10) + c4A[q];
    }
    const _Float16* pB[2]; int c8B[2], rowB[2];
    #pragma unroll
    for (int q = 0; q < 2; ++q) {
        int idx = q * 256 + tid; rowB[q] = idx >> 3; c8B[q] = (idx & 7) * 8;
        pB[q] = HtIn + ((size_t)b << 16) + ((size_t)rowB[q] << 10) + c8B[q];
    }

    f32x4 acc[3];
    #pragma unroll
    for (int n = 0; n < 3; ++n) acc[n] = (f32x4){0.f, 0.f, 0.f, 0.f};

    f16x4 ra[3]; f16x8 rb[2];
    #pragma unroll
    for (int q = 0; q < 3; ++q) ra[q] = *(const f16x4*)pA[q];
    #pragma unroll
    for (int q = 0; q < 2; ++q) rb[q] = *(const f16x8*)pB[q];
    #pragma unroll
    for (int q = 0; q < 3; ++q) *(f16x4*)&sA[0][rowA[q]][c4A[q]] = ra[q];
    #pragma unroll
    for (int q = 0; q < 2; ++q) *(f16x8*)&sB[0][rowB[q]][c8B[q]] = rb[q];
    __syncthreads();

    int kbF = (w * 3) >> 2, kbL = (w * 3 + 2) >> 2;
    for (int tt = 0; tt < 16; ++tt) {
        int cur = tt & 1;
        if (tt < 15) {
            int kn = (tt + 1) * 64;
            #pragma unroll
            for (int q = 0; q < 3; ++q) ra[q] = *(const f16x4*)&pA[q][kn];
            #pragma unroll
            for (int q = 0; q < 2; ++q) rb[q] = *(const f16x8*)&pB[q][kn];
        }
        #pragma unroll
        for (int ks = 0; ks < 2; ++ks) {
            int ko = ks * 32 + kg * 8;
            f16x8 aF = *(const f16x8*)&sA[cur][kbF * 16 + ln][ko];
            f16x8 aL = *(const f16x8*)&sA[cur][kbL * 16 + ln][ko];
            #pragma unroll
            for (int ni = 0; ni < 3; ++ni) {
                int ct = w * 3 + ni;
                f16x8 bb = *(const f16x8*)&sB[cur][(ct & 3) * 16 + ln][ko];
                f16x8 a = ((ct >> 2) != kbF) ? aL : aF;
                acc[ni] = __builtin_amdgcn_mfma_f32_16x16x32_f16(a, bb, acc[ni], 0, 0, 0);
            }
        }
        if (tt < 15) {
            int nb = cur ^ 1;
            #pragma unroll
            for (int q = 0; q < 3; ++q) *(f16x4*)&sA[nb][rowA[q]][c4A[q]] = ra[q];
            #pragma unroll
            for (int q = 0; q < 2; ++q) *(f16x8*)&sB[nb][rowB[q]][c8B[q]] = rb[q];
            __syncthreads();
        }
    }
    __syncthreads();

    #pragma unroll
    for (int ni = 0; ni < 3; ++ni)
        #pragma unroll
        for (int r = 0; r < 4; ++r)
            sZ[kg * 4 + r][(w * 3 + ni) * 16 + ln] = (_Float16)acc[ni][r];

    f32x4 e = (f32x4){0.f, 0.f, 0.f, 0.f};
    for (int kc = 0; kc < 192; kc += 64) {
        #pragma unroll
        for (int it2 = 0; it2 < 2; ++it2) {
            int idx = it2 * 256 + tid; int row = idx >> 3, c8 = (idx & 7) * 8;
            *(f16x8*)&sW[row][c8] = *(const f16x8*)&wuhT[(size_t)row * 192 + kc + c8];
        }
        __syncthreads();
        #pragma unroll
        for (int ks = 0; ks < 4; ++ks) {
            int ko = ks * 16 + kg * 4;
            f16x4 az = *(const f16x4*)&sZ[ln][kc + ko];
            f16x4 bw = *(const f16x4*)&sW[w * 16 + ln][ko];
            e = __builtin_amdgcn_mfma_f32_16x16x16f16(az, bw, e, 0, 0, 0);
        }
        __syncthreads();
    }

    int o = w * 16 + ln;
    float w0 = sWX[o], w1 = sWX[64 + o], w2 = sWX[128 + o], bi = sBias[o];
    f16x4 z4 = *(const f16x4*)&zf[((size_t)(b * 64 + o) << 10) + i0 + kg * 4];
    alignas(8) _Float16 hb[4];
    float hnv[4];
    #pragma unroll
    for (int r = 0; r < 4; ++r) {
        int il = kg * 4 + r;
        float pre = e[r] + w0 * sS2[0][il] + w1 * sS2[1][il] + w2 * sS2[2][il] + bi;
        float hc = tanhf(pre);
        size_t gi = ((size_t)((b << 10) + i0 + il)) * H_ + o;
        float z = (float)z4[r];
        float hn = z * hc + (1.0f - z) * h[gi];
        h[gi] = hn;
        hnv[r] = hn;
        hb[r] = (_Float16)hn;
    }
    *(f16x4*)&HtOut[((size_t)(b * 64 + o) << 10) + i0 + kg * 4] = *(f16x4*)&hb[0];

    if (t == T_ - 1) {
        __syncthreads();
        float* hF  = (float*)smem;              // [16][64]
        float* wds = (float*)(smem + 4096);     // [768]
        float* bds = (float*)(smem + 7168);     // [12]
        #pragma unroll
        for (int r = 0; r < 4; ++r) hF[(kg * 4 + r) * 64 + o] = hnv[r];
        for (int idx = tid; idx < 768; idx += 256) wds[idx] = Wd[idx];
        if (tid < 12) bds[tid] = bd[tid];
        __syncthreads();
        for (int oidx = tid; oidx < 192; oidx += 256) {
            int il = oidx & 15, tt2 = oidx >> 4;
            float acc2 = bds[tt2];
            #pragma unroll
            for (int c = 0; c < 64; ++c) acc2 += hF[il * 64 + c] * wds[c * 12 + tt2];
            out[(((size_t)(b * T_ + tt2)) << 10) + i0 + il] = acc2;
        }
    }
}

extern "C" void kernel_launch(void* const* d_in, const int* in_sizes, int n_in,
                              void* d_out, int out_size, void* d_ws, size_t ws_size,
                              hipStream_t stream) {
    const float* x  = (const float*)d_in[0];
    const float* G  = (const float*)d_in[1];
    const float* A  = (const float*)d_in[2];
    const float* Wg = (const float*)d_in[3];
    const float* bg = (const float*)d_in[4];
    const float* Wu = (const float*)d_in[5];
    const float* bu = (const float*)d_in[6];
    const float* Wd = (const float*)d_in[7];
    const float* bd = (const float*)d_in[8];
    float* out = (float*)d_out;
    float* ws  = (float*)d_ws;

    float* h   = ws + OFF_H;
    float* S2  = ws + OFF_S2;
    float* wxb = ws + OFF_WX;
    _Float16* zf   = (_Float16*)(ws + OFF_ZF);
    _Float16* HtA  = (_Float16*)(ws + OFF_HTA);
    _Float16* HtB  = (_Float16*)(ws + OFF_HTB);
    _Float16* S1   = (_Float16*)(ws + OFF_S1);
    _Float16* wghT = (_Float16*)(ws + OFF_WGT);
    _Float16* wuhT = (_Float16*)(ws + OFF_WUT);
    _Float16* GfT  = (_Float16*)(ws + OFF_GT);
    _Float16* AG   = (_Float16*)(ws + OFF_AG);
    _Float16* Af   = (_Float16*)(ws + OFF_AF);

    hipMemsetAsync(h, 0, (size_t)B_ * N_ * H_ * sizeof(float), stream);
    hipMemsetAsync((void*)HtA, 0, (size_t)B_ * N_ * H_ * sizeof(_Float16), stream);
    k_pre<<<9203, 256, 0, stream>>>(A, G, x, Wg, Wu, Af, GfT, S1, wghT, wuhT, wxb);
    k_main<<<3328, 256, 0, stream>>>(Af, GfT, AG, S1, S2);

    // deterministic path choice: cooperative only if the runtime guarantees
    // 2 blocks/CU co-residency for k_loop (grid 512 on 256 CUs).
    int nb = 0;
    hipOccupancyMaxActiveBlocksPerMultiprocessor(&nb, k_loop, 256, 0);
    if (nb >= 2) {
        void* args[] = {(void*)&AG, (void*)&HtA, (void*)&HtB, (void*)&wghT, (void*)&wuhT,
                        (void*)&wxb, (void*)&bg, (void*)&bu, (void*)&S2,
                        (void*)&Wd, (void*)&bd, (void*)&out};
        hipLaunchCooperativeKernel((const void*)k_loop, dim3(512), dim3(256), args, 0, stream);
    } else {
        for (int t = 0; t < T_; ++t) {
            k_fzr2<<<1024, 256, 0, stream>>>(AG, HtA, wghT, wxb, bg, S2, h, zf, HtB, t);
            k_fup2<<<1024, 256, 0, stream>>>(AG, HtB, wuhT, wxb, bu, S2, zf, h, HtA, Wd, bd, out, t);
        }
    }
}

// Round 14
// 799.786 us; speedup vs baseline: 2.4526x; 1.0004x over previous
//
#include <hip/hip_runtime.h>
#include <hip/hip_cooperative_groups.h>

namespace cg = cooperative_groups;

#define B_  16
#define T_  12
#define N_  1024
#define K_  3
#define H_  64
#define DIN 65
#define KH  192
#define OG  128

typedef _Float16 f16x4 __attribute__((ext_vector_type(4)));
typedef _Float16 f16x8 __attribute__((ext_vector_type(8)));
typedef float    f32x4 __attribute__((ext_vector_type(4)));

// ---- workspace offsets (float units), total ~156.7 MB (< ~268 MB evidenced) ----
static const size_t OFF_H   = 0;          // f32 h    [16][1024][64]  (fallback only)
static const size_t OFF_ZF  = 1048576;    // f16 zf   [16][64][1024]  (fallback only)
static const size_t OFF_S2  = 2097152;    // f32 S2   [16][3][12][1024] (x1024)
static const size_t OFF_HTA = 2686976;    // f16 HtA  [16][64][1024]
static const size_t OFF_HTB = 3211264;    // f16 HtB  [16][64][1024]
static const size_t OFF_S1  = 3735552;    // f16 S1   [3][192][1024]
static const size_t OFF_WGT = 4030464;    // f16 wghT [128][192] (/1024)
static const size_t OFF_WUT = 4042752;    // f16 wuhT [64][192]  (/1024)
static const size_t OFF_WX  = 4048896;    // f32 wx (576)
static const size_t OFF_GT  = 4049472;    // f16 GfT  [3][1024][1024]
static const size_t OFF_AG  = 5622336;    // f16 AG   [16][3][1024][1024]
static const size_t OFF_AF  = 30788160;   // f16 Af   [16][1024][1024] = 1024*A

// ============================================================================
// Fused preamble phase A: [s1b | gtr | repack | acvt] (mutually independent).
// s1b first so its latency-bound tail overlaps the BW-bound rest.
// grid = 96 + 768 + 147 + 8192 = 9203
// ============================================================================
__global__ __launch_bounds__(256) void k_pre(const float* __restrict__ A,
                                             const float* __restrict__ G,
                                             const float* __restrict__ x,
                                             const float* __restrict__ Wg,
                                             const float* __restrict__ Wu,
                                             _Float16* __restrict__ Af,
                                             _Float16* __restrict__ GfT,
                                             _Float16* __restrict__ S1,
                                             _Float16* __restrict__ wghT,
                                             _Float16* __restrict__ wuhT,
                                             float* __restrict__ wx) {
    __shared__ __align__(16) char smem[23040];
    int bx0 = blockIdx.x, tid = threadIdx.x;
    if (bx0 < 96) {
        // ---- s1b: S1[k][m][i] = sum_j G[k][i][j] x[m][j] ----
        int bx = bx0;
        int nh = bx & 1, it = (bx >> 1) & 15, kk = bx >> 5;
        int i0 = it * 64, m0 = nh * 96;
        _Float16 (*sA)[72] = reinterpret_cast<_Float16(*)[72]>(smem);
        _Float16 (*sB)[72] = reinterpret_cast<_Float16(*)[72]>(smem + 9216);
        int wid = tid >> 6, ln = tid & 15, kl = (tid & 63) >> 4;
        const float* Gk = G + (size_t)kk * N_ * N_;
        f32x4 acc[6];
        #pragma unroll
        for (int n = 0; n < 6; ++n) acc[n] = (f32x4){0.f, 0.f, 0.f, 0.f};
        for (int kc = 0; kc < N_; kc += 64) {
            #pragma unroll
            for (int it2 = 0; it2 < 4; ++it2) {
                int idx = it2 * 256 + tid; int row = idx >> 4, c4 = (idx & 15) * 4;
                float4 g = *(const float4*)&Gk[(size_t)(i0 + row) * N_ + kc + c4];
                f16x4 hv = {(_Float16)g.x, (_Float16)g.y, (_Float16)g.z, (_Float16)g.w};
                *(f16x4*)&sA[row][c4] = hv;
            }
            #pragma unroll
            for (int it2 = 0; it2 < 6; ++it2) {
                int idx = it2 * 256 + tid; int row = idx >> 4, c4 = (idx & 15) * 4;
                float4 g = *(const float4*)&x[(size_t)(m0 + row) * N_ + kc + c4];
                f16x4 hv = {(_Float16)g.x, (_Float16)g.y, (_Float16)g.z, (_Float16)g.w};
                *(f16x4*)&sB[row][c4] = hv;
            }
            __syncthreads();
            #pragma unroll
            for (int ks = 0; ks < 4; ++ks) {
                int ko = ks * 16 + kl * 4;
                f16x4 a = *(const f16x4*)&sA[wid * 16 + ln][ko];
                #pragma unroll
                for (int n = 0; n < 6; ++n) {
                    f16x4 b = *(const f16x4*)&sB[n * 16 + ln][ko];
                    acc[n] = __builtin_amdgcn_mfma_f32_16x16x16f16(a, b, acc[n], 0, 0, 0);
                }
            }
            __syncthreads();
        }
        #pragma unroll
        for (int n = 0; n < 6; ++n) {
            int m = m0 + n * 16 + ln;
            #pragma unroll
            for (int r = 0; r < 4; ++r) {
                int i = i0 + wid * 16 + kl * 4 + r;
                S1[(((size_t)kk * 192 + m) << 10) + i] = (_Float16)acc[n][r];
            }
        }
    } else if (bx0 < 864) {
        // ---- gtr: GfT[k][j][p] = f16(G[k][p][j]) ----
        int bx = bx0 - 96;
        int kk = bx >> 8, rem = bx & 255, ti = rem >> 4, tj = rem & 15;
        int i0 = ti * 64, j0 = tj * 64;
        _Float16 (*s)[72] = reinterpret_cast<_Float16(*)[72]>(smem);
        int r = tid >> 2, cb = (tid & 3) * 16;
        const float* Gp = G + ((size_t)kk << 20) + ((size_t)(i0 + r) << 10) + j0 + cb;
        #pragma unroll
        for (int q = 0; q < 4; ++q) {
            float4 v = *(const float4*)&Gp[q * 4];
            f16x4 hv = {(_Float16)v.x, (_Float16)v.y, (_Float16)v.z, (_Float16)v.w};
            *(f16x4*)&s[r][cb + q * 4] = hv;
        }
        __syncthreads();
        alignas(16) _Float16 tmp[16];
        #pragma unroll
        for (int q = 0; q < 16; ++q) tmp[q] = s[cb + q][r];
        _Float16* outp = GfT + ((size_t)kk << 20) + ((size_t)(j0 + r) << 10) + i0 + cb;
        *(f16x8*)&outp[0] = *(f16x8*)&tmp[0];
        *(f16x8*)&outp[8] = *(f16x8*)&tmp[8];
    } else if (bx0 < 1011) {
        // ---- repack ----
        const float inv = 1.0f / 1024.0f;
        int idx = (bx0 - 864) * 256 + tid;
        if (idx < 128 * 192) {
            int o = idx / 192, d = idx % 192;
            int k = d / 64, c = d % 64;
            wghT[idx] = (_Float16)(Wg[(size_t)(k * DIN + 1 + c) * OG + o] * inv);
        } else if (idx < 128 * 192 + 64 * 192) {
            int j = idx - 128 * 192;
            int o = j / 192, d = j % 192;
            int k = d / 64, c = d % 64;
            wuhT[j] = (_Float16)(Wu[(size_t)(k * DIN + 1 + c) * H_ + o] * inv);
        } else if (idx < 128 * 192 + 64 * 192 + 576) {
            int j = idx - 128 * 192 - 64 * 192;
            if (j < 384) { int k = j >> 7, o = j & 127; wx[j] = Wg[(size_t)(k * DIN) * OG + o] * inv; }
            else { int j2 = j - 384; int k = j2 >> 6, o = j2 & 63; wx[j] = Wu[(size_t)(k * DIN) * H_ + o] * inv; }
        }
    } else {
        // ---- acvt: Af = f16(1024*A) ----
        size_t idx = ((size_t)(bx0 - 1011) * 256 + tid) * 8;
        float4 a = *(const float4*)&A[idx];
        float4 c = *(const float4*)&A[idx + 4];
        f16x8 v = {(_Float16)(a.x*1024.f), (_Float16)(a.y*1024.f), (_Float16)(a.z*1024.f), (_Float16)(a.w*1024.f),
                   (_Float16)(c.x*1024.f), (_Float16)(c.y*1024.f), (_Float16)(c.z*1024.f), (_Float16)(c.w*1024.f)};
        *(f16x8*)&Af[idx] = v;
    }
}

// ============================================================================
// Fused phase B: [s2b | ag]. s2b first (small), ag with XCD-chunked swizzle.
// grid = 256 + 3072 = 3328
// ============================================================================
__global__ __launch_bounds__(256) void k_main(const _Float16* __restrict__ Af,
                                              const _Float16* __restrict__ GfT,
                                              _Float16* __restrict__ AG,
                                              const _Float16* __restrict__ S1,
                                              float* __restrict__ S2) {
    __shared__ __align__(16) char smem[73728];
    int bx0 = blockIdx.x, tid = threadIdx.x;
    if (bx0 < 256) {
        // ---- s2b ----
        int bx = bx0; int it = bx & 15, b = bx >> 4; int i0 = it * 64;
        _Float16 (*sA)[72] = reinterpret_cast<_Float16(*)[72]>(smem);
        _Float16 (*sB)[72] = reinterpret_cast<_Float16(*)[72]>(smem + 9216);
        int wid = tid >> 6, ln = tid & 15, kl = (tid & 63) >> 4;
        f32x4 acc[3];
        #pragma unroll
        for (int n = 0; n < 3; ++n) acc[n] = (f32x4){0.f, 0.f, 0.f, 0.f};
        for (int kc = 0; kc < N_; kc += 64) {
            #pragma unroll
            for (int it2 = 0; it2 < 2; ++it2) {
                int idx = it2 * 256 + tid; int row = idx >> 3, c8 = (idx & 7) * 8;
                *(uint4*)&sA[row][c8] = *(const uint4*)&Af[((size_t)b << 20) + ((size_t)(i0 + row) << 10) + kc + c8];
            }
            for (int idx = tid; idx < 288; idx += 256) {
                int row = idx >> 3, c8 = (idx & 7) * 8;
                int kq = row / 12, tq = row - kq * 12;
                *(uint4*)&sB[row][c8] = *(const uint4*)&S1[(((size_t)kq * 192 + b * T_ + tq) << 10) + kc + c8];
            }
            __syncthreads();
            #pragma unroll
            for (int ks = 0; ks < 4; ++ks) {
                int ko = ks * 16 + kl * 4;
                f16x4 a = *(const f16x4*)&sA[wid * 16 + ln][ko];
                #pragma unroll
                for (int n = 0; n < 3; ++n) {
                    f16x4 b = *(const f16x4*)&sB[n * 16 + ln][ko];
                    acc[n] = __builtin_amdgcn_mfma_f32_16x16x16f16(a, b, acc[n], 0, 0, 0);
                }
            }
            __syncthreads();
        }
        #pragma unroll
        for (int n = 0; n < 3; ++n) {
            int col = n * 16 + ln;
            if (col < 36) {
                int kq = col / 12, tq = col - kq * 12;
                #pragma unroll
                for (int r = 0; r < 4; ++r) {
                    int i = i0 + wid * 16 + kl * 4 + r;
                    S2[(((size_t)(b * 3 + kq) * T_ + tq) << 10) + i] = acc[n][r];
                }
            }
        }
    } else {
        // ---- ag: AG[b][k] = Af[b] @ G[k], 128x128 tiles, reg-staged dbuf ----
        int bxr = bx0 - 256;
        int bx = (bxr & 7) * 384 + (bxr >> 3);     // bijective (3072 % 8 == 0)
        int inst = bx >> 6, tile = bx & 63;
        int b = inst / 3, kk = inst % 3;
        int i0 = (tile >> 3) * 128, j0 = (tile & 7) * 128;
        _Float16 (*sA)[128][72] = reinterpret_cast<_Float16(*)[128][72]>(smem);
        _Float16 (*sB)[128][72] = reinterpret_cast<_Float16(*)[128][72]>(smem + 36864);
        int w = tid >> 6, lane = tid & 63, ln = lane & 15, kg = lane >> 4;
        int mq = (w & 1) * 64, nq = (w >> 1) * 64;
        int srow = tid >> 1, cb = (tid & 1) * 32;
        const _Float16* qa = Af  + ((size_t)b << 20)  + ((size_t)(i0 + srow) << 10) + cb;
        const _Float16* qb = GfT + ((size_t)kk << 20) + ((size_t)(j0 + srow) << 10) + cb;

        f32x4 acc[4][4];
        #pragma unroll
        for (int mt = 0; mt < 4; ++mt)
            #pragma unroll
            for (int nt = 0; nt < 4; ++nt) acc[mt][nt] = (f32x4){0.f, 0.f, 0.f, 0.f};

        f16x8 ra[4], rb[4];
        #pragma unroll
        for (int q = 0; q < 4; ++q) { ra[q] = *(const f16x8*)&qa[q * 8]; rb[q] = *(const f16x8*)&qb[q * 8]; }
        #pragma unroll
        for (int q = 0; q < 4; ++q) {
            *(f16x8*)&sA[0][srow][cb + q * 8] = ra[q];
            *(f16x8*)&sB[0][srow][cb + q * 8] = rb[q];
        }
        __syncthreads();

        for (int tt = 0; tt < 16; ++tt) {
            int cur = tt & 1;
            if (tt < 15) {
                int kn = (tt + 1) * 64;
                #pragma unroll
                for (int q = 0; q < 4; ++q) { ra[q] = *(const f16x8*)&qa[kn + q * 8]; rb[q] = *(const f16x8*)&qb[kn + q * 8]; }
            }
            #pragma unroll
            for (int ks = 0; ks < 2; ++ks) {
                int ko = ks * 32 + kg * 8;
                f16x8 a[4], bfr[4];
                #pragma unroll
                for (int mt = 0; mt < 4; ++mt) a[mt] = *(const f16x8*)&sA[cur][mq + mt * 16 + ln][ko];
                #pragma unroll
                for (int nt = 0; nt < 4; ++nt) bfr[nt] = *(const f16x8*)&sB[cur][nq + nt * 16 + ln][ko];
                #pragma unroll
                for (int mt = 0; mt < 4; ++mt)
                    #pragma unroll
                    for (int nt = 0; nt < 4; ++nt)
                        acc[mt][nt] = __builtin_amdgcn_mfma_f32_16x16x32_f16(a[mt], bfr[nt], acc[mt][nt], 0, 0, 0);
            }
            if (tt < 15) {
                int nb = cur ^ 1;
                #pragma unroll
                for (int q = 0; q < 4; ++q) {
                    *(f16x8*)&sA[nb][srow][cb + q * 8] = ra[q];
                    *(f16x8*)&sB[nb][srow][cb + q * 8] = rb[q];
                }
                __syncthreads();
            }
        }

        _Float16* outp = AG + ((size_t)(b * 3 + kk) << 20);
        #pragma unroll
        for (int mt = 0; mt < 4; ++mt)
            #pragma unroll
            for (int r = 0; r < 4; ++r) {
                int i = i0 + mq + mt * 16 + kg * 4 + r;
                #pragma unroll
                for (int nt = 0; nt < 4; ++nt) {
                    int j = j0 + nq + nt * 16 + ln;
                    outp[((size_t)i << 10) + j] = (_Float16)acc[mt][nt][r];
                }
            }
    }
}

// ============================================================================
// Cooperative fused scan (preferred path): 12 x (gate, update) + decoder.
// grid 512, block 256, __launch_bounds__(256,2) to force 2 blocks/CU.
// LDS 50.6 KB/block. h carried in f32 registers; z in LDS; f16 HtA/HtB exchange.
// ============================================================================
__global__ __launch_bounds__(256, 2) void k_loop(const _Float16* __restrict__ AG,
                                                 _Float16* __restrict__ HtA,
                                                 _Float16* __restrict__ HtB,
                                                 const _Float16* __restrict__ wghT,
                                                 const _Float16* __restrict__ wuhT,
                                                 const float* __restrict__ wx,
                                                 const float* __restrict__ bg,
                                                 const float* __restrict__ bu,
                                                 const float* __restrict__ S2,
                                                 const float* __restrict__ Wd,
                                                 const float* __restrict__ bd,
                                                 float* __restrict__ out) {
    cg::grid_group grid = cg::this_grid();
    int bx = blockIdx.x; int it = bx & 31, b = bx >> 5; int i0 = it * 32;
    __shared__ __align__(16) char smem[46080];
    _Float16 (*sAm)[96][72] = reinterpret_cast<_Float16(*)[96][72]>(smem);
    _Float16 (*sBm)[64][72] = reinterpret_cast<_Float16(*)[64][72]>(smem + 27648);
    _Float16 (*sZ)[200]     = reinterpret_cast<_Float16(*)[200]>(smem);
    _Float16 (*sW)[72]      = reinterpret_cast<_Float16(*)[72]>(smem + 12800);
    __shared__ _Float16 zS[32][64];   // persistent gate output
    __shared__ float sS2[3][32];
    int tid = threadIdx.x;
    int w = tid >> 6, lane = tid & 63, ln = lane & 15, kg = lane >> 4;

    float h_reg[2][4] = {{0.f, 0.f, 0.f, 0.f}, {0.f, 0.f, 0.f, 0.f}};
    float wxg0[2], wxg1[2], wxg2[2], bgr[2];
    #pragma unroll
    for (int n = 0; n < 2; ++n) {
        int o = w * 32 + n * 16 + ln;
        wxg0[n] = wx[o]; wxg1[n] = wx[128 + o]; wxg2[n] = wx[256 + o]; bgr[n] = bg[o];
    }
    int ou = w * 16 + ln;
    float wxu0 = wx[384 + ou], wxu1 = wx[448 + ou], wxu2 = wx[512 + ou], bur = bu[ou];

    int srow = tid >> 3, sc8 = (tid & 7) * 8;
    const _Float16* pa0 = AG + ((size_t)(b * 3 + 0) << 20) + ((size_t)(i0 + srow) << 10) + sc8;
    const _Float16* pa1 = AG + ((size_t)(b * 3 + 1) << 20) + ((size_t)(i0 + srow) << 10) + sc8;
    const _Float16* pa2 = AG + ((size_t)(b * 3 + 2) << 20) + ((size_t)(i0 + srow) << 10) + sc8;
    size_t hoff0 = ((size_t)b << 16) + ((size_t)srow << 10) + sc8;
    size_t hoff1 = ((size_t)b << 16) + ((size_t)(srow + 32) << 10) + sc8;
    int kbF = (w * 3) >> 2, kbL = (w * 3 + 2) >> 2;

    for (int t = 0; t < T_; ++t) {
        #pragma unroll
        for (int phase = 0; phase < 2; ++phase) {
            const _Float16* HtIn = phase ? HtB : HtA;
            if (tid < 96) { int k = tid >> 5, il = tid & 31; sS2[k][il] = S2[(((size_t)(b * 3 + k) * T_ + t) << 10) + i0 + il]; }
            const _Float16* pb0 = HtIn + hoff0;
            const _Float16* pb1 = HtIn + hoff1;

            f32x4 acc[2][3];
            #pragma unroll
            for (int m = 0; m < 2; ++m)
                #pragma unroll
                for (int n = 0; n < 3; ++n) acc[m][n] = (f32x4){0.f, 0.f, 0.f, 0.f};

            f16x8 rA0 = *(const f16x8*)pa0, rA1 = *(const f16x8*)pa1, rA2 = *(const f16x8*)pa2;
            f16x8 rB0 = *(const f16x8*)pb0, rB1 = *(const f16x8*)pb1;
            *(f16x8*)&sAm[0][srow][sc8] = rA0;
            *(f16x8*)&sAm[0][32 + srow][sc8] = rA1;
            *(f16x8*)&sAm[0][64 + srow][sc8] = rA2;
            *(f16x8*)&sBm[0][srow][sc8] = rB0;
            *(f16x8*)&sBm[0][srow + 32][sc8] = rB1;
            __syncthreads();

            for (int tt = 0; tt < 16; ++tt) {
                int cur = tt & 1;
                if (tt < 15) {
                    int kn = (tt + 1) * 64;
                    rA0 = *(const f16x8*)&pa0[kn]; rA1 = *(const f16x8*)&pa1[kn]; rA2 = *(const f16x8*)&pa2[kn];
                    rB0 = *(const f16x8*)&pb0[kn]; rB1 = *(const f16x8*)&pb1[kn];
                }
                #pragma unroll
                for (int ks = 0; ks < 2; ++ks) {
                    int ko = ks * 32 + kg * 8;
                    f16x8 aF0 = *(const f16x8*)&sAm[cur][kbF * 32 + ln][ko];
                    f16x8 aF1 = *(const f16x8*)&sAm[cur][kbF * 32 + 16 + ln][ko];
                    f16x8 aL0 = *(const f16x8*)&sAm[cur][kbL * 32 + ln][ko];
                    f16x8 aL1 = *(const f16x8*)&sAm[cur][kbL * 32 + 16 + ln][ko];
                    #pragma unroll
                    for (int ni = 0; ni < 3; ++ni) {
                        int ct = w * 3 + ni;
                        f16x8 bb = *(const f16x8*)&sBm[cur][(ct & 3) * 16 + ln][ko];
                        bool late = (ct >> 2) != kbF;
                        f16x8 a0 = late ? aL0 : aF0;
                        f16x8 a1 = late ? aL1 : aF1;
                        acc[0][ni] = __builtin_amdgcn_mfma_f32_16x16x32_f16(a0, bb, acc[0][ni], 0, 0, 0);
                        acc[1][ni] = __builtin_amdgcn_mfma_f32_16x16x32_f16(a1, bb, acc[1][ni], 0, 0, 0);
                    }
                }
                if (tt < 15) {
                    int nb = cur ^ 1;
                    *(f16x8*)&sAm[nb][srow][sc8] = rA0;
                    *(f16x8*)&sAm[nb][32 + srow][sc8] = rA1;
                    *(f16x8*)&sAm[nb][64 + srow][sc8] = rA2;
                    *(f16x8*)&sBm[nb][srow][sc8] = rB0;
                    *(f16x8*)&sBm[nb][srow + 32][sc8] = rB1;
                    __syncthreads();
                }
            }
            __syncthreads();

            #pragma unroll
            for (int m = 0; m < 2; ++m)
                #pragma unroll
                for (int ni = 0; ni < 3; ++ni)
                    #pragma unroll
                    for (int r = 0; r < 4; ++r)
                        sZ[m * 16 + kg * 4 + r][(w * 3 + ni) * 16 + ln] = (_Float16)acc[m][ni][r];

            if (phase == 0) {
                f32x4 e[2][2];
                #pragma unroll
                for (int m = 0; m < 2; ++m)
                    #pragma unroll
                    for (int n = 0; n < 2; ++n) e[m][n] = (f32x4){0.f, 0.f, 0.f, 0.f};
                for (int kc = 0; kc < 192; kc += 64) {
                    #pragma unroll
                    for (int it2 = 0; it2 < 4; ++it2) {
                        int idx = it2 * 256 + tid; int row = idx >> 3, c8 = (idx & 7) * 8;
                        *(f16x8*)&sW[row][c8] = *(const f16x8*)&wghT[(size_t)row * 192 + kc + c8];
                    }
                    __syncthreads();
                    #pragma unroll
                    for (int ks = 0; ks < 4; ++ks) {
                        int ko = ks * 16 + kg * 4;
                        f16x4 az0 = *(const f16x4*)&sZ[ln][kc + ko];
                        f16x4 az1 = *(const f16x4*)&sZ[16 + ln][kc + ko];
                        f16x4 bw0 = *(const f16x4*)&sW[w * 32 + ln][ko];
                        f16x4 bw1 = *(const f16x4*)&sW[w * 32 + 16 + ln][ko];
                        e[0][0] = __builtin_amdgcn_mfma_f32_16x16x16f16(az0, bw0, e[0][0], 0, 0, 0);
                        e[0][1] = __builtin_amdgcn_mfma_f32_16x16x16f16(az0, bw1, e[0][1], 0, 0, 0);
                        e[1][0] = __builtin_amdgcn_mfma_f32_16x16x16f16(az1, bw0, e[1][0], 0, 0, 0);
                        e[1][1] = __builtin_amdgcn_mfma_f32_16x16x16f16(az1, bw1, e[1][1], 0, 0, 0);
                    }
                    __syncthreads();
                }
                #pragma unroll
                for (int n = 0; n < 2; ++n) {
                    int o = w * 32 + n * 16 + ln;
                    if (o < H_) {
                        #pragma unroll
                        for (int m = 0; m < 2; ++m)
                            #pragma unroll
                            for (int r = 0; r < 4; ++r) {
                                int il = m * 16 + kg * 4 + r;
                                float pre = e[m][n][r] + wxg0[n] * sS2[0][il] + wxg1[n] * sS2[1][il] + wxg2[n] * sS2[2][il] + bgr[n];
                                zS[il][o] = (_Float16)(1.0f / (1.0f + expf(-pre)));
                            }
                    } else {
                        int c = o - H_;
                        #pragma unroll
                        for (int m = 0; m < 2; ++m) {
                            f16x4 hold4 = *(const f16x4*)&HtA[((size_t)(b * 64 + c) << 10) + i0 + m * 16 + kg * 4];
                            alignas(8) _Float16 hb[4];
                            #pragma unroll
                            for (int r = 0; r < 4; ++r) {
                                int il = m * 16 + kg * 4 + r;
                                float pre = e[m][n][r] + wxg0[n] * sS2[0][il] + wxg1[n] * sS2[1][il] + wxg2[n] * sS2[2][il] + bgr[n];
                                float v = 1.0f / (1.0f + expf(-pre));
                                hb[r] = (_Float16)(v * (float)hold4[r]);
                            }
                            *(f16x4*)&HtB[((size_t)(b * 64 + c) << 10) + i0 + m * 16 + kg * 4] = *(f16x4*)&hb[0];
                        }
                    }
                }
            } else {
                f32x4 e[2];
                e[0] = (f32x4){0.f, 0.f, 0.f, 0.f};
                e[1] = (f32x4){0.f, 0.f, 0.f, 0.f};
                for (int kc = 0; kc < 192; kc += 64) {
                    #pragma unroll
                    for (int it2 = 0; it2 < 2; ++it2) {
                        int idx = it2 * 256 + tid; int row = idx >> 3, c8 = (idx & 7) * 8;
                        *(f16x8*)&sW[row][c8] = *(const f16x8*)&wuhT[(size_t)row * 192 + kc + c8];
                    }
                    __syncthreads();
                    #pragma unroll
                    for (int ks = 0; ks < 4; ++ks) {
                        int ko = ks * 16 + kg * 4;
                        f16x4 az0 = *(const f16x4*)&sZ[ln][kc + ko];
                        f16x4 az1 = *(const f16x4*)&sZ[16 + ln][kc + ko];
                        f16x4 bw  = *(const f16x4*)&sW[w * 16 + ln][ko];
                        e[0] = __builtin_amdgcn_mfma_f32_16x16x16f16(az0, bw, e[0], 0, 0, 0);
                        e[1] = __builtin_amdgcn_mfma_f32_16x16x16f16(az1, bw, e[1], 0, 0, 0);
                    }
                    __syncthreads();
                }
                #pragma unroll
                for (int m = 0; m < 2; ++m) {
                    alignas(8) _Float16 hb[4];
                    #pragma unroll
                    for (int r = 0; r < 4; ++r) {
                        int il = m * 16 + kg * 4 + r;
                        float pre = e[m][r] + wxu0 * sS2[0][il] + wxu1 * sS2[1][il] + wxu2 * sS2[2][il] + bur;
                        float hc = tanhf(pre);
                        float z = (float)zS[il][ou];
                        float hn = z * hc + (1.0f - z) * h_reg[m][r];
                        h_reg[m][r] = hn;
                        hb[r] = (_Float16)hn;
                    }
                    *(f16x4*)&HtA[((size_t)(b * 64 + ou) << 10) + i0 + m * 16 + kg * 4] = *(f16x4*)&hb[0];
                }
            }
            if (t < T_ - 1 || phase == 0) {
                __threadfence();
                grid.sync();
            }
        }
    }

    // ---- decoder from f32 h_reg ----
    __syncthreads();
    float* hF  = (float*)smem;              // [32][64]
    float* wds = (float*)(smem + 8192);     // [768]
    float* bds = (float*)(smem + 11264);    // [12]
    #pragma unroll
    for (int m = 0; m < 2; ++m)
        #pragma unroll
        for (int r = 0; r < 4; ++r)
            hF[(m * 16 + kg * 4 + r) * 64 + ou] = h_reg[m][r];
    for (int idx = tid; idx < 768; idx += 256) wds[idx] = Wd[idx];
    if (tid < 12) bds[tid] = bd[tid];
    __syncthreads();
    for (int oidx = tid; oidx < 384; oidx += 256) {
        int il = oidx & 31, tt = oidx >> 5;
        float acc = bds[tt];
        #pragma unroll
        for (int c = 0; c < 64; ++c) acc += hF[il * 64 + c] * wds[c * 12 + tt];
        out[(((size_t)(b * T_ + tt)) << 10) + i0 + il] = acc;
    }
}

// ============================================================================
// Fallback path (proven round-11 structure): per-step kernels, grid 1024.
// zf is f16; h stays f32 (proven numerics). Decoder folded into fup at t=11.
// ============================================================================
__global__ __launch_bounds__(256) void k_fzr2(const _Float16* __restrict__ AG,
                                              const _Float16* __restrict__ HtIn,
                                              const _Float16* __restrict__ wghT,
                                              const float* __restrict__ wx,
                                              const float* __restrict__ bg,
                                              const float* __restrict__ S2,
                                              const float* __restrict__ h,
                                              _Float16* __restrict__ zf,
                                              _Float16* __restrict__ HtOut, int t) {
    int bx = blockIdx.x; int it = bx & 63, b = bx >> 6; int i0 = it * 16;
    __shared__ __align__(16) char smem[32256];
    _Float16 (*sA)[48][72] = reinterpret_cast<_Float16(*)[48][72]>(smem);
    _Float16 (*sB)[64][72] = reinterpret_cast<_Float16(*)[64][72]>(smem + 13824);
    _Float16 (*sZ)[200]    = reinterpret_cast<_Float16(*)[200]>(smem);
    _Float16 (*sW)[72]     = reinterpret_cast<_Float16(*)[72]>(smem + 6400);
    __shared__ float sS2[3][16];
    __shared__ float sWX[384];
    __shared__ float sBias[128];
    int tid = threadIdx.x;
    int w = tid >> 6, lane = tid & 63, ln = lane & 15, kg = lane >> 4;
    if (tid < 48) { int k = tid >> 4, il = tid & 15; sS2[k][il] = S2[(((size_t)(b * 3 + k) * T_ + t) << 10) + i0 + il]; }
    for (int q = tid; q < 384; q += 256) sWX[q] = wx[q];
    if (tid < 128) sBias[tid] = bg[tid];

    const _Float16* pA[3]; int c4A[3], rowA[3];
    #pragma unroll
    for (int q = 0; q < 3; ++q) {
        int idx = q * 256 + tid; rowA[q] = idx >> 4; c4A[q] = (idx & 15) * 4;
        int kb = rowA[q] >> 4, rloc = rowA[q] & 15;
        pA[q] = AG + ((size_t)(b * 3 + kb) << 20) + ((size_t)(i0 + rloc) << 10) + c4A[q];
    }
    const _Float16* pB[2]; int c8B[2], rowB[2];
    #pragma unroll
    for (int q = 0; q < 2; ++q) {
        int idx = q * 256 + tid; rowB[q] = idx >> 3; c8B[q] = (idx & 7) * 8;
        pB[q] = HtIn + ((size_t)b << 16) + ((size_t)rowB[q] << 10) + c8B[q];
    }

    f32x4 acc[3];
    #pragma unroll
    for (int n = 0; n < 3; ++n) acc[n] = (f32x4){0.f, 0.f, 0.f, 0.f};

    f16x4 ra[3]; f16x8 rb[2];
    #pragma unroll
    for (int q = 0; q < 3; ++q) ra[q] = *(const f16x4*)pA[q];
    #pragma unroll
    for (int q = 0; q < 2; ++q) rb[q] = *(const f16x8*)pB[q];
    #pragma unroll
    for (int q = 0; q < 3; ++q) *(f16x4*)&sA[0][rowA[q]][c4A[q]] = ra[q];
    #pragma unroll
    for (int q = 0; q < 2; ++q) *(f16x8*)&sB[0][rowB[q]][c8B[q]] = rb[q];
    __syncthreads();

    int kbF = (w * 3) >> 2, kbL = (w * 3 + 2) >> 2;
    for (int tt = 0; tt < 16; ++tt) {
        int cur = tt & 1;
        if (tt < 15) {
            int kn = (tt + 1) * 64;
            #pragma unroll
            for (int q = 0; q < 3; ++q) ra[q] = *(const f16x4*)&pA[q][kn];
            #pragma unroll
            for (int q = 0; q < 2; ++q) rb[q] = *(const f16x8*)&pB[q][kn];
        }
        #pragma unroll
        for (int ks = 0; ks < 2; ++ks) {
            int ko = ks * 32 + kg * 8;
            f16x8 aF = *(const f16x8*)&sA[cur][kbF * 16 + ln][ko];
            f16x8 aL = *(const f16x8*)&sA[cur][kbL * 16 + ln][ko];
            #pragma unroll
            for (int ni = 0; ni < 3; ++ni) {
                int ct = w * 3 + ni;
                f16x8 bb = *(const f16x8*)&sB[cur][(ct & 3) * 16 + ln][ko];
                f16x8 a = ((ct >> 2) != kbF) ? aL : aF;
                acc[ni] = __builtin_amdgcn_mfma_f32_16x16x32_f16(a, bb, acc[ni], 0, 0, 0);
            }
        }
        if (tt < 15) {
            int nb = cur ^ 1;
            #pragma unroll
            for (int q = 0; q < 3; ++q) *(f16x4*)&sA[nb][rowA[q]][c4A[q]] = ra[q];
            #pragma unroll
            for (int q = 0; q < 2; ++q) *(f16x8*)&sB[nb][rowB[q]][c8B[q]] = rb[q];
            __syncthreads();
        }
    }
    __syncthreads();

    #pragma unroll
    for (int ni = 0; ni < 3; ++ni)
        #pragma unroll
        for (int r = 0; r < 4; ++r)
            sZ[kg * 4 + r][(w * 3 + ni) * 16 + ln] = (_Float16)acc[ni][r];

    f32x4 e[2];
    e[0] = (f32x4){0.f, 0.f, 0.f, 0.f};
    e[1] = (f32x4){0.f, 0.f, 0.f, 0.f};
    for (int kc = 0; kc < 192; kc += 64) {
        #pragma unroll
        for (int it2 = 0; it2 < 4; ++it2) {
            int idx = it2 * 256 + tid; int row = idx >> 3, c8 = (idx & 7) * 8;
            *(f16x8*)&sW[row][c8] = *(const f16x8*)&wghT[(size_t)row * 192 + kc + c8];
        }
        __syncthreads();
        #pragma unroll
        for (int ks = 0; ks < 4; ++ks) {
            int ko = ks * 16 + kg * 4;
            f16x4 az  = *(const f16x4*)&sZ[ln][kc + ko];
            f16x4 bw0 = *(const f16x4*)&sW[w * 32 + ln][ko];
            f16x4 bw1 = *(const f16x4*)&sW[w * 32 + 16 + ln][ko];
            e[0] = __builtin_amdgcn_mfma_f32_16x16x16f16(az, bw0, e[0], 0, 0, 0);
            e[1] = __builtin_amdgcn_mfma_f32_16x16x16f16(az, bw1, e[1], 0, 0, 0);
        }
        __syncthreads();
    }

    #pragma unroll
    for (int n = 0; n < 2; ++n) {
        int o = w * 32 + n * 16 + ln;
        float w0 = sWX[o], w1 = sWX[128 + o], w2 = sWX[256 + o], bi = sBias[o];
        if (o < H_) {
            alignas(8) _Float16 zv[4];
            #pragma unroll
            for (int r = 0; r < 4; ++r) {
                int il = kg * 4 + r;
                float pre = e[n][r] + w0 * sS2[0][il] + w1 * sS2[1][il] + w2 * sS2[2][il] + bi;
                zv[r] = (_Float16)(1.0f / (1.0f + expf(-pre)));
            }
            *(f16x4*)&zf[((size_t)(b * 64 + o) << 10) + i0 + kg * 4] = *(f16x4*)&zv[0];
        } else {
            int c = o - H_;
            alignas(8) _Float16 hb[4];
            #pragma unroll
            for (int r = 0; r < 4; ++r) {
                int il = kg * 4 + r;
                float pre = e[n][r] + w0 * sS2[0][il] + w1 * sS2[1][il] + w2 * sS2[2][il] + bi;
                float v = 1.0f / (1.0f + expf(-pre));
                hb[r] = (_Float16)(v * h[((size_t)((b << 10) + i0 + il)) * H_ + c]);
            }
            *(f16x4*)&HtOut[((size_t)(b * 64 + c) << 10) + i0 + kg * 4] = *(f16x4*)&hb[0];
        }
    }
}

__global__ __launch_bounds__(256) void k_fup2(const _Float16* __restrict__ AG,
                                              const _Float16* __restrict__ HtIn,
                                              const _Float16* __restrict__ wuhT,
                                              const float* __restrict__ wx,
                                              const float* __restrict__ bu,
                                              const float* __restrict__ S2,
                                              const _Float16* __restrict__ zf,
                                              float* __restrict__ h,
                                              _Float16* __restrict__ HtOut,
                                              const float* __restrict__ Wd,
                                              const float* __restrict__ bd,
                                              float* __restrict__ out, int t) {
    int bx = blockIdx.x; int it = bx & 63, b = bx >> 6; int i0 = it * 16;
    __shared__ __align__(16) char smem[32256];
    _Float16 (*sA)[48][72] = reinterpret_cast<_Float16(*)[48][72]>(smem);
    _Float16 (*sB)[64][72] = reinterpret_cast<_Float16(*)[64][72]>(smem + 13824);
    _Float16 (*sZ)[200]    = reinterpret_cast<_Float16(*)[200]>(smem);
    _Float16 (*sW)[72]     = reinterpret_cast<_Float16(*)[72]>(smem + 6400);
    __shared__ float sS2[3][16];
    __shared__ float sWX[192];
    __shared__ float sBias[64];
    int tid = threadIdx.x;
    int w = tid >> 6, lane = tid & 63, ln = lane & 15, kg = lane >> 4;
    if (tid < 48) { int k = tid >> 4, il = tid & 15; sS2[k][il] = S2[(((size_t)(b * 3 + k) * T_ + t) << 10) + i0 + il]; }
    if (tid < 192) sWX[tid] = wx[384 + tid];
    if (tid < 64) sBias[tid] = bu[tid];

    const _Float16* pA[3]; int c4A[3], rowA[3];
    #pragma unroll
    for (int q = 0; q < 3; ++q) {
        int idx = q * 256 + tid; rowA[q] = idx >> 4; c4A[q] = (idx & 15) * 4;
        int kb = rowA[q] >> 4, rloc = rowA[q] & 15;
        pA[q] = AG + ((size_t)(b * 3 + kb) << 20) + ((size_t)(i0 + rloc) << 10) + c4A[q];
    }
    const _Float16* pB[2]; int c8B[2], rowB[2];
    #pragma unroll
    for (int q = 0; q < 2; ++q) {
        int idx = q * 256 + tid; rowB[q] = idx >> 3; c8B[q] = (idx & 7) * 8;
        pB[q] = HtIn + ((size_t)b << 16) + ((size_t)rowB[q] << 10) + c8B[q];
    }

    f32x4 acc[3];
    #pragma unroll
    for (int n = 0; n < 3; ++n) acc[n] = (f32x4){0.f, 0.f, 0.f, 0.f};

    f16x4 ra[3]; f16x8 rb[2];
    #pragma unroll
    for (int q = 0; q < 3; ++q) ra[q] = *(const f16x4*)pA[q];
    #pragma unroll
    for (int q = 0; q < 2; ++q) rb[q] = *(const f16x8*)pB[q];
    #pragma unroll
    for (int q = 0; q < 3; ++q) *(f16x4*)&sA[0][rowA[q]][c4A[q]] = ra[q];
    #pragma unroll
    for (int q = 0; q < 2; ++q) *(f16x8*)&sB[0][rowB[q]][c8B[q]] = rb[q];
    __syncthreads();

    int kbF = (w * 3) >> 2, kbL = (w * 3 + 2) >> 2;
    for (int tt = 0; tt < 16; ++tt) {
        int cur = tt & 1;
        if (tt < 15) {
            int kn = (tt + 1) * 64;
            #pragma unroll
            for (int q = 0; q < 3; ++q) ra[q] = *(const f16x4*)&pA[q][kn];
            #pragma unroll
            for (int q = 0; q < 2; ++q) rb[q] = *(const f16x8*)&pB[q][kn];
        }
        #pragma unroll
        for (int ks = 0; ks < 2; ++ks) {
            int ko = ks * 32 + kg * 8;
            f16x8 aF = *(const f16x8*)&sA[cur][kbF * 16 + ln][ko];
            f16x8 aL = *(const f16x8*)&sA[cur][kbL * 16 + ln][ko];
            #pragma unroll
            for (int ni = 0; ni < 3; ++ni) {
                int ct = w * 3 + ni;
                f16x8 bb = *(const f16x8*)&sB[cur][(ct & 3) * 16 + ln][ko];
                f16x8 a = ((ct >> 2) != kbF) ? aL : aF;
                acc[ni] = __builtin_amdgcn_mfma_f32_16x16x32_f16(a, bb, acc[ni], 0, 0, 0);
            }
        }
        if (tt < 15) {
            int nb = cur ^ 1;
            #pragma unroll
            for (int q = 0; q < 3; ++q) *(f16x4*)&sA[nb][rowA[q]][c4A[q]] = ra[q];
            #pragma unroll
            for (int q = 0; q < 2; ++q) *(f16x8*)&sB[nb][rowB[q]][c8B[q]] = rb[q];
            __syncthreads();
        }
    }
    __syncthreads();

    #pragma unroll
    for (int ni = 0; ni < 3; ++ni)
        #pragma unroll
        for (int r = 0; r < 4; ++r)
            sZ[kg * 4 + r][(w * 3 + ni) * 16 + ln] = (_Float16)acc[ni][r];

    f32x4 e = (f32x4){0.f, 0.f, 0.f, 0.f};
    for (int kc = 0; kc < 192; kc += 64) {
        #pragma unroll
        for (int it2 = 0; it2 < 2; ++it2) {
            int idx = it2 * 256 + tid; int row = idx >> 3, c8 = (idx & 7) * 8;
            *(f16x8*)&sW[row][c8] = *(const f16x8*)&wuhT[(size_t)row * 192 + kc + c8];
        }
        __syncthreads();
        #pragma unroll
        for (int ks = 0; ks < 4; ++ks) {
            int ko = ks * 16 + kg * 4;
            f16x4 az = *(const f16x4*)&sZ[ln][kc + ko];
            f16x4 bw = *(const f16x4*)&sW[w * 16 + ln][ko];
            e = __builtin_amdgcn_mfma_f32_16x16x16f16(az, bw, e, 0, 0, 0);
        }
        __syncthreads();
    }

    int o = w * 16 + ln;
    float w0 = sWX[o], w1 = sWX[64 + o], w2 = sWX[128 + o], bi = sBias[o];
    f16x4 z4 = *(const f16x4*)&zf[((size_t)(b * 64 + o) << 10) + i0 + kg * 4];
    alignas(8) _Float16 hb[4];
    float hnv[4];
    #pragma unroll
    for (int r = 0; r < 4; ++r) {
        int il = kg * 4 + r;
        float pre = e[r] + w0 * sS2[0][il] + w1 * sS2[1][il] + w2 * sS2[2][il] + bi;
        float hc = tanhf(pre);
        size_t gi = ((size_t)((b << 10) + i0 + il)) * H_ + o;
        float z = (float)z4[r];
        float hn = z * hc + (1.0f - z) * h[gi];
        h[gi] = hn;
        hnv[r] = hn;
        hb[r] = (_Float16)hn;
    }
    *(f16x4*)&HtOut[((size_t)(b * 64 + o) << 10) + i0 + kg * 4] = *(f16x4*)&hb[0];

    if (t == T_ - 1) {
        __syncthreads();
        float* hF  = (float*)smem;              // [16][64]
        float* wds = (float*)(smem + 4096);     // [768]
        float* bds = (float*)(smem + 7168);     // [12]
        #pragma unroll
        for (int r = 0; r < 4; ++r) hF[(kg * 4 + r) * 64 + o] = hnv[r];
        for (int idx = tid; idx < 768; idx += 256) wds[idx] = Wd[idx];
        if (tid < 12) bds[tid] = bd[tid];
        __syncthreads();
        for (int oidx = tid; oidx < 192; oidx += 256) {
            int il = oidx & 15, tt2 = oidx >> 4;
            float acc2 = bds[tt2];
            #pragma unroll
            for (int c = 0; c < 64; ++c) acc2 += hF[il * 64 + c] * wds[c * 12 + tt2];
            out[(((size_t)(b * T_ + tt2)) << 10) + i0 + il] = acc2;
        }
    }
}

extern "C" void kernel_launch(void* const* d_in, const int* in_sizes, int n_in,
                              void* d_out, int out_size, void* d_ws, size_t ws_size,
                              hipStream_t stream) {
    const float* x  = (const float*)d_in[0];
    const float* G  = (const float*)d_in[1];
    const float* A  = (const float*)d_in[2];
    const float* Wg = (const float*)d_in[3];
    const float* bg = (const float*)d_in[4];
    const float* Wu = (const float*)d_in[5];
    const float* bu = (const float*)d_in[6];
    const float* Wd = (const float*)d_in[7];
    const float* bd = (const float*)d_in[8];
    float* out = (float*)d_out;
    float* ws  = (float*)d_ws;

    float* h   = ws + OFF_H;
    float* S2  = ws + OFF_S2;
    float* wxb = ws + OFF_WX;
    _Float16* zf   = (_Float16*)(ws + OFF_ZF);
    _Float16* HtA  = (_Float16*)(ws + OFF_HTA);
    _Float16* HtB  = (_Float16*)(ws + OFF_HTB);
    _Float16* S1   = (_Float16*)(ws + OFF_S1);
    _Float16* wghT = (_Float16*)(ws + OFF_WGT);
    _Float16* wuhT = (_Float16*)(ws + OFF_WUT);
    _Float16* GfT  = (_Float16*)(ws + OFF_GT);
    _Float16* AG   = (_Float16*)(ws + OFF_AG);
    _Float16* Af   = (_Float16*)(ws + OFF_AF);

    hipMemsetAsync(h, 0, (size_t)B_ * N_ * H_ * sizeof(float), stream);
    hipMemsetAsync((void*)HtA, 0, (size_t)B_ * N_ * H_ * sizeof(_Float16), stream);
    k_pre<<<9203, 256, 0, stream>>>(A, G, x, Wg, Wu, Af, GfT, S1, wghT, wuhT, wxb);
    k_main<<<3328, 256, 0, stream>>>(Af, GfT, AG, S1, S2);

    // deterministic path choice: cooperative only if the runtime guarantees
    // 2 blocks/CU co-residency for k_loop (grid 512 on 256 CUs).
    int nb = 0;
    hipOccupancyMaxActiveBlocksPerMultiprocessor(&nb, k_loop, 256, 0);
    if (nb >= 2) {
        void* args[] = {(void*)&AG, (void*)&HtA, (void*)&HtB, (void*)&wghT, (void*)&wuhT,
                        (void*)&wxb, (void*)&bg, (void*)&bu, (void*)&S2,
                        (void*)&Wd, (void*)&bd, (void*)&out};
        hipLaunchCooperativeKernel((const void*)k_loop, dim3(512), dim3(256), args, 0, stream);
    } else {
        for (int t = 0; t < T_; ++t) {
            k_fzr2<<<1024, 256, 0, stream>>>(AG, HtA, wghT, wxb, bg, S2, h, zf, HtB, t);
            k_fup2<<<1024, 256, 0, stream>>>(AG, HtB, wuhT, wxb, bu, S2, zf, h, HtA, Wd, bd, out, t);
        }
    }
}

// Round 15
// 799.009 us; speedup vs baseline: 2.4550x; 1.0010x over previous
//
#include <hip/hip_runtime.h>
#include <hip/hip_cooperative_groups.h>

namespace cg = cooperative_groups;

#define B_  16
#define T_  12
#define N_  1024
#define K_  3
#define H_  64
#define DIN 65
#define KH  192
#define OG  128

typedef _Float16 f16x4 __attribute__((ext_vector_type(4)));
typedef _Float16 f16x8 __attribute__((ext_vector_type(8)));
typedef float    f32x4 __attribute__((ext_vector_type(4)));

// ---- workspace offsets (float units), total ~156.7 MB (< ~268 MB evidenced) ----
static const size_t OFF_H   = 0;          // f32 h    [16][1024][64]  (fallback only)
static const size_t OFF_ZF  = 1048576;    // f16 zf   [16][64][1024]  (fallback only)
static const size_t OFF_S2  = 2097152;    // f32 S2   [16][3][12][1024] (x1024)
static const size_t OFF_HTA = 2686976;    // f16 HtA  [16][64][1024]
static const size_t OFF_HTB = 3211264;    // f16 HtB  [16][64][1024]
static const size_t OFF_S1  = 3735552;    // f16 S1   [3][192][1024]
static const size_t OFF_WGT = 4030464;    // f16 wghT [128][192] (/1024)
static const size_t OFF_WUT = 4042752;    // f16 wuhT [64][192]  (/1024)
static const size_t OFF_WX  = 4048896;    // f32 wx (576)
static const size_t OFF_GT  = 4049472;    // f16 GfT  [3][1024][1024]
static const size_t OFF_AG  = 5622336;    // f16 AG   [16][3][1024][1024]
static const size_t OFF_AF  = 30788160;   // f16 Af   [16][1024][1024] = 1024*A

// ============================================================================
// Fused preamble phase A: [s1b | gtr | repack | acvt] (mutually independent).
// s1b first so its latency-bound tail overlaps the BW-bound rest.
// grid = 96 + 768 + 147 + 8192 = 9203
// ============================================================================
__global__ __launch_bounds__(256) void k_pre(const float* __restrict__ A,
                                             const float* __restrict__ G,
                                             const float* __restrict__ x,
                                             const float* __restrict__ Wg,
                                             const float* __restrict__ Wu,
                                             _Float16* __restrict__ Af,
                                             _Float16* __restrict__ GfT,
                                             _Float16* __restrict__ S1,
                                             _Float16* __restrict__ wghT,
                                             _Float16* __restrict__ wuhT,
                                             float* __restrict__ wx) {
    __shared__ __align__(16) char smem[23040];
    int bx0 = blockIdx.x, tid = threadIdx.x;
    if (bx0 < 96) {
        // ---- s1b: S1[k][m][i] = sum_j G[k][i][j] x[m][j] ----
        int bx = bx0;
        int nh = bx & 1, it = (bx >> 1) & 15, kk = bx >> 5;
        int i0 = it * 64, m0 = nh * 96;
        _Float16 (*sA)[72] = reinterpret_cast<_Float16(*)[72]>(smem);
        _Float16 (*sB)[72] = reinterpret_cast<_Float16(*)[72]>(smem + 9216);
        int wid = tid >> 6, ln = tid & 15, kl = (tid & 63) >> 4;
        const float* Gk = G + (size_t)kk * N_ * N_;
        f32x4 acc[6];
        #pragma unroll
        for (int n = 0; n < 6; ++n) acc[n] = (f32x4){0.f, 0.f, 0.f, 0.f};
        for (int kc = 0; kc < N_; kc += 64) {
            #pragma unroll
            for (int it2 = 0; it2 < 4; ++it2) {
                int idx = it2 * 256 + tid; int row = idx >> 4, c4 = (idx & 15) * 4;
                float4 g = *(const float4*)&Gk[(size_t)(i0 + row) * N_ + kc + c4];
                f16x4 hv = {(_Float16)g.x, (_Float16)g.y, (_Float16)g.z, (_Float16)g.w};
                *(f16x4*)&sA[row][c4] = hv;
            }
            #pragma unroll
            for (int it2 = 0; it2 < 6; ++it2) {
                int idx = it2 * 256 + tid; int row = idx >> 4, c4 = (idx & 15) * 4;
                float4 g = *(const float4*)&x[(size_t)(m0 + row) * N_ + kc + c4];
                f16x4 hv = {(_Float16)g.x, (_Float16)g.y, (_Float16)g.z, (_Float16)g.w};
                *(f16x4*)&sB[row][c4] = hv;
            }
            __syncthreads();
            #pragma unroll
            for (int ks = 0; ks < 4; ++ks) {
                int ko = ks * 16 + kl * 4;
                f16x4 a = *(const f16x4*)&sA[wid * 16 + ln][ko];
                #pragma unroll
                for (int n = 0; n < 6; ++n) {
                    f16x4 b = *(const f16x4*)&sB[n * 16 + ln][ko];
                    acc[n] = __builtin_amdgcn_mfma_f32_16x16x16f16(a, b, acc[n], 0, 0, 0);
                }
            }
            __syncthreads();
        }
        #pragma unroll
        for (int n = 0; n < 6; ++n) {
            int m = m0 + n * 16 + ln;
            #pragma unroll
            for (int r = 0; r < 4; ++r) {
                int i = i0 + wid * 16 + kl * 4 + r;
                S1[(((size_t)kk * 192 + m) << 10) + i] = (_Float16)acc[n][r];
            }
        }
    } else if (bx0 < 864) {
        // ---- gtr: GfT[k][j][p] = f16(G[k][p][j]) ----
        int bx = bx0 - 96;
        int kk = bx >> 8, rem = bx & 255, ti = rem >> 4, tj = rem & 15;
        int i0 = ti * 64, j0 = tj * 64;
        _Float16 (*s)[72] = reinterpret_cast<_Float16(*)[72]>(smem);
        int r = tid >> 2, cb = (tid & 3) * 16;
        const float* Gp = G + ((size_t)kk << 20) + ((size_t)(i0 + r) << 10) + j0 + cb;
        #pragma unroll
        for (int q = 0; q < 4; ++q) {
            float4 v = *(const float4*)&Gp[q * 4];
            f16x4 hv = {(_Float16)v.x, (_Float16)v.y, (_Float16)v.z, (_Float16)v.w};
            *(f16x4*)&s[r][cb + q * 4] = hv;
        }
        __syncthreads();
        alignas(16) _Float16 tmp[16];
        #pragma unroll
        for (int q = 0; q < 16; ++q) tmp[q] = s[cb + q][r];
        _Float16* outp = GfT + ((size_t)kk << 20) + ((size_t)(j0 + r) << 10) + i0 + cb;
        *(f16x8*)&outp[0] = *(f16x8*)&tmp[0];
        *(f16x8*)&outp[8] = *(f16x8*)&tmp[8];
    } else if (bx0 < 1011) {
        // ---- repack ----
        const float inv = 1.0f / 1024.0f;
        int idx = (bx0 - 864) * 256 + tid;
        if (idx < 128 * 192) {
            int o = idx / 192, d = idx % 192;
            int k = d / 64, c = d % 64;
            wghT[idx] = (_Float16)(Wg[(size_t)(k * DIN + 1 + c) * OG + o] * inv);
        } else if (idx < 128 * 192 + 64 * 192) {
            int j = idx - 128 * 192;
            int o = j / 192, d = j % 192;
            int k = d / 64, c = d % 64;
            wuhT[j] = (_Float16)(Wu[(size_t)(k * DIN + 1 + c) * H_ + o] * inv);
        } else if (idx < 128 * 192 + 64 * 192 + 576) {
            int j = idx - 128 * 192 - 64 * 192;
            if (j < 384) { int k = j >> 7, o = j & 127; wx[j] = Wg[(size_t)(k * DIN) * OG + o] * inv; }
            else { int j2 = j - 384; int k = j2 >> 6, o = j2 & 63; wx[j] = Wu[(size_t)(k * DIN) * H_ + o] * inv; }
        }
    } else {
        // ---- acvt: Af = f16(1024*A) ----
        size_t idx = ((size_t)(bx0 - 1011) * 256 + tid) * 8;
        float4 a = *(const float4*)&A[idx];
        float4 c = *(const float4*)&A[idx + 4];
        f16x8 v = {(_Float16)(a.x*1024.f), (_Float16)(a.y*1024.f), (_Float16)(a.z*1024.f), (_Float16)(a.w*1024.f),
                   (_Float16)(c.x*1024.f), (_Float16)(c.y*1024.f), (_Float16)(c.z*1024.f), (_Float16)(c.w*1024.f)};
        *(f16x8*)&Af[idx] = v;
    }
}

// ============================================================================
// Fused phase B: [s2b | ag]. s2b first (small), ag with XCD-chunked swizzle.
// grid = 256 + 3072 = 3328
// ============================================================================
__global__ __launch_bounds__(256) void k_main(const _Float16* __restrict__ Af,
                                              const _Float16* __restrict__ GfT,
                                              _Float16* __restrict__ AG,
                                              const _Float16* __restrict__ S1,
                                              float* __restrict__ S2) {
    __shared__ __align__(16) char smem[73728];
    int bx0 = blockIdx.x, tid = threadIdx.x;
    if (bx0 < 256) {
        // ---- s2b ----
        int bx = bx0; int it = bx & 15, b = bx >> 4; int i0 = it * 64;
        _Float16 (*sA)[72] = reinterpret_cast<_Float16(*)[72]>(smem);
        _Float16 (*sB)[72] = reinterpret_cast<_Float16(*)[72]>(smem + 9216);
        int wid = tid >> 6, ln = tid & 15, kl = (tid & 63) >> 4;
        f32x4 acc[3];
        #pragma unroll
        for (int n = 0; n < 3; ++n) acc[n] = (f32x4){0.f, 0.f, 0.f, 0.f};
        for (int kc = 0; kc < N_; kc += 64) {
            #pragma unroll
            for (int it2 = 0; it2 < 2; ++it2) {
                int idx = it2 * 256 + tid; int row = idx >> 3, c8 = (idx & 7) * 8;
                *(uint4*)&sA[row][c8] = *(const uint4*)&Af[((size_t)b << 20) + ((size_t)(i0 + row) << 10) + kc + c8];
            }
            for (int idx = tid; idx < 288; idx += 256) {
                int row = idx >> 3, c8 = (idx & 7) * 8;
                int kq = row / 12, tq = row - kq * 12;
                *(uint4*)&sB[row][c8] = *(const uint4*)&S1[(((size_t)kq * 192 + b * T_ + tq) << 10) + kc + c8];
            }
            __syncthreads();
            #pragma unroll
            for (int ks = 0; ks < 4; ++ks) {
                int ko = ks * 16 + kl * 4;
                f16x4 a = *(const f16x4*)&sA[wid * 16 + ln][ko];
                #pragma unroll
                for (int n = 0; n < 3; ++n) {
                    f16x4 b = *(const f16x4*)&sB[n * 16 + ln][ko];
                    acc[n] = __builtin_amdgcn_mfma_f32_16x16x16f16(a, b, acc[n], 0, 0, 0);
                }
            }
            __syncthreads();
        }
        #pragma unroll
        for (int n = 0; n < 3; ++n) {
            int col = n * 16 + ln;
            if (col < 36) {
                int kq = col / 12, tq = col - kq * 12;
                #pragma unroll
                for (int r = 0; r < 4; ++r) {
                    int i = i0 + wid * 16 + kl * 4 + r;
                    S2[(((size_t)(b * 3 + kq) * T_ + tq) << 10) + i] = acc[n][r];
                }
            }
        }
    } else {
        // ---- ag: AG[b][k] = Af[b] @ G[k], 128x128 tiles, reg-staged dbuf ----
        int bxr = bx0 - 256;
        int bx = (bxr & 7) * 384 + (bxr >> 3);     // bijective (3072 % 8 == 0)
        int inst = bx >> 6, tile = bx & 63;
        int b = inst / 3, kk = inst % 3;
        int i0 = (tile >> 3) * 128, j0 = (tile & 7) * 128;
        _Float16 (*sA)[128][72] = reinterpret_cast<_Float16(*)[128][72]>(smem);
        _Float16 (*sB)[128][72] = reinterpret_cast<_Float16(*)[128][72]>(smem + 36864);
        int w = tid >> 6, lane = tid & 63, ln = lane & 15, kg = lane >> 4;
        int mq = (w & 1) * 64, nq = (w >> 1) * 64;
        int srow = tid >> 1, cb = (tid & 1) * 32;
        const _Float16* qa = Af  + ((size_t)b << 20)  + ((size_t)(i0 + srow) << 10) + cb;
        const _Float16* qb = GfT + ((size_t)kk << 20) + ((size_t)(j0 + srow) << 10) + cb;

        f32x4 acc[4][4];
        #pragma unroll
        for (int mt = 0; mt < 4; ++mt)
            #pragma unroll
            for (int nt = 0; nt < 4; ++nt) acc[mt][nt] = (f32x4){0.f, 0.f, 0.f, 0.f};

        f16x8 ra[4], rb[4];
        #pragma unroll
        for (int q = 0; q < 4; ++q) { ra[q] = *(const f16x8*)&qa[q * 8]; rb[q] = *(const f16x8*)&qb[q * 8]; }
        #pragma unroll
        for (int q = 0; q < 4; ++q) {
            *(f16x8*)&sA[0][srow][cb + q * 8] = ra[q];
            *(f16x8*)&sB[0][srow][cb + q * 8] = rb[q];
        }
        __syncthreads();

        for (int tt = 0; tt < 16; ++tt) {
            int cur = tt & 1;
            if (tt < 15) {
                int kn = (tt + 1) * 64;
                #pragma unroll
                for (int q = 0; q < 4; ++q) { ra[q] = *(const f16x8*)&qa[kn + q * 8]; rb[q] = *(const f16x8*)&qb[kn + q * 8]; }
            }
            #pragma unroll
            for (int ks = 0; ks < 2; ++ks) {
                int ko = ks * 32 + kg * 8;
                f16x8 a[4], bfr[4];
                #pragma unroll
                for (int mt = 0; mt < 4; ++mt) a[mt] = *(const f16x8*)&sA[cur][mq + mt * 16 + ln][ko];
                #pragma unroll
                for (int nt = 0; nt < 4; ++nt) bfr[nt] = *(const f16x8*)&sB[cur][nq + nt * 16 + ln][ko];
                #pragma unroll
                for (int mt = 0; mt < 4; ++mt)
                    #pragma unroll
                    for (int nt = 0; nt < 4; ++nt)
                        acc[mt][nt] = __builtin_amdgcn_mfma_f32_16x16x32_f16(a[mt], bfr[nt], acc[mt][nt], 0, 0, 0);
            }
            if (tt < 15) {
                int nb = cur ^ 1;
                #pragma unroll
                for (int q = 0; q < 4; ++q) {
                    *(f16x8*)&sA[nb][srow][cb + q * 8] = ra[q];
                    *(f16x8*)&sB[nb][srow][cb + q * 8] = rb[q];
                }
                __syncthreads();
            }
        }

        _Float16* outp = AG + ((size_t)(b * 3 + kk) << 20);
        #pragma unroll
        for (int mt = 0; mt < 4; ++mt)
            #pragma unroll
            for (int r = 0; r < 4; ++r) {
                int i = i0 + mq + mt * 16 + kg * 4 + r;
                #pragma unroll
                for (int nt = 0; nt < 4; ++nt) {
                    int j = j0 + nq + nt * 16 + ln;
                    outp[((size_t)i << 10) + j] = (_Float16)acc[mt][nt][r];
                }
            }
    }
}

// ============================================================================
// Cooperative fused scan (preferred path): 12 x (gate, update) + decoder.
// grid 512, block 256, __launch_bounds__(256,2) to force 2 blocks/CU.
// LDS 50.6 KB/block. h carried in f32 registers; z in LDS; f16 HtA/HtB exchange.
// ============================================================================
__global__ __launch_bounds__(256, 2) void k_loop(const _Float16* __restrict__ AG,
                                                 _Float16* __restrict__ HtA,
                                                 _Float16* __restrict__ HtB,
                                                 const _Float16* __restrict__ wghT,
                                                 const _Float16* __restrict__ wuhT,
                                                 const float* __restrict__ wx,
                                                 const float* __restrict__ bg,
                                                 const float* __restrict__ bu,
                                                 const float* __restrict__ S2,
                                                 const float* __restrict__ Wd,
                                                 const float* __restrict__ bd,
                                                 float* __restrict__ out) {
    cg::grid_group grid = cg::this_grid();
    int bx = blockIdx.x; int it = bx & 31, b = bx >> 5; int i0 = it * 32;
    __shared__ __align__(16) char smem[46080];
    _Float16 (*sAm)[96][72] = reinterpret_cast<_Float16(*)[96][72]>(smem);
    _Float16 (*sBm)[64][72] = reinterpret_cast<_Float16(*)[64][72]>(smem + 27648);
    _Float16 (*sZ)[200]     = reinterpret_cast<_Float16(*)[200]>(smem);
    _Float16 (*sW)[72]      = reinterpret_cast<_Float16(*)[72]>(smem + 12800);
    __shared__ _Float16 zS[32][64];   // persistent gate output
    __shared__ float sS2[3][32];
    int tid = threadIdx.x;
    int w = tid >> 6, lane = tid & 63, ln = lane & 15, kg = lane >> 4;

    float h_reg[2][4] = {{0.f, 0.f, 0.f, 0.f}, {0.f, 0.f, 0.f, 0.f}};
    float wxg0[2], wxg1[2], wxg2[2], bgr[2];
    #pragma unroll
    for (int n = 0; n < 2; ++n) {
        int o = w * 32 + n * 16 + ln;
        wxg0[n] = wx[o]; wxg1[n] = wx[128 + o]; wxg2[n] = wx[256 + o]; bgr[n] = bg[o];
    }
    int ou = w * 16 + ln;
    float wxu0 = wx[384 + ou], wxu1 = wx[448 + ou], wxu2 = wx[512 + ou], bur = bu[ou];

    int srow = tid >> 3, sc8 = (tid & 7) * 8;
    const _Float16* pa0 = AG + ((size_t)(b * 3 + 0) << 20) + ((size_t)(i0 + srow) << 10) + sc8;
    const _Float16* pa1 = AG + ((size_t)(b * 3 + 1) << 20) + ((size_t)(i0 + srow) << 10) + sc8;
    const _Float16* pa2 = AG + ((size_t)(b * 3 + 2) << 20) + ((size_t)(i0 + srow) << 10) + sc8;
    size_t hoff0 = ((size_t)b << 16) + ((size_t)srow << 10) + sc8;
    size_t hoff1 = ((size_t)b << 16) + ((size_t)(srow + 32) << 10) + sc8;
    int kbF = (w * 3) >> 2, kbL = (w * 3 + 2) >> 2;

    for (int t = 0; t < T_; ++t) {
        #pragma unroll
        for (int phase = 0; phase < 2; ++phase) {
            const _Float16* HtIn = phase ? HtB : HtA;
            if (tid < 96) { int k = tid >> 5, il = tid & 31; sS2[k][il] = S2[(((size_t)(b * 3 + k) * T_ + t) << 10) + i0 + il]; }
            const _Float16* pb0 = HtIn + hoff0;
            const _Float16* pb1 = HtIn + hoff1;

            f32x4 acc[2][3];
            #pragma unroll
            for (int m = 0; m < 2; ++m)
                #pragma unroll
                for (int n = 0; n < 3; ++n) acc[m][n] = (f32x4){0.f, 0.f, 0.f, 0.f};

            f16x8 rA0 = *(const f16x8*)pa0, rA1 = *(const f16x8*)pa1, rA2 = *(const f16x8*)pa2;
            f16x8 rB0 = *(const f16x8*)pb0, rB1 = *(const f16x8*)pb1;
            *(f16x8*)&sAm[0][srow][sc8] = rA0;
            *(f16x8*)&sAm[0][32 + srow][sc8] = rA1;
            *(f16x8*)&sAm[0][64 + srow][sc8] = rA2;
            *(f16x8*)&sBm[0][srow][sc8] = rB0;
            *(f16x8*)&sBm[0][srow + 32][sc8] = rB1;
            __syncthreads();

            for (int tt = 0; tt < 16; ++tt) {
                int cur = tt & 1;
                if (tt < 15) {
                    int kn = (tt + 1) * 64;
                    rA0 = *(const f16x8*)&pa0[kn]; rA1 = *(const f16x8*)&pa1[kn]; rA2 = *(const f16x8*)&pa2[kn];
                    rB0 = *(const f16x8*)&pb0[kn]; rB1 = *(const f16x8*)&pb1[kn];
                }
                #pragma unroll
                for (int ks = 0; ks < 2; ++ks) {
                    int ko = ks * 32 + kg * 8;
                    f16x8 aF0 = *(const f16x8*)&sAm[cur][kbF * 32 + ln][ko];
                    f16x8 aF1 = *(const f16x8*)&sAm[cur][kbF * 32 + 16 + ln][ko];
                    f16x8 aL0 = *(const f16x8*)&sAm[cur][kbL * 32 + ln][ko];
                    f16x8 aL1 = *(const f16x8*)&sAm[cur][kbL * 32 + 16 + ln][ko];
                    #pragma unroll
                    for (int ni = 0; ni < 3; ++ni) {
                        int ct = w * 3 + ni;
                        f16x8 bb = *(const f16x8*)&sBm[cur][(ct & 3) * 16 + ln][ko];
                        bool late = (ct >> 2) != kbF;
                        f16x8 a0 = late ? aL0 : aF0;
                        f16x8 a1 = late ? aL1 : aF1;
                        acc[0][ni] = __builtin_amdgcn_mfma_f32_16x16x32_f16(a0, bb, acc[0][ni], 0, 0, 0);
                        acc[1][ni] = __builtin_amdgcn_mfma_f32_16x16x32_f16(a1, bb, acc[1][ni], 0, 0, 0);
                    }
                }
                if (tt < 15) {
                    int nb = cur ^ 1;
                    *(f16x8*)&sAm[nb][srow][sc8] = rA0;
                    *(f16x8*)&sAm[nb][32 + srow][sc8] = rA1;
                    *(f16x8*)&sAm[nb][64 + srow][sc8] = rA2;
                    *(f16x8*)&sBm[nb][srow][sc8] = rB0;
                    *(f16x8*)&sBm[nb][srow + 32][sc8] = rB1;
                    __syncthreads();
                }
            }
            __syncthreads();

            #pragma unroll
            for (int m = 0; m < 2; ++m)
                #pragma unroll
                for (int ni = 0; ni < 3; ++ni)
                    #pragma unroll
                    for (int r = 0; r < 4; ++r)
                        sZ[m * 16 + kg * 4 + r][(w * 3 + ni) * 16 + ln] = (_Float16)acc[m][ni][r];

            if (phase == 0) {
                f32x4 e[2][2];
                #pragma unroll
                for (int m = 0; m < 2; ++m)
                    #pragma unroll
                    for (int n = 0; n < 2; ++n) e[m][n] = (f32x4){0.f, 0.f, 0.f, 0.f};
                for (int kc = 0; kc < 192; kc += 64) {
                    #pragma unroll
                    for (int it2 = 0; it2 < 4; ++it2) {
                        int idx = it2 * 256 + tid; int row = idx >> 3, c8 = (idx & 7) * 8;
                        *(f16x8*)&sW[row][c8] = *(const f16x8*)&wghT[(size_t)row * 192 + kc + c8];
                    }
                    __syncthreads();
                    #pragma unroll
                    for (int ks = 0; ks < 4; ++ks) {
                        int ko = ks * 16 + kg * 4;
                        f16x4 az0 = *(const f16x4*)&sZ[ln][kc + ko];
                        f16x4 az1 = *(const f16x4*)&sZ[16 + ln][kc + ko];
                        f16x4 bw0 = *(const f16x4*)&sW[w * 32 + ln][ko];
                        f16x4 bw1 = *(const f16x4*)&sW[w * 32 + 16 + ln][ko];
                        e[0][0] = __builtin_amdgcn_mfma_f32_16x16x16f16(az0, bw0, e[0][0], 0, 0, 0);
                        e[0][1] = __builtin_amdgcn_mfma_f32_16x16x16f16(az0, bw1, e[0][1], 0, 0, 0);
                        e[1][0] = __builtin_amdgcn_mfma_f32_16x16x16f16(az1, bw0, e[1][0], 0, 0, 0);
                        e[1][1] = __builtin_amdgcn_mfma_f32_16x16x16f16(az1, bw1, e[1][1], 0, 0, 0);
                    }
                    __syncthreads();
                }
                #pragma unroll
                for (int n = 0; n < 2; ++n) {
                    int o = w * 32 + n * 16 + ln;
                    if (o < H_) {
                        #pragma unroll
                        for (int m = 0; m < 2; ++m)
                            #pragma unroll
                            for (int r = 0; r < 4; ++r) {
                                int il = m * 16 + kg * 4 + r;
                                float pre = e[m][n][r] + wxg0[n] * sS2[0][il] + wxg1[n] * sS2[1][il] + wxg2[n] * sS2[2][il] + bgr[n];
                                zS[il][o] = (_Float16)(1.0f / (1.0f + expf(-pre)));
                            }
                    } else {
                        int c = o - H_;
                        #pragma unroll
                        for (int m = 0; m < 2; ++m) {
                            f16x4 hold4 = *(const f16x4*)&HtA[((size_t)(b * 64 + c) << 10) + i0 + m * 16 + kg * 4];
                            alignas(8) _Float16 hb[4];
                            #pragma unroll
                            for (int r = 0; r < 4; ++r) {
                                int il = m * 16 + kg * 4 + r;
                                float pre = e[m][n][r] + wxg0[n] * sS2[0][il] + wxg1[n] * sS2[1][il] + wxg2[n] * sS2[2][il] + bgr[n];
                                float v = 1.0f / (1.0f + expf(-pre));
                                hb[r] = (_Float16)(v * (float)hold4[r]);
                            }
                            *(f16x4*)&HtB[((size_t)(b * 64 + c) << 10) + i0 + m * 16 + kg * 4] = *(f16x4*)&hb[0];
                        }
                    }
                }
            } else {
                f32x4 e[2];
                e[0] = (f32x4){0.f, 0.f, 0.f, 0.f};
                e[1] = (f32x4){0.f, 0.f, 0.f, 0.f};
                for (int kc = 0; kc < 192; kc += 64) {
                    #pragma unroll
                    for (int it2 = 0; it2 < 2; ++it2) {
                        int idx = it2 * 256 + tid; int row = idx >> 3, c8 = (idx & 7) * 8;
                        *(f16x8*)&sW[row][c8] = *(const f16x8*)&wuhT[(size_t)row * 192 + kc + c8];
                    }
                    __syncthreads();
                    #pragma unroll
                    for (int ks = 0; ks < 4; ++ks) {
                        int ko = ks * 16 + kg * 4;
                        f16x4 az0 = *(const f16x4*)&sZ[ln][kc + ko];
                        f16x4 az1 = *(const f16x4*)&sZ[16 + ln][kc + ko];
                        f16x4 bw  = *(const f16x4*)&sW[w * 16 + ln][ko];
                        e[0] = __builtin_amdgcn_mfma_f32_16x16x16f16(az0, bw, e[0], 0, 0, 0);
                        e[1] = __builtin_amdgcn_mfma_f32_16x16x16f16(az1, bw, e[1], 0, 0, 0);
                    }
                    __syncthreads();
                }
                #pragma unroll
                for (int m = 0; m < 2; ++m) {
                    alignas(8) _Float16 hb[4];
                    #pragma unroll
                    for (int r = 0; r < 4; ++r) {
                        int il = m * 16 + kg * 4 + r;
                        float pre = e[m][r] + wxu0 * sS2[0][il] + wxu1 * sS2[1][il] + wxu2 * sS2[2][il] + bur;
                        float hc = tanhf(pre);
                        float z = (float)zS[il][ou];
                        float hn = z * hc + (1.0f - z) * h_reg[m][r];
                        h_reg[m][r] = hn;
                        hb[r] = (_Float16)hn;
                    }
                    *(f16x4*)&HtA[((size_t)(b * 64 + ou) << 10) + i0 + m * 16 + kg * 4] = *(f16x4*)&hb[0];
                }
            }
            if (t < T_ - 1 || phase == 0) {
                __threadfence();
                grid.sync();
            }
        }
    }

    // ---- decoder from f32 h_reg ----
    __syncthreads();
    float* hF  = (float*)smem;              // [32][64]
    float* wds = (float*)(smem + 8192);     // [768]
    float* bds = (float*)(smem + 11264);    // [12]
    #pragma unroll
    for (int m = 0; m < 2; ++m)
        #pragma unroll
        for (int r = 0; r < 4; ++r)
            hF[(m * 16 + kg * 4 + r) * 64 + ou] = h_reg[m][r];
    for (int idx = tid; idx < 768; idx += 256) wds[idx] = Wd[idx];
    if (tid < 12) bds[tid] = bd[tid];
    __syncthreads();
    for (int oidx = tid; oidx < 384; oidx += 256) {
        int il = oidx & 31, tt = oidx >> 5;
        float acc = bds[tt];
        #pragma unroll
        for (int c = 0; c < 64; ++c) acc += hF[il * 64 + c] * wds[c * 12 + tt];
        out[(((size_t)(b * T_ + tt)) << 10) + i0 + il] = acc;
    }
}

// ============================================================================
// Fallback path (proven round-11 structure): per-step kernels, grid 1024.
// zf is f16; h stays f32 (proven numerics). Decoder folded into fup at t=11.
// ============================================================================
__global__ __launch_bounds__(256) void k_fzr2(const _Float16* __restrict__ AG,
                                              const _Float16* __restrict__ HtIn,
                                              const _Float16* __restrict__ wghT,
                                              const float* __restrict__ wx,
                                              const float* __restrict__ bg,
                                              const float* __restrict__ S2,
                                              const float* __restrict__ h,
                                              _Float16* __restrict__ zf,
                                              _Float16* __restrict__ HtOut, int t) {
    int bx = blockIdx.x; int it = bx & 63, b = bx >> 6; int i0 = it * 16;
    __shared__ __align__(16) char smem[32256];
    _Float16 (*sA)[48][72] = reinterpret_cast<_Float16(*)[48][72]>(smem);
    _Float16 (*sB)[64][72] = reinterpret_cast<_Float16(*)[64][72]>(smem + 13824);
    _Float16 (*sZ)[200]    = reinterpret_cast<_Float16(*)[200]>(smem);
    _Float16 (*sW)[72]     = reinterpret_cast<_Float16(*)[72]>(smem + 6400);
    __shared__ float sS2[3][16];
    __shared__ float sWX[384];
    __shared__ float sBias[128];
    int tid = threadIdx.x;
    int w = tid >> 6, lane = tid & 63, ln = lane & 15, kg = lane >> 4;
    if (tid < 48) { int k = tid >> 4, il = tid & 15; sS2[k][il] = S2[(((size_t)(b * 3 + k) * T_ + t) << 10) + i0 + il]; }
    for (int q = tid; q < 384; q += 256) sWX[q] = wx[q];
    if (tid < 128) sBias[tid] = bg[tid];

    const _Float16* pA[3]; int c4A[3], rowA[3];
    #pragma unroll
    for (int q = 0; q < 3; ++q) {
        int idx = q * 256 + tid; rowA[q] = idx >> 4; c4A[q] = (idx & 15) * 4;
        int kb = rowA[q] >> 4, rloc = rowA[q] & 15;
        pA[q] = AG + ((size_t)(b * 3 + kb) << 20) + ((size_t)(i0 + rloc) << 10) + c4A[q];
    }
    const _Float16* pB[2]; int c8B[2], rowB[2];
    #pragma unroll
    for (int q = 0; q < 2; ++q) {
        int idx = q * 256 + tid; rowB[q] = idx >> 3; c8B[q] = (idx & 7) * 8;
        pB[q] = HtIn + ((size_t)b << 16) + ((size_t)rowB[q] << 10) + c8B[q];
    }

    f32x4 acc[3];
    #pragma unroll
    for (int n = 0; n < 3; ++n) acc[n] = (f32x4){0.f, 0.f, 0.f, 0.f};

    f16x4 ra[3]; f16x8 rb[2];
    #pragma unroll
    for (int q = 0; q < 3; ++q) ra[q] = *(const f16x4*)pA[q];
    #pragma unroll
    for (int q = 0; q < 2; ++q) rb[q] = *(const f16x8*)pB[q];
    #pragma unroll
    for (int q = 0; q < 3; ++q) *(f16x4*)&sA[0][rowA[q]][c4A[q]] = ra[q];
    #pragma unroll
    for (int q = 0; q < 2; ++q) *(f16x8*)&sB[0][rowB[q]][c8B[q]] = rb[q];
    __syncthreads();

    int kbF = (w * 3) >> 2, kbL = (w * 3 + 2) >> 2;
    for (int tt = 0; tt < 16; ++tt) {
        int cur = tt & 1;
        if (tt < 15) {
            int kn = (tt + 1) * 64;
            #pragma unroll
            for (int q = 0; q < 3; ++q) ra[q] = *(const f16x4*)&pA[q][kn];
            #pragma unroll
            for (int q = 0; q < 2; ++q) rb[q] = *(const f16x8*)&pB[q][kn];
        }
        #pragma unroll
        for (int ks = 0; ks < 2; ++ks) {
            int ko = ks * 32 + kg * 8;
            f16x8 aF = *(const f16x8*)&sA[cur][kbF * 16 + ln][ko];
            f16x8 aL = *(const f16x8*)&sA[cur][kbL * 16 + ln][ko];
            #pragma unroll
            for (int ni = 0; ni < 3; ++ni) {
                int ct = w * 3 + ni;
                f16x8 bb = *(const f16x8*)&sB[cur][(ct & 3) * 16 + ln][ko];
                f16x8 a = ((ct >> 2) != kbF) ? aL : aF;
                acc[ni] = __builtin_amdgcn_mfma_f32_16x16x32_f16(a, bb, acc[ni], 0, 0, 0);
            }
        }
        if (tt < 15) {
            int nb = cur ^ 1;
            #pragma unroll
            for (int q = 0; q < 3; ++q) *(f16x4*)&sA[nb][rowA[q]][c4A[q]] = ra[q];
            #pragma unroll
            for (int q = 0; q < 2; ++q) *(f16x8*)&sB[nb][rowB[q]][c8B[q]] = rb[q];
            __syncthreads();
        }
    }
    __syncthreads();

    #pragma unroll
    for (int ni = 0; ni < 3; ++ni)
        #pragma unroll
        for (int r = 0; r < 4; ++r)
            sZ[kg * 4 + r][(w * 3 + ni) * 16 + ln] = (_Float16)acc[ni][r];

    f32x4 e[2];
    e[0] = (f32x4){0.f, 0.f, 0.f, 0.f};
    e[1] = (f32x4){0.f, 0.f, 0.f, 0.f};
    for (int kc = 0; kc < 192; kc += 64) {
        #pragma unroll
        for (int it2 = 0; it2 < 4; ++it2) {
            int idx = it2 * 256 + tid; int row = idx >> 3, c8 = (idx & 7) * 8;
            *(f16x8*)&sW[row][c8] = *(const f16x8*)&wghT[(size_t)row * 192 + kc + c8];
        }
        __syncthreads();
        #pragma unroll
        for (int ks = 0; ks < 4; ++ks) {
            int ko = ks * 16 + kg * 4;
            f16x4 az  = *(const f16x4*)&sZ[ln][kc + ko];
            f16x4 bw0 = *(const f16x4*)&sW[w * 32 + ln][ko];
            f16x4 bw1 = *(const f16x4*)&sW[w * 32 + 16 + ln][ko];
            e[0] = __builtin_amdgcn_mfma_f32_16x16x16f16(az, bw0, e[0], 0, 0, 0);
            e[1] = __builtin_amdgcn_mfma_f32_16x16x16f16(az, bw1, e[1], 0, 0, 0);
        }
        __syncthreads();
    }

    #pragma unroll
    for (int n = 0; n < 2; ++n) {
        int o = w * 32 + n * 16 + ln;
        float w0 = sWX[o], w1 = sWX[128 + o], w2 = sWX[256 + o], bi = sBias[o];
        if (o < H_) {
            alignas(8) _Float16 zv[4];
            #pragma unroll
            for (int r = 0; r < 4; ++r) {
                int il = kg * 4 + r;
                float pre = e[n][r] + w0 * sS2[0][il] + w1 * sS2[1][il] + w2 * sS2[2][il] + bi;
                zv[r] = (_Float16)(1.0f / (1.0f + expf(-pre)));
            }
            *(f16x4*)&zf[((size_t)(b * 64 + o) << 10) + i0 + kg * 4] = *(f16x4*)&zv[0];
        } else {
            int c = o - H_;
            alignas(8) _Float16 hb[4];
            #pragma unroll
            for (int r = 0; r < 4; ++r) {
                int il = kg * 4 + r;
                float pre = e[n][r] + w0 * sS2[0][il] + w1 * sS2[1][il] + w2 * sS2[2][il] + bi;
                float v = 1.0f / (1.0f + expf(-pre));
                hb[r] = (_Float16)(v * h[((size_t)((b << 10) + i0 + il)) * H_ + c]);
            }
            *(f16x4*)&HtOut[((size_t)(b * 64 + c) << 10) + i0 + kg * 4] = *(f16x4*)&hb[0];
        }
    }
}

__global__ __launch_bounds__(256) void k_fup2(const _Float16* __restrict__ AG,
                                              const _Float16* __restrict__ HtIn,
                                              const _Float16* __restrict__ wuhT,
                                              const float* __restrict__ wx,
                                              const float* __restrict__ bu,
                                              const float* __restrict__ S2,
                                              const _Float16* __restrict__ zf,
                                              float* __restrict__ h,
                                              _Float16* __restrict__ HtOut,
                                              const float* __restrict__ Wd,
                                              const float* __restrict__ bd,
                                              float* __restrict__ out, int t) {
    int bx = blockIdx.x; int it = bx & 63, b = bx >> 6; int i0 = it * 16;
    __shared__ __align__(16) char smem[32256];
    _Float16 (*sA)[48][72] = reinterpret_cast<_Float16(*)[48][72]>(smem);
    _Float16 (*sB)[64][72] = reinterpret_cast<_Float16(*)[64][72]>(smem + 13824);
    _Float16 (*sZ)[200]    = reinterpret_cast<_Float16(*)[200]>(smem);
    _Float16 (*sW)[72]     = reinterpret_cast<_Float16(*)[72]>(smem + 6400);
    __shared__ float sS2[3][16];
    __shared__ float sWX[192];
    __shared__ float sBias[64];
    int tid = threadIdx.x;
    int w = tid >> 6, lane = tid & 63, ln = lane & 15, kg = lane >> 4;
    if (tid < 48) { int k = tid >> 4, il = tid & 15; sS2[k][il] = S2[(((size_t)(b * 3 + k) * T_ + t) << 10) + i0 + il]; }
    if (tid < 192) sWX[tid] = wx[384 + tid];
    if (tid < 64) sBias[tid] = bu[tid];

    const _Float16* pA[3]; int c4A[3], rowA[3];
    #pragma unroll
    for (int q = 0; q < 3; ++q) {
        int idx = q * 256 + tid; rowA[q] = idx >> 4; c4A[q] = (idx & 15) * 4;
        int kb = rowA[q] >> 4, rloc = rowA[q] & 15;
        pA[q] = AG + ((size_t)(b * 3 + kb) << 20) + ((size_t)(i0 + rloc) << 10) + c4A[q];
    }
    const _Float16* pB[2]; int c8B[2], rowB[2];
    #pragma unroll
    for (int q = 0; q < 2; ++q) {
        int idx = q * 256 + tid; rowB[q] = idx >> 3; c8B[q] = (idx & 7) * 8;
        pB[q] = HtIn + ((size_t)b << 16) + ((size_t)rowB[q] << 10) + c8B[q];
    }

    f32x4 acc[3];
    #pragma unroll
    for (int n = 0; n < 3; ++n) acc[n] = (f32x4){0.f, 0.f, 0.f, 0.f};

    f16x4 ra[3]; f16x8 rb[2];
    #pragma unroll
    for (int q = 0; q < 3; ++q) ra[q] = *(const f16x4*)pA[q];
    #pragma unroll
    for (int q = 0; q < 2; ++q) rb[q] = *(const f16x8*)pB[q];
    #pragma unroll
    for (int q = 0; q < 3; ++q) *(f16x4*)&sA[0][rowA[q]][c4A[q]] = ra[q];
    #pragma unroll
    for (int q = 0; q < 2; ++q) *(f16x8*)&sB[0][rowB[q]][c8B[q]] = rb[q];
    __syncthreads();

    int kbF = (w * 3) >> 2, kbL = (w * 3 + 2) >> 2;
    for (int tt = 0; tt < 16; ++tt) {
        int cur = tt & 1;
        if (tt < 15) {
            int kn = (tt + 1) * 64;
            #pragma unroll
            for (int q = 0; q < 3; ++q) ra[q] = *(const f16x4*)&pA[q][kn];
            #pragma unroll
            for (int q = 0; q < 2; ++q) rb[q] = *(const f16x8*)&pB[q][kn];
        }
        #pragma unroll
        for (int ks = 0; ks < 2; ++ks) {
            int ko = ks * 32 + kg * 8;
            f16x8 aF = *(const f16x8*)&sA[cur][kbF * 16 + ln][ko];
            f16x8 aL = *(const f16x8*)&sA[cur][kbL * 16 + ln][ko];
            #pragma unroll
            for (int ni = 0; ni < 3; ++ni) {
                int ct = w * 3 + ni;
                f16x8 bb = *(const f16x8*)&sB[cur][(ct & 3) * 16 + ln][ko];
                f16x8 a = ((ct >> 2) != kbF) ? aL : aF;
                acc[ni] = __builtin_amdgcn_mfma_f32_16x16x32_f16(a, bb, acc[ni], 0, 0, 0);
            }
        }
        if (tt < 15) {
            int nb = cur ^ 1;
            #pragma unroll
            for (int q = 0; q < 3; ++q) *(f16x4*)&sA[nb][rowA[q]][c4A[q]] = ra[q];
            #pragma unroll
            for (int q = 0; q < 2; ++q) *(f16x8*)&sB[nb][rowB[q]][c8B[q]] = rb[q];
            __syncthreads();
        }
    }
    __syncthreads();

    #pragma unroll
    for (int ni = 0; ni < 3; ++ni)
        #pragma unroll
        for (int r = 0; r < 4; ++r)
            sZ[kg * 4 + r][(w * 3 + ni) * 16 + ln] = (_Float16)acc[ni][r];

    f32x4 e = (f32x4){0.f, 0.f, 0.f, 0.f};
    for (int kc = 0; kc < 192; kc += 64) {
        #pragma unroll
        for (int it2 = 0; it2 < 2; ++it2) {
            int idx = it2 * 256 + tid; int row = idx >> 3, c8 = (idx & 7) * 8;
            *(f16x8*)&sW[row][c8] = *(const f16x8*)&wuhT[(size_t)row * 192 + kc + c8];
        }
        __syncthreads();
        #pragma unroll
        for (int ks = 0; ks < 4; ++ks) {
            int ko = ks * 16 + kg * 4;
            f16x4 az = *(const f16x4*)&sZ[ln][kc + ko];
            f16x4 bw = *(const f16x4*)&sW[w * 16 + ln][ko];
            e = __builtin_amdgcn_mfma_f32_16x16x16f16(az, bw, e, 0, 0, 0);
        }
        __syncthreads();
    }

    int o = w * 16 + ln;
    float w0 = sWX[o], w1 = sWX[64 + o], w2 = sWX[128 + o], bi = sBias[o];
    f16x4 z4 = *(const f16x4*)&zf[((size_t)(b * 64 + o) << 10) + i0 + kg * 4];
    alignas(8) _Float16 hb[4];
    float hnv[4];
    #pragma unroll
    for (int r = 0; r < 4; ++r) {
        int il = kg * 4 + r;
        float pre = e[r] + w0 * sS2[0][il] + w1 * sS2[1][il] + w2 * sS2[2][il] + bi;
        float hc = tanhf(pre);
        size_t gi = ((size_t)((b << 10) + i0 + il)) * H_ + o;
        float z = (float)z4[r];
        float hn = z * hc + (1.0f - z) * h[gi];
        h[gi] = hn;
        hnv[r] = hn;
        hb[r] = (_Float16)hn;
    }
    *(f16x4*)&HtOut[((size_t)(b * 64 + o) << 10) + i0 + kg * 4] = *(f16x4*)&hb[0];

    if (t == T_ - 1) {
        __syncthreads();
        float* hF  = (float*)smem;              // [16][64]
        float* wds = (float*)(smem + 4096);     // [768]
        float* bds = (float*)(smem + 7168);     // [12]
        #pragma unroll
        for (int r = 0; r < 4; ++r) hF[(kg * 4 + r) * 64 + o] = hnv[r];
        for (int idx = tid; idx < 768; idx += 256) wds[idx] = Wd[idx];
        if (tid < 12) bds[tid] = bd[tid];
        __syncthreads();
        for (int oidx = tid; oidx < 192; oidx += 256) {
            int il = oidx & 15, tt2 = oidx >> 4;
            float acc2 = bds[tt2];
            #pragma unroll
            for (int c = 0; c < 64; ++c) acc2 += hF[il * 64 + c] * wds[c * 12 + tt2];
            out[(((size_t)(b * T_ + tt2)) << 10) + i0 + il] = acc2;
        }
    }
}

extern "C" void kernel_launch(void* const* d_in, const int* in_sizes, int n_in,
                              void* d_out, int out_size, void* d_ws, size_t ws_size,
                              hipStream_t stream) {
    const float* x  = (const float*)d_in[0];
    const float* G  = (const float*)d_in[1];
    const float* A  = (const float*)d_in[2];
    const float* Wg = (const float*)d_in[3];
    const float* bg = (const float*)d_in[4];
    const float* Wu = (const float*)d_in[5];
    const float* bu = (const float*)d_in[6];
    const float* Wd = (const float*)d_in[7];
    const float* bd = (const float*)d_in[8];
    float* out = (float*)d_out;
    float* ws  = (float*)d_ws;

    float* h   = ws + OFF_H;
    float* S2  = ws + OFF_S2;
    float* wxb = ws + OFF_WX;
    _Float16* zf   = (_Float16*)(ws + OFF_ZF);
    _Float16* HtA  = (_Float16*)(ws + OFF_HTA);
    _Float16* HtB  = (_Float16*)(ws + OFF_HTB);
    _Float16* S1   = (_Float16*)(ws + OFF_S1);
    _Float16* wghT = (_Float16*)(ws + OFF_WGT);
    _Float16* wuhT = (_Float16*)(ws + OFF_WUT);
    _Float16* GfT  = (_Float16*)(ws + OFF_GT);
    _Float16* AG   = (_Float16*)(ws + OFF_AG);
    _Float16* Af   = (_Float16*)(ws + OFF_AF);

    hipMemsetAsync(h, 0, (size_t)B_ * N_ * H_ * sizeof(float), stream);
    hipMemsetAsync((void*)HtA, 0, (size_t)B_ * N_ * H_ * sizeof(_Float16), stream);
    k_pre<<<9203, 256, 0, stream>>>(A, G, x, Wg, Wu, Af, GfT, S1, wghT, wuhT, wxb);
    k_main<<<3328, 256, 0, stream>>>(Af, GfT, AG, S1, S2);

    // deterministic path choice: cooperative only if the runtime guarantees
    // 2 blocks/CU co-residency for k_loop (grid 512 on 256 CUs).
    int nb = 0;
    hipOccupancyMaxActiveBlocksPerMultiprocessor(&nb, k_loop, 256, 0);
    if (nb >= 2) {
        void* args[] = {(void*)&AG, (void*)&HtA, (void*)&HtB, (void*)&wghT, (void*)&wuhT,
                        (void*)&wxb, (void*)&bg, (void*)&bu, (void*)&S2,
                        (void*)&Wd, (void*)&bd, (void*)&out};
        hipLaunchCooperativeKernel((const void*)k_loop, dim3(512), dim3(256), args, 0, stream);
    } else {
        for (int t = 0; t < T_; ++t) {
            k_fzr2<<<1024, 256, 0, stream>>>(AG, HtA, wghT, wxb, bg, S2, h, zf, HtB, t);
            k_fup2<<<1024, 256, 0, stream>>>(AG, HtB, wuhT, wxb, bu, S2, zf, h, HtA, Wd, bd, out, t);
        }
    }
}